// Round 5
// baseline (280.807 us; speedup 1.0000x reference)
//
#include <hip/hip_runtime.h>
#include <hip/hip_bf16.h>
#include <stdint.h>

typedef __bf16 bf16_t;
typedef __bf16 bf16x8 __attribute__((ext_vector_type(8)));
typedef __bf16 bf16x4 __attribute__((ext_vector_type(4)));
typedef __bf16 bf16x2 __attribute__((ext_vector_type(2)));
typedef float floatx4 __attribute__((ext_vector_type(4)));

#define QSCALE 0.180336879f  /* 0.125 * log2(e) : fold score scale + exp2 domain into Q */

#if __has_builtin(__builtin_amdgcn_cvt_pk_bf16_f32)
#define HAS_PK_BF16 1
#endif

__device__ static inline void gll16(const void* g, void* l) {
    __builtin_amdgcn_global_load_lds((const __attribute__((address_space(1))) void*)g,
                                     (__attribute__((address_space(3))) void*)l, 16, 0, 0);
}

__device__ static inline bf16x8 pack8(const float* p) {
    bf16x8 o;
#ifdef HAS_PK_BF16
#pragma unroll
    for (int j = 0; j < 4; j++) {
        bf16x2 t2 = __builtin_amdgcn_cvt_pk_bf16_f32(p[2 * j], p[2 * j + 1]);
        o[2 * j] = t2[0]; o[2 * j + 1] = t2[1];
    }
#else
#pragma unroll
    for (int j = 0; j < 8; j++) o[j] = (bf16_t)p[j];
#endif
    return o;
}

// ---------------------------------------------------------------- fp32 -> bf16 (fused: inp, Wqkv, Wo)
__global__ __launch_bounds__(256) void cvt_all(const float* __restrict__ inp,
                                               const float* __restrict__ wqkv,
                                               const float* __restrict__ wo,
                                               bf16_t* __restrict__ o_inp,
                                               bf16_t* __restrict__ o_wqkv,
                                               bf16_t* __restrict__ o_wo) {
    int blk = blockIdx.x;
    const float* src;
    bf16_t* dst;
    if (blk < 4096)      { src = inp;  dst = o_inp; }
    else if (blk < 7168) { src = wqkv; dst = o_wqkv; blk -= 4096; }
    else                 { src = wo;   dst = o_wo;   blk -= 7168; }
    int i = blk * 256 + threadIdx.x;
    float4 v = ((const float4*)src)[i];
    float p[4] = {v.x, v.y, v.z, v.w};
    bf16x4 o;
#ifdef HAS_PK_BF16
    bf16x2 t0 = __builtin_amdgcn_cvt_pk_bf16_f32(p[0], p[1]);
    bf16x2 t1 = __builtin_amdgcn_cvt_pk_bf16_f32(p[2], p[3]);
    o[0] = t0[0]; o[1] = t0[1]; o[2] = t1[0]; o[3] = t1[1];
#else
    o[0] = (bf16_t)p[0]; o[1] = (bf16_t)p[1]; o[2] = (bf16_t)p[2]; o[3] = (bf16_t)p[3];
#endif
    ((bf16x4*)dst)[i] = o;
}

// ---------------------------------------------------------------- QKV GEMM
// Depth-2 prefetch (3 LDS buffers), counted vmcnt + raw barriers, LDS chunk-XOR
// swizzle (8-way -> 2-way bank conflicts; source-side inverse per rule #21),
// XCD-chunked block swizzle.
// vT columns are t-PERMUTED within each 32-group: p = (t&~31) | q*8 | h*4 | r.
__global__ __launch_bounds__(256, 3)
void gemm_qkv(const bf16_t* __restrict__ A, const bf16_t* __restrict__ Bw,
              const float* __restrict__ bias,
              bf16_t* __restrict__ qk, bf16_t* __restrict__ vT) {
    constexpr int K = 1024;
    __shared__ bf16_t lA[3][128 * 32];
    __shared__ bf16_t lB[3][128 * 32];
    const int tid  = threadIdx.x;
    const int lane = tid & 63, wave = tid >> 6;
    const int quad = lane >> 4, l16 = lane & 15;
    const int wy = wave >> 1, wx = wave & 1;

    // XCD-chunked swizzle: 768 wg -> 96/XCD contiguous (768 % 8 == 0, bijective).
    const int L  = blockIdx.y * 24 + blockIdx.x;
    const int nL = (L & 7) * 96 + (L >> 3);
    const int bm = (nL / 24) * 128, bn = (nL % 24) * 128;

    const int c0 = tid, c1 = tid + 256;
    // source chunk pre-swizzle: LDS slot s of row r holds global chunk s ^ ((r>>1)&3)
    const int k0 = ((c0 & 3) ^ ((c0 >> 3) & 3)) * 8;
    const int k1 = ((c1 & 3) ^ ((c1 >> 3) & 3)) * 8;
    const bf16_t* Ap0 = A + (size_t)(bm + (c0 >> 2)) * K + k0;
    const bf16_t* Ap1 = A + (size_t)(bm + (c1 >> 2)) * K + k1;
    const bf16_t* Bp0 = Bw + (size_t)(bn + (c0 >> 2)) * K + k0;
    const bf16_t* Bp1 = Bw + (size_t)(bn + (c1 >> 2)) * K + k1;
    const int d0 = (wave * 64) * 8;          // wave-uniform dest (elems); HW adds lane*16B
    const int d1 = (256 + wave * 64) * 8;

    // read-side swizzled chunk: chunk `quad` of row R lives in slot quad ^ ((R>>1)&3);
    // (R>>1)&3 == (l16>>1)&3 for all fragment rows (i*16, wy*64 don't touch bits 1-2)
    const int sq8 = (quad ^ ((l16 >> 1) & 3)) * 8;

    floatx4 acc[4][4] = {};

    // prologue: stage tiles 0 and 1 (8 gll in flight)
    gll16(Ap0, &lA[0][d0]); gll16(Ap1, &lA[0][d1]);
    gll16(Bp0, &lB[0][d0]); gll16(Bp1, &lB[0][d1]);
    gll16(Ap0 + 32, &lA[1][d0]); gll16(Ap1 + 32, &lA[1][d1]);
    gll16(Bp0 + 32, &lB[1][d0]); gll16(Bp1 + 32, &lB[1][d1]);

    int cur = 0;
    for (int it = 0; it < 32; ++it) {
        if (it < 30) {
            const int kt = (it + 2) * 32;
            const int nb = cur >= 1 ? cur - 1 : 2;        // (cur+2)%3
            gll16(Ap0 + kt, &lA[nb][d0]); gll16(Ap1 + kt, &lA[nb][d1]);
            gll16(Bp0 + kt, &lB[nb][d0]); gll16(Bp1 + kt, &lB[nb][d1]);
            asm volatile("s_waitcnt vmcnt(8)" ::: "memory");   // tile `it` landed; 8 newer stay in flight
        } else if (it == 30) {
            asm volatile("s_waitcnt vmcnt(4)" ::: "memory");
        } else {
            asm volatile("s_waitcnt vmcnt(0)" ::: "memory");
        }
        __builtin_amdgcn_s_barrier();          // all waves' tile-cur data visible
        __builtin_amdgcn_sched_barrier(0);

        bf16x8 af[4], bfr[4];
#pragma unroll
        for (int i = 0; i < 4; i++) {
            af[i]  = *(const bf16x8*)(&lA[cur][(wy * 64 + i * 16 + l16) * 32 + sq8]);
            bfr[i] = *(const bf16x8*)(&lB[cur][(wx * 64 + i * 16 + l16) * 32 + sq8]);
        }
#pragma unroll
        for (int i = 0; i < 4; i++)
#pragma unroll
            for (int j = 0; j < 4; j++)
                acc[i][j] = __builtin_amdgcn_mfma_f32_16x16x32_bf16(af[i], bfr[j], acc[i][j], 0, 0, 0);

        __builtin_amdgcn_sched_barrier(0);
        __builtin_amdgcn_s_barrier();          // reads of buf[cur] complete -> safe to overwrite next iter
        cur = cur < 2 ? cur + 1 : 0;
    }

    const bool is_v = (bn >= 2048);
#pragma unroll
    for (int j = 0; j < 4; j++) {
        const int n = bn + wx * 64 + j * 16 + l16;
        const float bv = bias[n];
        const bool isq = (n < 1024);
#pragma unroll
        for (int i = 0; i < 4; i++) {
            const int mbase = bm + wy * 64 + i * 16 + quad * 4;
            if (!is_v) {
#pragma unroll
                for (int r = 0; r < 4; r++) {
                    float c = acc[i][j][r] + bv;
                    if (isq) c *= QSCALE;
                    qk[(size_t)(mbase + r) * 2048 + n] = (bf16_t)c;
                }
            } else {
                const int nn = n - 2048;             // h*64 + d
                const int b  = mbase >> 11;
                const int t  = mbase & 2047;         // 4-aligned
                const int vrow = b * 1024 + nn;      // (b*16+h)*64 + d
                const int pcol = (t & ~31) | (((t >> 2) & 3) << 3) | (((t >> 4) & 1) << 2);
                bf16x4 pack;
#pragma unroll
                for (int r = 0; r < 4; r++) pack[r] = (bf16_t)(acc[i][j][r] + bv);
                *(bf16x4*)(vT + (size_t)vrow * 2048 + pcol) = pack;
            }
        }
    }
}

// ---------------------------------------------------------------- flash attention (S^T, split-K, LDS-FREE)
// R4: K/V MFMA fragments loaded DIRECTLY global->VGPR. Per-XCD K/V working set
// (4 heads x 512 KB) = 2 MB -> L2-resident; 16 qt-blocks per (hl,half) reuse it
// from L2. No LDS, no barriers, no staging: waves fully independent (setprio
// regime per m191). Removes the LDS pipe (~1/3 of the old cycle budget) and the
// barrier lockstep that kept MFMA/TRANS/LDS pipes from overlapping.
// Grid 1024 = 32 hl x 16 qt x 2 t-halves. Block = 4 waves x 32 q-rows.
__global__ __launch_bounds__(256, 4)
void attn_kernel(const bf16_t* __restrict__ qk, const bf16_t* __restrict__ vT,
                 bf16_t* __restrict__ Opart, float* __restrict__ lpart) {
    const int tid  = threadIdx.x;
    const int lane = tid & 63, wave = tid >> 6;
    const int quad = lane >> 4, l16 = lane & 15;
    const int bid = blockIdx.x;
    const int s    = bid & 63;
    const int hl   = ((s & 7) << 2) | ((s >> 3) & 3);  // XCD-swizzle: 4 heads/XCD
    const int half = (s >> 5) & 1;
    const int qt   = bid >> 6;
    const int b = hl >> 4, h = hl & 15;
    const int kt0 = half * 1024;

    const bf16_t* Qbase = qk + (size_t)(b * 2048 + qt * 128 + wave * 32) * 2048 + h * 64;
    // per-lane K fragment base: row b*2048 + kt0 + l16, K-half col h*64 + quad*8
    const bf16_t* Kl = qk + (size_t)(b * 2048 + kt0 + l16) * 2048 + 1024 + h * 64 + quad * 8;
    // per-lane V fragment base: row hl*64 + l16, col kt0 + quad*8 (t-permuted layout)
    const bf16_t* Vl = vT + (size_t)(hl * 64 + l16) * 2048 + kt0 + quad * 8;

    bf16x8 qf[2][2];  // B-operand: n = q = l16, k = kc*32 + quad*8
#pragma unroll
    for (int rt = 0; rt < 2; rt++)
#pragma unroll
        for (int kc = 0; kc < 2; kc++)
            qf[rt][kc] = *(const bf16x8*)(Qbase + (size_t)(rt * 16 + l16) * 2048 + kc * 32 + quad * 8);

    floatx4 accO[2][4] = {};    // O[q=quad*4+r][d=ct*16+l16]
    float lacc[2] = {0.f, 0.f};

    for (int it = 0; it < 16; ++it) {
        const bf16_t* Kit = Kl + (size_t)it * 64 * 2048;
        const bf16_t* Vit = Vl + it * 64;
        // issue all 8 K fragment loads up front (compiler pipelines the vmcnt waits)
        bf16x8 kf0[4], kf1[4];
#pragma unroll
        for (int nt = 0; nt < 4; nt++) {
            kf0[nt] = *(const bf16x8*)(Kit + (size_t)(nt * 16) * 2048);
            kf1[nt] = *(const bf16x8*)(Kit + (size_t)(nt * 16) * 2048 + 32);
        }
        // S^T = K.Q^T : rows t (quad*4+r per nt-tile), cols q (l16)
        floatx4 st[2][4] = {};
        __builtin_amdgcn_s_setprio(1);
#pragma unroll
        for (int nt = 0; nt < 4; nt++) {
            st[0][nt] = __builtin_amdgcn_mfma_f32_16x16x32_bf16(kf0[nt], qf[0][0], st[0][nt], 0, 0, 0);
            st[0][nt] = __builtin_amdgcn_mfma_f32_16x16x32_bf16(kf1[nt], qf[0][1], st[0][nt], 0, 0, 0);
            st[1][nt] = __builtin_amdgcn_mfma_f32_16x16x32_bf16(kf0[nt], qf[1][0], st[1][nt], 0, 0, 0);
            st[1][nt] = __builtin_amdgcn_mfma_f32_16x16x32_bf16(kf1[nt], qf[1][1], st[1][nt], 0, 0, 0);
        }
        __builtin_amdgcn_s_setprio(0);
        // per t-half: V frags direct from L2; P frags built in-register (permuted t-order)
#pragma unroll
        for (int kc2 = 0; kc2 < 2; kc2++) {
            bf16x8 vf[4];
#pragma unroll
            for (int ct = 0; ct < 4; ct++)
                vf[ct] = *(const bf16x8*)(Vit + (size_t)(ct * 16) * 2048 + kc2 * 32);
#pragma unroll
            for (int rt = 0; rt < 2; rt++) {
                float p[8];
                float ls = 0.f;
#pragma unroll
                for (int j = 0; j < 8; j++) {
                    p[j] = __builtin_amdgcn_exp2f(st[rt][kc2 * 2 + (j >> 2)][j & 3]);
                    ls += p[j];
                }
                lacc[rt] += ls;
                bf16x8 pf = pack8(p);
                __builtin_amdgcn_s_setprio(1);
#pragma unroll
                for (int ct = 0; ct < 4; ct++)
                    accO[rt][ct] = __builtin_amdgcn_mfma_f32_16x16x32_bf16(pf, vf[ct], accO[rt][ct], 0, 0, 0);
                __builtin_amdgcn_s_setprio(0);
            }
        }
    }

    // partial l
    float lsum[2];
#pragma unroll
    for (int rt = 0; rt < 2; rt++) {
        float l = lacc[rt];
        l += __shfl_xor(l, 16);
        l += __shfl_xor(l, 32);
        lsum[rt] = l;
    }
    // partial O with "faithful bug" permutation: dest row (hl&1)*2048 + t, col (hl>>1)*64 + d
    const int b2 = hl & 1;
    const int colb = hl >> 1;
    const int rowb = b2 * 2048 + qt * 128 + wave * 32;
    bf16_t* outb = Opart + (size_t)half * (4096 * 1024) + (size_t)rowb * 1024 + colb * 64;
#pragma unroll
    for (int rt = 0; rt < 2; rt++)
#pragma unroll
        for (int ct = 0; ct < 4; ct++)
#pragma unroll
            for (int r = 0; r < 4; r++)
                outb[(size_t)(rt * 16 + quad * 4 + r) * 1024 + ct * 16 + l16] = (bf16_t)(accO[rt][ct][r]);
    if (quad == 0) {
#pragma unroll
        for (int rt = 0; rt < 2; rt++)
            lpart[half * 65536 + (rowb + rt * 16 + l16) * 16 + colb] = lsum[rt];
    }
}

// ---------------------------------------------------------------- O GEMM, double-buffered, fused split-K combine
// B via gll prefetch-after-barrier (source chunk pre-swizzled); A regs prefetched at
// iter i, combined+staged to lA[nxt] with swizzled ds_write slot AFTER the MFMA phase.
// Single barrier per iter. Output bf16.
__global__ __launch_bounds__(256, 4)
void gemm_o(const bf16_t* __restrict__ Op, const float* __restrict__ lp,
            const bf16_t* __restrict__ Bw, bf16_t* __restrict__ out) {
    constexpr int K = 1024;
    __shared__ bf16_t lA[2][64 * 32];    // 2 x 4 KB
    __shared__ bf16_t lB[2][128 * 32];   // 2 x 8 KB
    const int tid  = threadIdx.x;
    const int lane = tid & 63, wave = tid >> 6;
    const int quad = lane >> 4, l16 = lane & 15;
    const int wy = wave >> 1, wx = wave & 1;   // wave tile: 32m x 64n
    const int bm = blockIdx.y * 64, bn = blockIdx.x * 128;

    const int ca = tid;                         // A: 64 rows x 4 chunks
    const int arow = bm + (ca >> 2);
    const int ak   = (ca & 3) * 8;              // global chunk carried by this thread
    // swizzled LDS write slot: slot = chunk ^ ((row>>1)&3)
    const int aslot = ((ca & 3) ^ ((ca >> 3) & 3));
    const int awr   = ((ca >> 2) * 4 + aslot) * 8;
    const bf16_t* Ap0 = Op + (size_t)arow * 1024 + ak;
    const bf16_t* Ap1 = Ap0 + (size_t)4096 * 1024;
    const float*  lrow = lp + arow * 16;
    const int cb0 = tid, cb1 = tid + 256;       // B: 128 rows x 4 chunks
    // B source chunk pre-swizzle (gll writes LDS linearly)
    const int bk0 = ((cb0 & 3) ^ ((cb0 >> 3) & 3)) * 8;
    const int bk1 = ((cb1 & 3) ^ ((cb1 >> 3) & 3)) * 8;
    const bf16_t* Bp0 = Bw + (size_t)(bn + (cb0 >> 2)) * K + bk0;
    const bf16_t* Bp1 = Bw + (size_t)(bn + (cb1 >> 2)) * K + bk1;
    const int d0 = (wave * 64) * 8;
    const int d1 = (256 + wave * 64) * 8;

    // read-side swizzled chunk (fragment rows: bits 1-2 from l16 only)
    const int xq8 = (quad ^ ((l16 >> 1) & 3)) * 8;

    // prologue: stage tile 0 (A combine + B gll)
    gll16(Bp0, &lB[0][d0]);
    gll16(Bp1, &lB[0][d1]);
    {
        bf16x8 a0 = *(const bf16x8*)(Ap0);
        bf16x8 a1 = *(const bf16x8*)(Ap1);
        const float inv = 1.0f / (lrow[ak >> 6] + lrow[65536 + (ak >> 6)]);
        float p[8];
#pragma unroll
        for (int j = 0; j < 8; j++) p[j] = ((float)a0[j] + (float)a1[j]) * inv;
        *(bf16x8*)&lA[0][awr] = pack8(p);
    }

    floatx4 acc[2][4] = {};
    for (int it = 0; it < 32; ++it) {
        const int cur = it & 1, nxt = cur ^ 1;
        __syncthreads();                    // drains gll + lA writes -> [cur] ready
        bf16x8 na0, na1;
        int kt1 = (it + 1) * 32;
        if (it < 31) {
            na0 = *(const bf16x8*)(Ap0 + kt1);
            na1 = *(const bf16x8*)(Ap1 + kt1);
            gll16(Bp0 + kt1, &lB[nxt][d0]);
            gll16(Bp1 + kt1, &lB[nxt][d1]);
        }
        bf16x8 af[2], bfr[4];
#pragma unroll
        for (int i = 0; i < 2; i++)
            af[i] = *(const bf16x8*)(&lA[cur][(wy * 32 + i * 16 + l16) * 32 + xq8]);
#pragma unroll
        for (int j = 0; j < 4; j++)
            bfr[j] = *(const bf16x8*)(&lB[cur][(wx * 64 + j * 16 + l16) * 32 + xq8]);
#pragma unroll
        for (int i = 0; i < 2; i++)
#pragma unroll
            for (int j = 0; j < 4; j++)
                acc[i][j] = __builtin_amdgcn_mfma_f32_16x16x32_bf16(af[i], bfr[j], acc[i][j], 0, 0, 0);
        if (it < 31) {                      // combine after MFMA phase (na latency hidden)
            const int cb = (kt1 + ak) >> 6;
            const float inv = 1.0f / (lrow[cb] + lrow[65536 + cb]);
            float p[8];
#pragma unroll
            for (int j = 0; j < 8; j++) p[j] = ((float)na0[j] + (float)na1[j]) * inv;
            *(bf16x8*)&lA[nxt][awr] = pack8(p);
        }
    }
#pragma unroll
    for (int j = 0; j < 4; j++) {
        const int n = bn + wx * 64 + j * 16 + l16;
#pragma unroll
        for (int i = 0; i < 2; i++) {
            const int mbase = bm + wy * 32 + i * 16 + quad * 4;
#pragma unroll
            for (int r = 0; r < 4; r++)
                out[(size_t)(mbase + r) * 1024 + n] = (bf16_t)acc[i][j][r];
        }
    }
}

// ---------------------------------------------------------------- residual + LayerNorm (ao in bf16)
__global__ __launch_bounds__(256)
void ln_kernel(const float* __restrict__ inp, const bf16_t* __restrict__ ao,
               const float* __restrict__ gamma, const float* __restrict__ beta,
               float* __restrict__ out) {
    const int row = blockIdx.x, tid = threadIdx.x;
    const int wave = tid >> 6, lane = tid & 63;
    float4 a = ((const float4*)(inp + (size_t)row * 1024))[tid];
    bf16x4 c4 = ((const bf16x4*)(ao + (size_t)row * 1024))[tid];
    float x0 = a.x + (float)c4[0], x1 = a.y + (float)c4[1];
    float x2 = a.z + (float)c4[2], x3 = a.w + (float)c4[3];
    float s = x0 + x1 + x2 + x3;
    float sq = x0 * x0 + x1 * x1 + x2 * x2 + x3 * x3;
#pragma unroll
    for (int mm = 32; mm >= 1; mm >>= 1) {
        s += __shfl_xor(s, mm);
        sq += __shfl_xor(sq, mm);
    }
    __shared__ float rs[4], rq[4];
    if (lane == 0) { rs[wave] = s; rq[wave] = sq; }
    __syncthreads();
    s = rs[0] + rs[1] + rs[2] + rs[3];
    sq = rq[0] + rq[1] + rq[2] + rq[3];
    const float mu = s * (1.0f / 1024.0f);
    const float var = sq * (1.0f / 1024.0f) - mu * mu;
    const float rstd = rsqrtf(var + 1e-5f);
    float4 g = ((const float4*)gamma)[tid], bt = ((const float4*)beta)[tid];
    float4 o;
    o.x = (x0 - mu) * rstd * g.x + bt.x;
    o.y = (x1 - mu) * rstd * g.y + bt.y;
    o.z = (x2 - mu) * rstd * g.z + bt.z;
    o.w = (x3 - mu) * rstd * g.w + bt.w;
    ((float4*)(out + (size_t)row * 1024))[tid] = o;
}

// ---------------------------------------------------------------- launch
extern "C" void kernel_launch(void* const* d_in, const int* in_sizes, int n_in,
                              void* d_out, int out_size, void* d_ws, size_t ws_size,
                              hipStream_t stream) {
    const float* inp   = (const float*)d_in[0];
    const float* Wqkv  = (const float*)d_in[1];
    const float* bqkv  = (const float*)d_in[2];
    const float* Wo    = (const float*)d_in[3];
    const float* gamma = (const float*)d_in[4];
    const float* beta  = (const float*)d_in[5];
    float* out = (float*)d_out;

    // workspace layout (64 MB):
    //  0- 8 : inp_bf   (dead after gemm_qkv)  -> lpart overlay (512 KB, attn)
    //  8-14 : wqkv_bf  (dead after gemm_qkv)
    // 14-16 : wo_bf    (live until gemm_o)
    // 16-32 : qk_buf   (dead after attn)
    // 32-40 : vT_buf   (dead after attn)      -> ao_bf overlay (8 MB, gemm_o out)
    // 48-64 : opart    (2 x 8 MB, attn out, read by gemm_o)
    char* ws = (char*)d_ws;
    bf16_t* inp_bf  = (bf16_t*)(ws);
    bf16_t* wqkv_bf = (bf16_t*)(ws + (8u << 20));
    bf16_t* wo_bf   = (bf16_t*)(ws + (14u << 20));
    bf16_t* qk_buf  = (bf16_t*)(ws + (16u << 20));
    bf16_t* vT_buf  = (bf16_t*)(ws + (32u << 20));
    bf16_t* ao_bf   = (bf16_t*)(ws + (32u << 20));
    bf16_t* opart   = (bf16_t*)(ws + (48u << 20));
    float*  lpart   = (float*)(ws);

    cvt_all<<<8192, 256, 0, stream>>>(inp, Wqkv, Wo, inp_bf, wqkv_bf, wo_bf);
    gemm_qkv<<<dim3(24, 32), 256, 0, stream>>>(inp_bf, wqkv_bf, bqkv, qk_buf, vT_buf);
    attn_kernel<<<1024, 256, 0, stream>>>(qk_buf, vT_buf, opart, lpart);
    gemm_o<<<dim3(8, 64), 256, 0, stream>>>(opart, lpart, wo_bf, ao_bf);
    ln_kernel<<<4096, 256, 0, stream>>>(inp, ao_bf, gamma, beta, out);
}

// Round 6
// 207.157 us; speedup vs baseline: 1.3555x; 1.3555x over previous
//
#include <hip/hip_runtime.h>
#include <hip/hip_bf16.h>
#include <stdint.h>

typedef __bf16 bf16_t;
typedef __bf16 bf16x8 __attribute__((ext_vector_type(8)));
typedef __bf16 bf16x4 __attribute__((ext_vector_type(4)));
typedef __bf16 bf16x2 __attribute__((ext_vector_type(2)));
typedef float floatx4 __attribute__((ext_vector_type(4)));

#define QSCALE 0.180336879f  /* 0.125 * log2(e) : fold score scale + exp2 domain into Q */

#if __has_builtin(__builtin_amdgcn_cvt_pk_bf16_f32)
#define HAS_PK_BF16 1
#endif

__device__ static inline void gll16(const void* g, void* l) {
    __builtin_amdgcn_global_load_lds((const __attribute__((address_space(1))) void*)g,
                                     (__attribute__((address_space(3))) void*)l, 16, 0, 0);
}

__device__ static inline bf16x8 pack8(const float* p) {
    bf16x8 o;
#ifdef HAS_PK_BF16
#pragma unroll
    for (int j = 0; j < 4; j++) {
        bf16x2 t2 = __builtin_amdgcn_cvt_pk_bf16_f32(p[2 * j], p[2 * j + 1]);
        o[2 * j] = t2[0]; o[2 * j + 1] = t2[1];
    }
#else
#pragma unroll
    for (int j = 0; j < 8; j++) o[j] = (bf16_t)p[j];
#endif
    return o;
}

// ---------------------------------------------------------------- fp32 -> bf16 (fused: inp, Wqkv, Wo)
__global__ __launch_bounds__(256) void cvt_all(const float* __restrict__ inp,
                                               const float* __restrict__ wqkv,
                                               const float* __restrict__ wo,
                                               bf16_t* __restrict__ o_inp,
                                               bf16_t* __restrict__ o_wqkv,
                                               bf16_t* __restrict__ o_wo) {
    int blk = blockIdx.x;
    const float* src;
    bf16_t* dst;
    if (blk < 4096)      { src = inp;  dst = o_inp; }
    else if (blk < 7168) { src = wqkv; dst = o_wqkv; blk -= 4096; }
    else                 { src = wo;   dst = o_wo;   blk -= 7168; }
    int i = blk * 256 + threadIdx.x;
    float4 v = ((const float4*)src)[i];
    float p[4] = {v.x, v.y, v.z, v.w};
    bf16x4 o;
#ifdef HAS_PK_BF16
    bf16x2 t0 = __builtin_amdgcn_cvt_pk_bf16_f32(p[0], p[1]);
    bf16x2 t1 = __builtin_amdgcn_cvt_pk_bf16_f32(p[2], p[3]);
    o[0] = t0[0]; o[1] = t0[1]; o[2] = t1[0]; o[3] = t1[1];
#else
    o[0] = (bf16_t)p[0]; o[1] = (bf16_t)p[1]; o[2] = (bf16_t)p[2]; o[3] = (bf16_t)p[3];
#endif
    ((bf16x4*)dst)[i] = o;
}

// ---------------------------------------------------------------- QKV GEMM
// Depth-2 prefetch (3 LDS buffers), counted vmcnt + raw barriers, LDS chunk-XOR
// swizzle, XCD-chunked block swizzle.
// R5 epilogue: K and V written in FRAGMENT-LINEAR layouts so attn's MFMA
// fragment loads are single coalesced base+lane*16B loads (no LDS needed):
//   kT : per 64x64 tile, slot (nt*2+dh)*512 + lane*8 + j
//        = K[t=nt*16+(l&15)][d=dh*32+(l>>4)*8+j]
//   vT2: per 64x64 tile, slot (kc2*4+ct)*512 + lane*8 + j
//        = V[d=ct*16+(l&15)][t6=kc2*32+(j>>2)*16+(l>>4)*4+(j&3)]  (p-perm folded)
__global__ __launch_bounds__(256, 3)
void gemm_qkv(const bf16_t* __restrict__ A, const bf16_t* __restrict__ Bw,
              const float* __restrict__ bias,
              bf16_t* __restrict__ qk, bf16_t* __restrict__ kT,
              bf16_t* __restrict__ vT2) {
    constexpr int K = 1024;
    __shared__ bf16_t lA[3][128 * 32];
    __shared__ bf16_t lB[3][128 * 32];
    const int tid  = threadIdx.x;
    const int lane = tid & 63, wave = tid >> 6;
    const int quad = lane >> 4, l16 = lane & 15;
    const int wy = wave >> 1, wx = wave & 1;

    // XCD-chunked swizzle: 768 wg -> 96/XCD contiguous (768 % 8 == 0, bijective).
    const int L  = blockIdx.y * 24 + blockIdx.x;
    const int nL = (L & 7) * 96 + (L >> 3);
    const int bm = (nL / 24) * 128, bn = (nL % 24) * 128;

    const int c0 = tid, c1 = tid + 256;
    // source chunk pre-swizzle: LDS slot s of row r holds global chunk s ^ ((r>>1)&3)
    const int k0 = ((c0 & 3) ^ ((c0 >> 3) & 3)) * 8;
    const int k1 = ((c1 & 3) ^ ((c1 >> 3) & 3)) * 8;
    const bf16_t* Ap0 = A + (size_t)(bm + (c0 >> 2)) * K + k0;
    const bf16_t* Ap1 = A + (size_t)(bm + (c1 >> 2)) * K + k1;
    const bf16_t* Bp0 = Bw + (size_t)(bn + (c0 >> 2)) * K + k0;
    const bf16_t* Bp1 = Bw + (size_t)(bn + (c1 >> 2)) * K + k1;
    const int d0 = (wave * 64) * 8;          // wave-uniform dest (elems); HW adds lane*16B
    const int d1 = (256 + wave * 64) * 8;

    // read-side swizzled chunk
    const int sq8 = (quad ^ ((l16 >> 1) & 3)) * 8;

    floatx4 acc[4][4] = {};

    // prologue: stage tiles 0 and 1 (8 gll in flight)
    gll16(Ap0, &lA[0][d0]); gll16(Ap1, &lA[0][d1]);
    gll16(Bp0, &lB[0][d0]); gll16(Bp1, &lB[0][d1]);
    gll16(Ap0 + 32, &lA[1][d0]); gll16(Ap1 + 32, &lA[1][d1]);
    gll16(Bp0 + 32, &lB[1][d0]); gll16(Bp1 + 32, &lB[1][d1]);

    int cur = 0;
    for (int it = 0; it < 32; ++it) {
        if (it < 30) {
            const int kt = (it + 2) * 32;
            const int nb = cur >= 1 ? cur - 1 : 2;        // (cur+2)%3
            gll16(Ap0 + kt, &lA[nb][d0]); gll16(Ap1 + kt, &lA[nb][d1]);
            gll16(Bp0 + kt, &lB[nb][d0]); gll16(Bp1 + kt, &lB[nb][d1]);
            asm volatile("s_waitcnt vmcnt(8)" ::: "memory");
        } else if (it == 30) {
            asm volatile("s_waitcnt vmcnt(4)" ::: "memory");
        } else {
            asm volatile("s_waitcnt vmcnt(0)" ::: "memory");
        }
        __builtin_amdgcn_s_barrier();
        __builtin_amdgcn_sched_barrier(0);

        bf16x8 af[4], bfr[4];
#pragma unroll
        for (int i = 0; i < 4; i++) {
            af[i]  = *(const bf16x8*)(&lA[cur][(wy * 64 + i * 16 + l16) * 32 + sq8]);
            bfr[i] = *(const bf16x8*)(&lB[cur][(wx * 64 + i * 16 + l16) * 32 + sq8]);
        }
#pragma unroll
        for (int i = 0; i < 4; i++)
#pragma unroll
            for (int j = 0; j < 4; j++)
                acc[i][j] = __builtin_amdgcn_mfma_f32_16x16x32_bf16(af[i], bfr[j], acc[i][j], 0, 0, 0);

        __builtin_amdgcn_sched_barrier(0);
        __builtin_amdgcn_s_barrier();
        cur = cur < 2 ? cur + 1 : 0;
    }

#pragma unroll
    for (int j = 0; j < 4; j++) {
        const int n = bn + wx * 64 + j * 16 + l16;
        const float bv = bias[n];
#pragma unroll
        for (int i = 0; i < 4; i++) {
            const int mbase = bm + wy * 64 + i * 16 + quad * 4;
            const int bb = mbase >> 11;           // batch
            const int t2 = mbase & 2047;          // 4-aligned t within batch
            const int tt = t2 >> 6, t6b = t2 & 63;
            if (n < 1024) {                       // Q: row-major, QSCALE folded
#pragma unroll
                for (int r = 0; r < 4; r++) {
                    float c = (acc[i][j][r] + bv) * QSCALE;
                    qk[(size_t)(mbase + r) * 2048 + n] = (bf16_t)c;
                }
            } else if (n < 2048) {                // K -> kT fragment-linear
                const int hd = n - 1024;
                const int hh = hd >> 6, d = hd & 63;
                const size_t tb = ((size_t)((bb * 16 + hh) * 32 + tt)) * 4096
                                + (((t6b >> 4) & 3) * 2 + (d >> 5)) * 512
                                + (((d >> 3) & 3) * 16 + (t6b & 15)) * 8 + (d & 7);
                // r varies t6&15 -> stride 8 elems (16B): 4 scalar stores (as before)
#pragma unroll
                for (int r = 0; r < 4; r++)
                    kT[tb + (size_t)r * 8] = (bf16_t)(acc[i][j][r] + bv);
            } else {                              // V -> vT2 fragment-linear (p-perm folded)
                const int nn = n - 2048;
                const int hh = nn >> 6, d = nn & 63;
                const int hl2 = bb * 16 + hh;
                const int kc2 = t6b >> 5;
                const int jb  = ((t6b >> 4) & 1) * 4;
                const int ll  = ((t6b >> 2) & 3) * 16 + (d & 15);
                const size_t off = ((((size_t)(hl2 * 32 + tt)) * 2 + kc2) * 4 + (d >> 4)) * 512
                                 + ll * 8 + jb;
                bf16x4 pk;
#pragma unroll
                for (int r = 0; r < 4; r++) pk[r] = (bf16_t)(acc[i][j][r] + bv);
                *(bf16x4*)(vT2 + off) = pk;
            }
        }
    }
}

// ---------------------------------------------------------------- flash attention (S^T, split-K, LDS-FREE, coalesced)
// R5: K/V fragments are fragment-linear in memory (written by gemm_qkv), so each
// fragment is ONE coalesced base+lane*16B load from an L2-resident 8KB tile.
// No LDS, no barriers; waves independent; compiler pipelines loads across iters.
// Arithmetic identical to the verified R1 kernel (same fragments, same MFMA order).
// Grid 1024 = 32 hl x 16 qt x 2 t-halves. Block = 4 waves x 32 q-rows.
__global__ __launch_bounds__(256, 4)
void attn_kernel(const bf16_t* __restrict__ qk, const bf16_t* __restrict__ kT,
                 const bf16_t* __restrict__ vT2,
                 bf16_t* __restrict__ Opart, float* __restrict__ lpart) {
    const int tid  = threadIdx.x;
    const int lane = tid & 63, wave = tid >> 6;
    const int quad = lane >> 4, l16 = lane & 15;
    const int bid = blockIdx.x;
    const int s    = bid & 63;
    const int hl   = ((s & 7) << 2) | ((s >> 3) & 3);  // XCD-swizzle: 4 heads/XCD
    const int half = (s >> 5) & 1;
    const int qt   = bid >> 6;
    const int b = hl >> 4, h = hl & 15;

    const bf16_t* Qbase = qk + (size_t)(b * 2048 + qt * 128 + wave * 32) * 2048 + h * 64;
    const bf16_t* Ktile = kT  + ((size_t)(hl * 32 + half * 16)) * 4096 + lane * 8;
    const bf16_t* Vtile = vT2 + ((size_t)(hl * 32 + half * 16)) * 4096 + lane * 8;

    bf16x8 qf[2][2];  // B-operand: n = q = l16, k = kc*32 + quad*8
#pragma unroll
    for (int rt = 0; rt < 2; rt++)
#pragma unroll
        for (int kc = 0; kc < 2; kc++)
            qf[rt][kc] = *(const bf16x8*)(Qbase + (size_t)(rt * 16 + l16) * 2048 + kc * 32 + quad * 8);

    floatx4 accO[2][4] = {};    // O[q=quad*4+r][d=ct*16+l16]
    float lacc[2] = {0.f, 0.f};

    for (int it = 0; it < 16; ++it) {
        const bf16_t* kt_ = Ktile + it * 4096;
        const bf16_t* vt_ = Vtile + it * 4096;
        // S^T = K.Q^T : rows t (quad*4+r per nt-tile), cols q (l16)
        floatx4 st[2][4] = {};
#pragma unroll
        for (int nt = 0; nt < 4; nt++) {
            bf16x8 kf0 = *(const bf16x8*)(kt_ + nt * 1024);
            bf16x8 kf1 = *(const bf16x8*)(kt_ + nt * 1024 + 512);
            __builtin_amdgcn_s_setprio(1);
            st[0][nt] = __builtin_amdgcn_mfma_f32_16x16x32_bf16(kf0, qf[0][0], st[0][nt], 0, 0, 0);
            st[0][nt] = __builtin_amdgcn_mfma_f32_16x16x32_bf16(kf1, qf[0][1], st[0][nt], 0, 0, 0);
            st[1][nt] = __builtin_amdgcn_mfma_f32_16x16x32_bf16(kf0, qf[1][0], st[1][nt], 0, 0, 0);
            st[1][nt] = __builtin_amdgcn_mfma_f32_16x16x32_bf16(kf1, qf[1][1], st[1][nt], 0, 0, 0);
            __builtin_amdgcn_s_setprio(0);
        }
        // per t-half: V frags coalesced from L2; P frags built in-register
#pragma unroll
        for (int kc2 = 0; kc2 < 2; kc2++) {
            bf16x8 vf[4];
#pragma unroll
            for (int ct = 0; ct < 4; ct++)
                vf[ct] = *(const bf16x8*)(vt_ + (kc2 * 4 + ct) * 512);
#pragma unroll
            for (int rt = 0; rt < 2; rt++) {
                float p[8];
                float ls = 0.f;
#pragma unroll
                for (int j = 0; j < 8; j++) {
                    p[j] = __builtin_amdgcn_exp2f(st[rt][kc2 * 2 + (j >> 2)][j & 3]);
                    ls += p[j];
                }
                lacc[rt] += ls;
                bf16x8 pf = pack8(p);
                __builtin_amdgcn_s_setprio(1);
#pragma unroll
                for (int ct = 0; ct < 4; ct++)
                    accO[rt][ct] = __builtin_amdgcn_mfma_f32_16x16x32_bf16(pf, vf[ct], accO[rt][ct], 0, 0, 0);
                __builtin_amdgcn_s_setprio(0);
            }
        }
    }

    // partial l
    float lsum[2];
#pragma unroll
    for (int rt = 0; rt < 2; rt++) {
        float l = lacc[rt];
        l += __shfl_xor(l, 16);
        l += __shfl_xor(l, 32);
        lsum[rt] = l;
    }
    // partial O with "faithful bug" permutation: dest row (hl&1)*2048 + t, col (hl>>1)*64 + d
    const int b2 = hl & 1;
    const int colb = hl >> 1;
    const int rowb = b2 * 2048 + qt * 128 + wave * 32;
    bf16_t* outb = Opart + (size_t)half * (4096 * 1024) + (size_t)rowb * 1024 + colb * 64;
#pragma unroll
    for (int rt = 0; rt < 2; rt++)
#pragma unroll
        for (int ct = 0; ct < 4; ct++)
#pragma unroll
            for (int r = 0; r < 4; r++)
                outb[(size_t)(rt * 16 + quad * 4 + r) * 1024 + ct * 16 + l16] = (bf16_t)(accO[rt][ct][r]);
    if (quad == 0) {
#pragma unroll
        for (int rt = 0; rt < 2; rt++)
            lpart[half * 65536 + (rowb + rt * 16 + l16) * 16 + colb] = lsum[rt];
    }
}

// ---------------------------------------------------------------- O GEMM, double-buffered, fused split-K combine
__global__ __launch_bounds__(256, 4)
void gemm_o(const bf16_t* __restrict__ Op, const float* __restrict__ lp,
            const bf16_t* __restrict__ Bw, bf16_t* __restrict__ out) {
    constexpr int K = 1024;
    __shared__ bf16_t lA[2][64 * 32];    // 2 x 4 KB
    __shared__ bf16_t lB[2][128 * 32];   // 2 x 8 KB
    const int tid  = threadIdx.x;
    const int lane = tid & 63, wave = tid >> 6;
    const int quad = lane >> 4, l16 = lane & 15;
    const int wy = wave >> 1, wx = wave & 1;   // wave tile: 32m x 64n
    const int bm = blockIdx.y * 64, bn = blockIdx.x * 128;

    const int ca = tid;                         // A: 64 rows x 4 chunks
    const int arow = bm + (ca >> 2);
    const int ak   = (ca & 3) * 8;
    const int aslot = ((ca & 3) ^ ((ca >> 3) & 3));
    const int awr   = ((ca >> 2) * 4 + aslot) * 8;
    const bf16_t* Ap0 = Op + (size_t)arow * 1024 + ak;
    const bf16_t* Ap1 = Ap0 + (size_t)4096 * 1024;
    const float*  lrow = lp + arow * 16;
    const int cb0 = tid, cb1 = tid + 256;       // B: 128 rows x 4 chunks
    const int bk0 = ((cb0 & 3) ^ ((cb0 >> 3) & 3)) * 8;
    const int bk1 = ((cb1 & 3) ^ ((cb1 >> 3) & 3)) * 8;
    const bf16_t* Bp0 = Bw + (size_t)(bn + (cb0 >> 2)) * K + bk0;
    const bf16_t* Bp1 = Bw + (size_t)(bn + (cb1 >> 2)) * K + bk1;
    const int d0 = (wave * 64) * 8;
    const int d1 = (256 + wave * 64) * 8;

    const int xq8 = (quad ^ ((l16 >> 1) & 3)) * 8;

    // prologue: stage tile 0 (A combine + B gll)
    gll16(Bp0, &lB[0][d0]);
    gll16(Bp1, &lB[0][d1]);
    {
        bf16x8 a0 = *(const bf16x8*)(Ap0);
        bf16x8 a1 = *(const bf16x8*)(Ap1);
        const float inv = 1.0f / (lrow[ak >> 6] + lrow[65536 + (ak >> 6)]);
        float p[8];
#pragma unroll
        for (int j = 0; j < 8; j++) p[j] = ((float)a0[j] + (float)a1[j]) * inv;
        *(bf16x8*)&lA[0][awr] = pack8(p);
    }

    floatx4 acc[2][4] = {};
    for (int it = 0; it < 32; ++it) {
        const int cur = it & 1, nxt = cur ^ 1;
        __syncthreads();                    // drains gll + lA writes -> [cur] ready
        bf16x8 na0, na1;
        int kt1 = (it + 1) * 32;
        if (it < 31) {
            na0 = *(const bf16x8*)(Ap0 + kt1);
            na1 = *(const bf16x8*)(Ap1 + kt1);
            gll16(Bp0 + kt1, &lB[nxt][d0]);
            gll16(Bp1 + kt1, &lB[nxt][d1]);
        }
        bf16x8 af[2], bfr[4];
#pragma unroll
        for (int i = 0; i < 2; i++)
            af[i] = *(const bf16x8*)(&lA[cur][(wy * 32 + i * 16 + l16) * 32 + xq8]);
#pragma unroll
        for (int j = 0; j < 4; j++)
            bfr[j] = *(const bf16x8*)(&lB[cur][(wx * 64 + j * 16 + l16) * 32 + xq8]);
#pragma unroll
        for (int i = 0; i < 2; i++)
#pragma unroll
            for (int j = 0; j < 4; j++)
                acc[i][j] = __builtin_amdgcn_mfma_f32_16x16x32_bf16(af[i], bfr[j], acc[i][j], 0, 0, 0);
        if (it < 31) {                      // combine after MFMA phase (na latency hidden)
            const int cb = (kt1 + ak) >> 6;
            const float inv = 1.0f / (lrow[cb] + lrow[65536 + cb]);
            float p[8];
#pragma unroll
            for (int j = 0; j < 8; j++) p[j] = ((float)na0[j] + (float)na1[j]) * inv;
            *(bf16x8*)&lA[nxt][awr] = pack8(p);
        }
    }
#pragma unroll
    for (int j = 0; j < 4; j++) {
        const int n = bn + wx * 64 + j * 16 + l16;
#pragma unroll
        for (int i = 0; i < 2; i++) {
            const int mbase = bm + wy * 32 + i * 16 + quad * 4;
#pragma unroll
            for (int r = 0; r < 4; r++)
                out[(size_t)(mbase + r) * 1024 + n] = (bf16_t)acc[i][j][r];
        }
    }
}

// ---------------------------------------------------------------- residual + LayerNorm (ao in bf16)
__global__ __launch_bounds__(256)
void ln_kernel(const float* __restrict__ inp, const bf16_t* __restrict__ ao,
               const float* __restrict__ gamma, const float* __restrict__ beta,
               float* __restrict__ out) {
    const int row = blockIdx.x, tid = threadIdx.x;
    const int wave = tid >> 6, lane = tid & 63;
    float4 a = ((const float4*)(inp + (size_t)row * 1024))[tid];
    bf16x4 c4 = ((const bf16x4*)(ao + (size_t)row * 1024))[tid];
    float x0 = a.x + (float)c4[0], x1 = a.y + (float)c4[1];
    float x2 = a.z + (float)c4[2], x3 = a.w + (float)c4[3];
    float s = x0 + x1 + x2 + x3;
    float sq = x0 * x0 + x1 * x1 + x2 * x2 + x3 * x3;
#pragma unroll
    for (int mm = 32; mm >= 1; mm >>= 1) {
        s += __shfl_xor(s, mm);
        sq += __shfl_xor(sq, mm);
    }
    __shared__ float rs[4], rq[4];
    if (lane == 0) { rs[wave] = s; rq[wave] = sq; }
    __syncthreads();
    s = rs[0] + rs[1] + rs[2] + rs[3];
    sq = rq[0] + rq[1] + rq[2] + rq[3];
    const float mu = s * (1.0f / 1024.0f);
    const float var = sq * (1.0f / 1024.0f) - mu * mu;
    const float rstd = rsqrtf(var + 1e-5f);
    float4 g = ((const float4*)gamma)[tid], bt = ((const float4*)beta)[tid];
    float4 o;
    o.x = (x0 - mu) * rstd * g.x + bt.x;
    o.y = (x1 - mu) * rstd * g.y + bt.y;
    o.z = (x2 - mu) * rstd * g.z + bt.z;
    o.w = (x3 - mu) * rstd * g.w + bt.w;
    ((float4*)(out + (size_t)row * 1024))[tid] = o;
}

// ---------------------------------------------------------------- launch
extern "C" void kernel_launch(void* const* d_in, const int* in_sizes, int n_in,
                              void* d_out, int out_size, void* d_ws, size_t ws_size,
                              hipStream_t stream) {
    const float* inp   = (const float*)d_in[0];
    const float* Wqkv  = (const float*)d_in[1];
    const float* bqkv  = (const float*)d_in[2];
    const float* Wo    = (const float*)d_in[3];
    const float* gamma = (const float*)d_in[4];
    const float* beta  = (const float*)d_in[5];
    float* out = (float*)d_out;

    // workspace layout (64 MB):
    //  0- 8 : inp_bf   (dead after gemm_qkv)  -> lpart overlay (512 KB, attn)
    //  8-14 : wqkv_bf  (dead after gemm_qkv)
    // 14-16 : wo_bf    (live until gemm_o)
    // 16-32 : qk_buf   (Q rows; dead after attn)
    // 32-40 : vT2_buf  (dead after attn)      -> ao_bf overlay (8 MB, gemm_o out)
    // 40-48 : kT_buf   (dead after attn)
    // 48-64 : opart    (2 x 8 MB, attn out, read by gemm_o)
    char* ws = (char*)d_ws;
    bf16_t* inp_bf  = (bf16_t*)(ws);
    bf16_t* wqkv_bf = (bf16_t*)(ws + (8u << 20));
    bf16_t* wo_bf   = (bf16_t*)(ws + (14u << 20));
    bf16_t* qk_buf  = (bf16_t*)(ws + (16u << 20));
    bf16_t* vT2_buf = (bf16_t*)(ws + (32u << 20));
    bf16_t* ao_bf   = (bf16_t*)(ws + (32u << 20));
    bf16_t* kT_buf  = (bf16_t*)(ws + (40u << 20));
    bf16_t* opart   = (bf16_t*)(ws + (48u << 20));
    float*  lpart   = (float*)(ws);

    cvt_all<<<8192, 256, 0, stream>>>(inp, Wqkv, Wo, inp_bf, wqkv_bf, wo_bf);
    gemm_qkv<<<dim3(24, 32), 256, 0, stream>>>(inp_bf, wqkv_bf, bqkv, qk_buf, kT_buf, vT2_buf);
    attn_kernel<<<1024, 256, 0, stream>>>(qk_buf, kT_buf, vT2_buf, opart, lpart);
    gemm_o<<<dim3(8, 64), 256, 0, stream>>>(opart, lpart, wo_bf, ao_bf);
    ln_kernel<<<4096, 256, 0, stream>>>(inp, ao_bf, gamma, beta, out);
}

// Round 7
// 204.381 us; speedup vs baseline: 1.3739x; 1.0136x over previous
//
#include <hip/hip_runtime.h>
#include <hip/hip_bf16.h>
#include <stdint.h>

typedef __bf16 bf16_t;
typedef __bf16 bf16x8 __attribute__((ext_vector_type(8)));
typedef __bf16 bf16x4 __attribute__((ext_vector_type(4)));
typedef __bf16 bf16x2 __attribute__((ext_vector_type(2)));
typedef float floatx4 __attribute__((ext_vector_type(4)));

#define QSCALE 0.180336879f  /* 0.125 * log2(e) : fold score scale + exp2 domain into Q */

#if __has_builtin(__builtin_amdgcn_cvt_pk_bf16_f32)
#define HAS_PK_BF16 1
#endif

__device__ static inline void gll16(const void* g, void* l) {
    __builtin_amdgcn_global_load_lds((const __attribute__((address_space(1))) void*)g,
                                     (__attribute__((address_space(3))) void*)l, 16, 0, 0);
}

__device__ static inline bf16x8 pack8(const float* p) {
    bf16x8 o;
#ifdef HAS_PK_BF16
#pragma unroll
    for (int j = 0; j < 4; j++) {
        bf16x2 t2 = __builtin_amdgcn_cvt_pk_bf16_f32(p[2 * j], p[2 * j + 1]);
        o[2 * j] = t2[0]; o[2 * j + 1] = t2[1];
    }
#else
#pragma unroll
    for (int j = 0; j < 8; j++) o[j] = (bf16_t)p[j];
#endif
    return o;
}

// ---------------------------------------------------------------- fp32 -> bf16 (fused: inp, Wqkv, Wo)
__global__ __launch_bounds__(256) void cvt_all(const float* __restrict__ inp,
                                               const float* __restrict__ wqkv,
                                               const float* __restrict__ wo,
                                               bf16_t* __restrict__ o_inp,
                                               bf16_t* __restrict__ o_wqkv,
                                               bf16_t* __restrict__ o_wo) {
    int blk = blockIdx.x;
    const float* src;
    bf16_t* dst;
    if (blk < 4096)      { src = inp;  dst = o_inp; }
    else if (blk < 7168) { src = wqkv; dst = o_wqkv; blk -= 4096; }
    else                 { src = wo;   dst = o_wo;   blk -= 7168; }
    int i = blk * 256 + threadIdx.x;
    float4 v = ((const float4*)src)[i];
    float p[4] = {v.x, v.y, v.z, v.w};
    bf16x4 o;
#ifdef HAS_PK_BF16
    bf16x2 t0 = __builtin_amdgcn_cvt_pk_bf16_f32(p[0], p[1]);
    bf16x2 t1 = __builtin_amdgcn_cvt_pk_bf16_f32(p[2], p[3]);
    o[0] = t0[0]; o[1] = t0[1]; o[2] = t1[0]; o[3] = t1[1];
#else
    o[0] = (bf16_t)p[0]; o[1] = (bf16_t)p[1]; o[2] = (bf16_t)p[2]; o[3] = (bf16_t)p[3];
#endif
    ((bf16x4*)dst)[i] = o;
}

// ---------------------------------------------------------------- QKV GEMM
// R1 pipeline: depth-2 prefetch (3 LDS buffers), counted vmcnt + raw barriers,
// chunk-XOR LDS swizzle, XCD-chunked block swizzle.
// R6: epilogue routed through LDS -> fully coalesced b128 stores (was 64
// scalar bf16 stores/thread; WRITE_SIZE showed 1.8x amplification).
// vT columns are t-PERMUTED within each 32-group: p = (t&~31) | q*8 | h*4 | r.
__global__ __launch_bounds__(256, 3)
void gemm_qkv(const bf16_t* __restrict__ A, const bf16_t* __restrict__ Bw,
              const float* __restrict__ bias,
              bf16_t* __restrict__ qk, bf16_t* __restrict__ vT) {
    constexpr int K = 1024;
    __shared__ bf16_t sm[24576];                 // 48 KB: lA[3] | lB[3]; epi overlay 128x136
#define LA(b) (sm + (b) * 4096)
#define LB(b) (sm + 12288 + (b) * 4096)
    const int tid  = threadIdx.x;
    const int lane = tid & 63, wave = tid >> 6;
    const int quad = lane >> 4, l16 = lane & 15;
    const int wy = wave >> 1, wx = wave & 1;

    // XCD-chunked swizzle: 768 wg -> 96/XCD contiguous (768 % 8 == 0, bijective).
    const int L  = blockIdx.y * 24 + blockIdx.x;
    const int nL = (L & 7) * 96 + (L >> 3);
    const int bm = (nL / 24) * 128, bn = (nL % 24) * 128;

    const int c0 = tid, c1 = tid + 256;
    const int k0 = ((c0 & 3) ^ ((c0 >> 3) & 3)) * 8;
    const int k1 = ((c1 & 3) ^ ((c1 >> 3) & 3)) * 8;
    const bf16_t* Ap0 = A + (size_t)(bm + (c0 >> 2)) * K + k0;
    const bf16_t* Ap1 = A + (size_t)(bm + (c1 >> 2)) * K + k1;
    const bf16_t* Bp0 = Bw + (size_t)(bn + (c0 >> 2)) * K + k0;
    const bf16_t* Bp1 = Bw + (size_t)(bn + (c1 >> 2)) * K + k1;
    const int d0 = (wave * 64) * 8;          // wave-uniform dest (elems); HW adds lane*16B
    const int d1 = (256 + wave * 64) * 8;

    const int sq8 = (quad ^ ((l16 >> 1) & 3)) * 8;

    floatx4 acc[4][4] = {};

    // prologue: stage tiles 0 and 1 (8 gll in flight)
    gll16(Ap0, LA(0) + d0); gll16(Ap1, LA(0) + d1);
    gll16(Bp0, LB(0) + d0); gll16(Bp1, LB(0) + d1);
    gll16(Ap0 + 32, LA(1) + d0); gll16(Ap1 + 32, LA(1) + d1);
    gll16(Bp0 + 32, LB(1) + d0); gll16(Bp1 + 32, LB(1) + d1);

    int cur = 0;
    for (int it = 0; it < 32; ++it) {
        if (it < 30) {
            const int kt = (it + 2) * 32;
            const int nb = cur >= 1 ? cur - 1 : 2;        // (cur+2)%3
            gll16(Ap0 + kt, LA(nb) + d0); gll16(Ap1 + kt, LA(nb) + d1);
            gll16(Bp0 + kt, LB(nb) + d0); gll16(Bp1 + kt, LB(nb) + d1);
            asm volatile("s_waitcnt vmcnt(8)" ::: "memory");
        } else if (it == 30) {
            asm volatile("s_waitcnt vmcnt(4)" ::: "memory");
        } else {
            asm volatile("s_waitcnt vmcnt(0)" ::: "memory");
        }
        __builtin_amdgcn_s_barrier();
        __builtin_amdgcn_sched_barrier(0);

        bf16x8 af[4], bfr[4];
#pragma unroll
        for (int i = 0; i < 4; i++) {
            af[i]  = *(const bf16x8*)(LA(cur) + (wy * 64 + i * 16 + l16) * 32 + sq8);
            bfr[i] = *(const bf16x8*)(LB(cur) + (wx * 64 + i * 16 + l16) * 32 + sq8);
        }
#pragma unroll
        for (int i = 0; i < 4; i++)
#pragma unroll
            for (int j = 0; j < 4; j++)
                acc[i][j] = __builtin_amdgcn_mfma_f32_16x16x32_bf16(af[i], bfr[j], acc[i][j], 0, 0, 0);

        __builtin_amdgcn_sched_barrier(0);
        __builtin_amdgcn_s_barrier();
        cur = cur < 2 ? cur + 1 : 0;
    }

    // -------- epilogue through LDS (coalesced b128 stores) --------
    __syncthreads();                             // all LDS reads of K-loop drained
    const bool is_v = (bn >= 2048);
    if (!is_v) {
#pragma unroll
        for (int j = 0; j < 4; j++) {
            const int n = bn + wx * 64 + j * 16 + l16;
            const float bv = bias[n];
            const bool isq = (n < 1024);
            const int nl = wx * 64 + j * 16 + l16;
#pragma unroll
            for (int i = 0; i < 4; i++) {
                const int mm = wy * 64 + i * 16 + quad * 4;
#pragma unroll
                for (int r = 0; r < 4; r++) {
                    float c = acc[i][j][r] + bv;
                    if (isq) c *= QSCALE;
                    sm[(mm + r) * 136 + nl] = (bf16_t)c;
                }
            }
        }
        __syncthreads();
#pragma unroll
        for (int k = 0; k < 8; k++) {
            const int row = wave * 32 + k * 4 + (lane >> 4);
            const int col = (lane & 15) * 8;
            bf16x8 v = *(const bf16x8*)&sm[row * 136 + col];
            *(bf16x8*)(qk + (size_t)(bm + row) * 2048 + bn + col) = v;
        }
    } else {
#pragma unroll
        for (int j = 0; j < 4; j++) {
            const int n = bn + wx * 64 + j * 16 + l16;
            const float bv = bias[n];
            const int rr = wx * 64 + j * 16 + l16;   // n-local = vT-tile row
#pragma unroll
            for (int i = 0; i < 4; i++) {
                const int mm = wy * 64 + i * 16 + quad * 4;   // t-local, 4-aligned
                const int ccL = (mm & ~31) | (((mm >> 2) & 3) << 3) | (((mm >> 4) & 1) << 2);
                bf16x4 pk;
#pragma unroll
                for (int r = 0; r < 4; r++) pk[r] = (bf16_t)(acc[i][j][r] + bv);
                *(bf16x4*)&sm[rr * 136 + ccL] = pk;
            }
        }
        __syncthreads();
        const int vrow0 = (bm >> 11) * 1024 + (bn - 2048);
        const int tcol0 = bm & 2047;
#pragma unroll
        for (int k = 0; k < 8; k++) {
            const int row = wave * 32 + k * 4 + (lane >> 4);
            const int col = (lane & 15) * 8;
            bf16x8 v = *(const bf16x8*)&sm[row * 136 + col];
            *(bf16x8*)(vT + (size_t)(vrow0 + row) * 2048 + tcol0 + col) = v;
        }
    }
#undef LA
#undef LB
}

// ---------------------------------------------------------------- flash attention (S^T, split-K, gll-staged K/V)
// Exact R1 structure (best measured: 43.2 us): 2 LDS buffers, one __syncthreads
// per iter with prefetch-after-barrier, chunk-XOR swizzle, no setprio.
// R6: Opart epilogue through LDS -> coalesced b128 stores (was 32 scalar/thread).
// Grid 1024 = 32 hl x 16 qt x 2 t-halves. Block = 4 waves x 32 q-rows.
__global__ __launch_bounds__(256, 4)
void attn_kernel(const bf16_t* __restrict__ qk, const bf16_t* __restrict__ vT,
                 bf16_t* __restrict__ Opart, float* __restrict__ lpart) {
    __shared__ bf16_t sm[16384];                 // 32 KB: Kbuf[2] | Vbuf[2]; epi overlay 128x72
#define KBUF(b) (sm + (b) * 4096)
#define VBUF(b) (sm + 8192 + (b) * 4096)
    const int tid  = threadIdx.x;
    const int lane = tid & 63, wave = tid >> 6;
    const int quad = lane >> 4, l16 = lane & 15;
    const int bid = blockIdx.x;
    const int s    = bid & 63;
    const int hl   = ((s & 7) << 2) | ((s >> 3) & 3);  // XCD-swizzle: 4 heads/XCD
    const int half = (s >> 5) & 1;
    const int qt   = bid >> 6;
    const int b = hl >> 4, h = hl & 15;
    const int kt0 = half * 1024;

    const bf16_t* Qbase = qk + (size_t)(b * 2048 + qt * 128 + wave * 32) * 2048 + h * 64;
    const bf16_t* Kbase = qk + (size_t)(b * 2048) * 2048 + 1024 + h * 64;
    const bf16_t* Vbase = vT + (size_t)(hl * 64) * 2048;

    const int srow = tid >> 2;
    const int sc8 = ((tid & 3) ^ ((tid >> 3) & 3)) * 8;
    const bf16_t* KgA = Kbase + (size_t)(kt0 + srow) * 2048 + sc8;   // d 0..31
    const bf16_t* KgB = KgA + 32;                                     // d 32..63
    const bf16_t* VgA = Vbase + (size_t)srow * 2048 + kt0 + sc8;     // t-half 0 (p-cols)
    const bf16_t* VgB = VgA + 32;                                     // t-half 1
    const int wbase = wave * 512;   // wave-uniform LDS dest; HW adds lane*16B

    const int xq8 = (quad ^ ((l16 >> 1) & 3)) * 8;

    bf16x8 qf[2][2];  // B-operand: n = q = l16, k = kc*32 + quad*8
#pragma unroll
    for (int rt = 0; rt < 2; rt++)
#pragma unroll
        for (int kc = 0; kc < 2; kc++)
            qf[rt][kc] = *(const bf16x8*)(Qbase + (size_t)(rt * 16 + l16) * 2048 + kc * 32 + quad * 8);

    floatx4 accO[2][4] = {};    // O[q=quad*4+r][d=ct*16+l16]
    float lacc[2] = {0.f, 0.f};

    gll16(KgA, KBUF(0) + wbase);
    gll16(KgB, KBUF(0) + 2048 + wbase);
    gll16(VgA, VBUF(0) + wbase);
    gll16(VgB, VBUF(0) + 2048 + wbase);

    for (int it = 0; it < 16; ++it) {
        const int cur = it & 1, nxt = cur ^ 1;
        __syncthreads();   // drains gll -> buf[cur] ready
        if (it < 15) {
            const size_t ko = (size_t)(it + 1) * 64 * 2048;
            const int    vo = (it + 1) * 64;
            gll16(KgA + ko, KBUF(nxt) + wbase);
            gll16(KgB + ko, KBUF(nxt) + 2048 + wbase);
            gll16(VgA + vo, VBUF(nxt) + wbase);
            gll16(VgB + vo, VBUF(nxt) + 2048 + wbase);
        }
        // S^T = K.Q^T : rows t (quad*4+r per nt-tile), cols q (l16)
        floatx4 st[2][4] = {};
#pragma unroll
        for (int nt = 0; nt < 4; nt++) {
            bf16x8 k0 = *(const bf16x8*)(KBUF(cur) + (nt * 16 + l16) * 32 + xq8);
            bf16x8 k1 = *(const bf16x8*)(KBUF(cur) + 2048 + (nt * 16 + l16) * 32 + xq8);
            st[0][nt] = __builtin_amdgcn_mfma_f32_16x16x32_bf16(k0, qf[0][0], st[0][nt], 0, 0, 0);
            st[0][nt] = __builtin_amdgcn_mfma_f32_16x16x32_bf16(k1, qf[0][1], st[0][nt], 0, 0, 0);
            st[1][nt] = __builtin_amdgcn_mfma_f32_16x16x32_bf16(k0, qf[1][0], st[1][nt], 0, 0, 0);
            st[1][nt] = __builtin_amdgcn_mfma_f32_16x16x32_bf16(k1, qf[1][1], st[1][nt], 0, 0, 0);
        }
        // per t-half: V frags once; P frags built in-register (permuted t-order)
#pragma unroll
        for (int kc2 = 0; kc2 < 2; kc2++) {
            bf16x8 vf[4];
#pragma unroll
            for (int ct = 0; ct < 4; ct++)
                vf[ct] = *(const bf16x8*)(VBUF(cur) + kc2 * 2048 + (ct * 16 + l16) * 32 + xq8);
#pragma unroll
            for (int rt = 0; rt < 2; rt++) {
                float p[8];
                float ls = 0.f;
#pragma unroll
                for (int j = 0; j < 8; j++) {
                    p[j] = __builtin_amdgcn_exp2f(st[rt][kc2 * 2 + (j >> 2)][j & 3]);
                    ls += p[j];
                }
                lacc[rt] += ls;
                bf16x8 pf = pack8(p);
#pragma unroll
                for (int ct = 0; ct < 4; ct++)
                    accO[rt][ct] = __builtin_amdgcn_mfma_f32_16x16x32_bf16(pf, vf[ct], accO[rt][ct], 0, 0, 0);
            }
        }
    }

    // partial l
    float lsum[2];
#pragma unroll
    for (int rt = 0; rt < 2; rt++) {
        float l = lacc[rt];
        l += __shfl_xor(l, 16);
        l += __shfl_xor(l, 32);
        lsum[rt] = l;
    }
    // -------- epilogue through LDS (coalesced b128 stores) --------
    // "faithful bug" permutation: dest row (hl&1)*2048 + t, col (hl>>1)*64 + d
    const int b2 = hl & 1;
    const int colb = hl >> 1;
    const int rowb  = b2 * 2048 + qt * 128 + wave * 32;   // for lpart (unchanged)
    const int rowb0 = b2 * 2048 + qt * 128;               // block base
    __syncthreads();                             // all LDS reads of K/V loop drained
#pragma unroll
    for (int rt = 0; rt < 2; rt++)
#pragma unroll
        for (int ct = 0; ct < 4; ct++)
#pragma unroll
            for (int r = 0; r < 4; r++)
                sm[(wave * 32 + rt * 16 + quad * 4 + r) * 72 + ct * 16 + l16] =
                    (bf16_t)(accO[rt][ct][r]);
    if (quad == 0) {
#pragma unroll
        for (int rt = 0; rt < 2; rt++)
            lpart[half * 65536 + (rowb + rt * 16 + l16) * 16 + colb] = lsum[rt];
    }
    __syncthreads();
    bf16_t* outb = Opart + (size_t)half * (4096 * 1024) + (size_t)rowb0 * 1024 + colb * 64;
#pragma unroll
    for (int k = 0; k < 4; k++) {
        const int row = wave * 32 + k * 8 + (lane >> 3);
        const int col = (lane & 7) * 8;
        bf16x8 v = *(const bf16x8*)&sm[row * 72 + col];
        *(bf16x8*)(outb + (size_t)row * 1024 + col) = v;
    }
#undef KBUF
#undef VBUF
}

// ---------------------------------------------------------------- O GEMM, double-buffered, fused split-K combine
// R1 structure; R6: out epilogue through LDS -> coalesced b128 stores.
__global__ __launch_bounds__(256, 4)
void gemm_o(const bf16_t* __restrict__ Op, const float* __restrict__ lp,
            const bf16_t* __restrict__ Bw, bf16_t* __restrict__ out) {
    constexpr int K = 1024;
    __shared__ bf16_t sm[12288];                 // 24 KB: lA[2](2x2048) | lB[2](2x4096); epi 64x136
#define LA(b) (sm + (b) * 2048)
#define LB(b) (sm + 4096 + (b) * 4096)
    const int tid  = threadIdx.x;
    const int lane = tid & 63, wave = tid >> 6;
    const int quad = lane >> 4, l16 = lane & 15;
    const int wy = wave >> 1, wx = wave & 1;   // wave tile: 32m x 64n
    const int bm = blockIdx.y * 64, bn = blockIdx.x * 128;

    const int ca = tid;                         // A: 64 rows x 4 chunks
    const int arow = bm + (ca >> 2);
    const int ak   = (ca & 3) * 8;
    const int aslot = ((ca & 3) ^ ((ca >> 3) & 3));
    const int awr   = ((ca >> 2) * 4 + aslot) * 8;
    const bf16_t* Ap0 = Op + (size_t)arow * 1024 + ak;
    const bf16_t* Ap1 = Ap0 + (size_t)4096 * 1024;
    const float*  lrow = lp + arow * 16;
    const int cb0 = tid, cb1 = tid + 256;       // B: 128 rows x 4 chunks
    const int bk0 = ((cb0 & 3) ^ ((cb0 >> 3) & 3)) * 8;
    const int bk1 = ((cb1 & 3) ^ ((cb1 >> 3) & 3)) * 8;
    const bf16_t* Bp0 = Bw + (size_t)(bn + (cb0 >> 2)) * K + bk0;
    const bf16_t* Bp1 = Bw + (size_t)(bn + (cb1 >> 2)) * K + bk1;
    const int d0 = (wave * 64) * 8;
    const int d1 = (256 + wave * 64) * 8;

    const int xq8 = (quad ^ ((l16 >> 1) & 3)) * 8;

    // prologue: stage tile 0 (A combine + B gll)
    gll16(Bp0, LB(0) + d0);
    gll16(Bp1, LB(0) + d1);
    {
        bf16x8 a0 = *(const bf16x8*)(Ap0);
        bf16x8 a1 = *(const bf16x8*)(Ap1);
        const float inv = 1.0f / (lrow[ak >> 6] + lrow[65536 + (ak >> 6)]);
        float p[8];
#pragma unroll
        for (int j = 0; j < 8; j++) p[j] = ((float)a0[j] + (float)a1[j]) * inv;
        *(bf16x8*)(LA(0) + awr) = pack8(p);
    }

    floatx4 acc[2][4] = {};
    for (int it = 0; it < 32; ++it) {
        const int cur = it & 1, nxt = cur ^ 1;
        __syncthreads();                    // drains gll + lA writes -> [cur] ready
        bf16x8 na0, na1;
        int kt1 = (it + 1) * 32;
        if (it < 31) {
            na0 = *(const bf16x8*)(Ap0 + kt1);
            na1 = *(const bf16x8*)(Ap1 + kt1);
            gll16(Bp0 + kt1, LB(nxt) + d0);
            gll16(Bp1 + kt1, LB(nxt) + d1);
        }
        bf16x8 af[2], bfr[4];
#pragma unroll
        for (int i = 0; i < 2; i++)
            af[i] = *(const bf16x8*)(LA(cur) + (wy * 32 + i * 16 + l16) * 32 + xq8);
#pragma unroll
        for (int j = 0; j < 4; j++)
            bfr[j] = *(const bf16x8*)(LB(cur) + (wx * 64 + j * 16 + l16) * 32 + xq8);
#pragma unroll
        for (int i = 0; i < 2; i++)
#pragma unroll
            for (int j = 0; j < 4; j++)
                acc[i][j] = __builtin_amdgcn_mfma_f32_16x16x32_bf16(af[i], bfr[j], acc[i][j], 0, 0, 0);
        if (it < 31) {                      // combine after MFMA phase (na latency hidden)
            const int cb = (kt1 + ak) >> 6;
            const float inv = 1.0f / (lrow[cb] + lrow[65536 + cb]);
            float p[8];
#pragma unroll
            for (int j = 0; j < 8; j++) p[j] = ((float)na0[j] + (float)na1[j]) * inv;
            *(bf16x8*)(LA(nxt) + awr) = pack8(p);
        }
    }

    // -------- epilogue through LDS (coalesced b128 stores) --------
    __syncthreads();
#pragma unroll
    for (int j = 0; j < 4; j++) {
        const int nl = wx * 64 + j * 16 + l16;
#pragma unroll
        for (int i = 0; i < 2; i++) {
            const int mm = wy * 32 + i * 16 + quad * 4;
#pragma unroll
            for (int r = 0; r < 4; r++)
                sm[(mm + r) * 136 + nl] = (bf16_t)acc[i][j][r];
        }
    }
    __syncthreads();
#pragma unroll
    for (int k = 0; k < 4; k++) {
        const int row = wave * 16 + k * 4 + (lane >> 4);
        const int col = (lane & 15) * 8;
        bf16x8 v = *(const bf16x8*)&sm[row * 136 + col];
        *(bf16x8*)(out + (size_t)(bm + row) * 1024 + bn + col) = v;
    }
#undef LA
#undef LB
}

// ---------------------------------------------------------------- residual + LayerNorm (ao in bf16)
__global__ __launch_bounds__(256)
void ln_kernel(const float* __restrict__ inp, const bf16_t* __restrict__ ao,
               const float* __restrict__ gamma, const float* __restrict__ beta,
               float* __restrict__ out) {
    const int row = blockIdx.x, tid = threadIdx.x;
    const int wave = tid >> 6, lane = tid & 63;
    float4 a = ((const float4*)(inp + (size_t)row * 1024))[tid];
    bf16x4 c4 = ((const bf16x4*)(ao + (size_t)row * 1024))[tid];
    float x0 = a.x + (float)c4[0], x1 = a.y + (float)c4[1];
    float x2 = a.z + (float)c4[2], x3 = a.w + (float)c4[3];
    float s = x0 + x1 + x2 + x3;
    float sq = x0 * x0 + x1 * x1 + x2 * x2 + x3 * x3;
#pragma unroll
    for (int mm = 32; mm >= 1; mm >>= 1) {
        s += __shfl_xor(s, mm);
        sq += __shfl_xor(sq, mm);
    }
    __shared__ float rs[4], rq[4];
    if (lane == 0) { rs[wave] = s; rq[wave] = sq; }
    __syncthreads();
    s = rs[0] + rs[1] + rs[2] + rs[3];
    sq = rq[0] + rq[1] + rq[2] + rq[3];
    const float mu = s * (1.0f / 1024.0f);
    const float var = sq * (1.0f / 1024.0f) - mu * mu;
    const float rstd = rsqrtf(var + 1e-5f);
    float4 g = ((const float4*)gamma)[tid], bt = ((const float4*)beta)[tid];
    float4 o;
    o.x = (x0 - mu) * rstd * g.x + bt.x;
    o.y = (x1 - mu) * rstd * g.y + bt.y;
    o.z = (x2 - mu) * rstd * g.z + bt.z;
    o.w = (x3 - mu) * rstd * g.w + bt.w;
    ((float4*)(out + (size_t)row * 1024))[tid] = o;
}

// ---------------------------------------------------------------- launch
extern "C" void kernel_launch(void* const* d_in, const int* in_sizes, int n_in,
                              void* d_out, int out_size, void* d_ws, size_t ws_size,
                              hipStream_t stream) {
    const float* inp   = (const float*)d_in[0];
    const float* Wqkv  = (const float*)d_in[1];
    const float* bqkv  = (const float*)d_in[2];
    const float* Wo    = (const float*)d_in[3];
    const float* gamma = (const float*)d_in[4];
    const float* beta  = (const float*)d_in[5];
    float* out = (float*)d_out;

    // workspace layout (64 MB):
    //  0- 8 : inp_bf   (dead after gemm_qkv)  -> lpart overlay (512 KB, attn)
    //  8-14 : wqkv_bf  (dead after gemm_qkv)
    // 14-16 : wo_bf    (live until gemm_o)
    // 16-32 : qk_buf   (dead after attn)
    // 32-40 : vT_buf   (dead after attn)      -> ao_bf overlay (8 MB, gemm_o out)
    // 48-64 : opart    (2 x 8 MB, attn out, read by gemm_o)
    char* ws = (char*)d_ws;
    bf16_t* inp_bf  = (bf16_t*)(ws);
    bf16_t* wqkv_bf = (bf16_t*)(ws + (8u << 20));
    bf16_t* wo_bf   = (bf16_t*)(ws + (14u << 20));
    bf16_t* qk_buf  = (bf16_t*)(ws + (16u << 20));
    bf16_t* vT_buf  = (bf16_t*)(ws + (32u << 20));
    bf16_t* ao_bf   = (bf16_t*)(ws + (32u << 20));
    bf16_t* opart   = (bf16_t*)(ws + (48u << 20));
    float*  lpart   = (float*)(ws);

    cvt_all<<<8192, 256, 0, stream>>>(inp, Wqkv, Wo, inp_bf, wqkv_bf, wo_bf);
    gemm_qkv<<<dim3(24, 32), 256, 0, stream>>>(inp_bf, wqkv_bf, bqkv, qk_buf, vT_buf);
    attn_kernel<<<1024, 256, 0, stream>>>(qk_buf, vT_buf, opart, lpart);
    gemm_o<<<dim3(8, 64), 256, 0, stream>>>(opart, lpart, wo_bf, ao_bf);
    ln_kernel<<<4096, 256, 0, stream>>>(inp, ao_bf, gamma, beta, out);
}

// Round 9
// 195.178 us; speedup vs baseline: 1.4387x; 1.0472x over previous
//
#include <hip/hip_runtime.h>
#include <hip/hip_bf16.h>
#include <stdint.h>

typedef __bf16 bf16_t;
typedef __bf16 bf16x8 __attribute__((ext_vector_type(8)));
typedef __bf16 bf16x4 __attribute__((ext_vector_type(4)));
typedef __bf16 bf16x2 __attribute__((ext_vector_type(2)));
typedef float floatx4 __attribute__((ext_vector_type(4)));

#define QSCALE 0.180336879f  /* 0.125 * log2(e) : fold score scale + exp2 domain into Q */

#if __has_builtin(__builtin_amdgcn_cvt_pk_bf16_f32)
#define HAS_PK_BF16 1
#endif

__device__ static inline void gll16(const void* g, void* l) {
    __builtin_amdgcn_global_load_lds((const __attribute__((address_space(1))) void*)g,
                                     (__attribute__((address_space(3))) void*)l, 16, 0, 0);
}

__device__ static inline bf16x8 pack8(const float* p) {
    bf16x8 o;
#ifdef HAS_PK_BF16
#pragma unroll
    for (int j = 0; j < 4; j++) {
        bf16x2 t2 = __builtin_amdgcn_cvt_pk_bf16_f32(p[2 * j], p[2 * j + 1]);
        o[2 * j] = t2[0]; o[2 * j + 1] = t2[1];
    }
#else
#pragma unroll
    for (int j = 0; j < 8; j++) o[j] = (bf16_t)p[j];
#endif
    return o;
}

// ---------------------------------------------------------------- fp32 -> bf16 (fused: inp, Wqkv, Wo)
__global__ __launch_bounds__(256) void cvt_all(const float* __restrict__ inp,
                                               const float* __restrict__ wqkv,
                                               const float* __restrict__ wo,
                                               bf16_t* __restrict__ o_inp,
                                               bf16_t* __restrict__ o_wqkv,
                                               bf16_t* __restrict__ o_wo) {
    int blk = blockIdx.x;
    const float* src;
    bf16_t* dst;
    if (blk < 4096)      { src = inp;  dst = o_inp; }
    else if (blk < 7168) { src = wqkv; dst = o_wqkv; blk -= 4096; }
    else                 { src = wo;   dst = o_wo;   blk -= 7168; }
    int i = blk * 256 + threadIdx.x;
    float4 v = ((const float4*)src)[i];
    float p[4] = {v.x, v.y, v.z, v.w};
    bf16x4 o;
#ifdef HAS_PK_BF16
    bf16x2 t0 = __builtin_amdgcn_cvt_pk_bf16_f32(p[0], p[1]);
    bf16x2 t1 = __builtin_amdgcn_cvt_pk_bf16_f32(p[2], p[3]);
    o[0] = t0[0]; o[1] = t0[1]; o[2] = t1[0]; o[3] = t1[1];
#else
    o[0] = (bf16_t)p[0]; o[1] = (bf16_t)p[1]; o[2] = (bf16_t)p[2]; o[3] = (bf16_t)p[3];
#endif
    ((bf16x4*)dst)[i] = o;
}

// ---------------------------------------------------------------- QKV GEMM
// Depth-2 prefetch (3 LDS buffers), counted vmcnt + raw barriers, LDS chunk-XOR
// swizzle (8-way -> 2-way bank conflicts; source-side inverse per rule #21),
// XCD-chunked block swizzle.  [R1 state — best measured e2e 202.09]
// vT columns are t-PERMUTED within each 32-group: p = (t&~31) | q*8 | h*4 | r.
__global__ __launch_bounds__(256, 3)
void gemm_qkv(const bf16_t* __restrict__ A, const bf16_t* __restrict__ Bw,
              const float* __restrict__ bias,
              bf16_t* __restrict__ qk, bf16_t* __restrict__ vT) {
    constexpr int K = 1024;
    __shared__ bf16_t lA[3][128 * 32];
    __shared__ bf16_t lB[3][128 * 32];
    const int tid  = threadIdx.x;
    const int lane = tid & 63, wave = tid >> 6;
    const int quad = lane >> 4, l16 = lane & 15;
    const int wy = wave >> 1, wx = wave & 1;

    // XCD-chunked swizzle: 768 wg -> 96/XCD contiguous (768 % 8 == 0, bijective).
    const int L  = blockIdx.y * 24 + blockIdx.x;
    const int nL = (L & 7) * 96 + (L >> 3);
    const int bm = (nL / 24) * 128, bn = (nL % 24) * 128;

    const int c0 = tid, c1 = tid + 256;
    // source chunk pre-swizzle: LDS slot s of row r holds global chunk s ^ ((r>>1)&3)
    const int k0 = ((c0 & 3) ^ ((c0 >> 3) & 3)) * 8;
    const int k1 = ((c1 & 3) ^ ((c1 >> 3) & 3)) * 8;
    const bf16_t* Ap0 = A + (size_t)(bm + (c0 >> 2)) * K + k0;
    const bf16_t* Ap1 = A + (size_t)(bm + (c1 >> 2)) * K + k1;
    const bf16_t* Bp0 = Bw + (size_t)(bn + (c0 >> 2)) * K + k0;
    const bf16_t* Bp1 = Bw + (size_t)(bn + (c1 >> 2)) * K + k1;
    const int d0 = (wave * 64) * 8;          // wave-uniform dest (elems); HW adds lane*16B
    const int d1 = (256 + wave * 64) * 8;

    // read-side swizzled chunk: chunk `quad` of row R lives in slot quad ^ ((R>>1)&3);
    // (R>>1)&3 == (l16>>1)&3 for all fragment rows (i*16, wy*64 don't touch bits 1-2)
    const int sq8 = (quad ^ ((l16 >> 1) & 3)) * 8;

    floatx4 acc[4][4] = {};

    // prologue: stage tiles 0 and 1 (8 gll in flight)
    gll16(Ap0, &lA[0][d0]); gll16(Ap1, &lA[0][d1]);
    gll16(Bp0, &lB[0][d0]); gll16(Bp1, &lB[0][d1]);
    gll16(Ap0 + 32, &lA[1][d0]); gll16(Ap1 + 32, &lA[1][d1]);
    gll16(Bp0 + 32, &lB[1][d0]); gll16(Bp1 + 32, &lB[1][d1]);

    int cur = 0;
    for (int it = 0; it < 32; ++it) {
        if (it < 30) {
            const int kt = (it + 2) * 32;
            const int nb = cur >= 1 ? cur - 1 : 2;        // (cur+2)%3
            gll16(Ap0 + kt, &lA[nb][d0]); gll16(Ap1 + kt, &lA[nb][d1]);
            gll16(Bp0 + kt, &lB[nb][d0]); gll16(Bp1 + kt, &lB[nb][d1]);
            asm volatile("s_waitcnt vmcnt(8)" ::: "memory");   // tile `it` landed; 8 newer stay in flight
        } else if (it == 30) {
            asm volatile("s_waitcnt vmcnt(4)" ::: "memory");
        } else {
            asm volatile("s_waitcnt vmcnt(0)" ::: "memory");
        }
        __builtin_amdgcn_s_barrier();          // all waves' tile-cur data visible
        __builtin_amdgcn_sched_barrier(0);

        bf16x8 af[4], bfr[4];
#pragma unroll
        for (int i = 0; i < 4; i++) {
            af[i]  = *(const bf16x8*)(&lA[cur][(wy * 64 + i * 16 + l16) * 32 + sq8]);
            bfr[i] = *(const bf16x8*)(&lB[cur][(wx * 64 + i * 16 + l16) * 32 + sq8]);
        }
#pragma unroll
        for (int i = 0; i < 4; i++)
#pragma unroll
            for (int j = 0; j < 4; j++)
                acc[i][j] = __builtin_amdgcn_mfma_f32_16x16x32_bf16(af[i], bfr[j], acc[i][j], 0, 0, 0);

        __builtin_amdgcn_sched_barrier(0);
        __builtin_amdgcn_s_barrier();          // reads of buf[cur] complete -> safe to overwrite next iter
        cur = cur < 2 ? cur + 1 : 0;
    }

    const bool is_v = (bn >= 2048);
#pragma unroll
    for (int j = 0; j < 4; j++) {
        const int n = bn + wx * 64 + j * 16 + l16;
        const float bv = bias[n];
        const bool isq = (n < 1024);
#pragma unroll
        for (int i = 0; i < 4; i++) {
            const int mbase = bm + wy * 64 + i * 16 + quad * 4;
            if (!is_v) {
#pragma unroll
                for (int r = 0; r < 4; r++) {
                    float c = acc[i][j][r] + bv;
                    if (isq) c *= QSCALE;
                    qk[(size_t)(mbase + r) * 2048 + n] = (bf16_t)c;
                }
            } else {
                const int nn = n - 2048;             // h*64 + d
                const int b  = mbase >> 11;
                const int t  = mbase & 2047;         // 4-aligned
                const int vrow = b * 1024 + nn;      // (b*16+h)*64 + d
                const int pcol = (t & ~31) | (((t >> 2) & 3) << 3) | (((t >> 4) & 1) << 2);
                bf16x4 pack;
#pragma unroll
                for (int r = 0; r < 4; r++) pack[r] = (bf16_t)(acc[i][j][r] + bv);
                *(bf16x4*)(vT + (size_t)vrow * 2048 + pcol) = pack;
            }
        }
    }
}

// ---------------------------------------------------------------- flash attention (S^T, split-K, gll-staged K/V)
// Exact R1 structure (best measured: 43.2 us, e2e 202.09): 2 LDS buffers, one
// __syncthreads per iter with prefetch-after-barrier, chunk-XOR swizzle.
// Grid 1024 = 32 hl x 16 qt x 2 t-halves. Block = 4 waves x 32 q-rows.
__global__ __launch_bounds__(256, 4)
void attn_kernel(const bf16_t* __restrict__ qk, const bf16_t* __restrict__ vT,
                 bf16_t* __restrict__ Opart, float* __restrict__ lpart) {
    __shared__ bf16_t Kbuf[2][64 * 64];   // [dbuf][ d-half(2) ][ t(64) ][ d(32) ]  (lane-linear)
    __shared__ bf16_t Vbuf[2][64 * 64];   // [dbuf][ t-half(2) ][ d(64) ][ p(32) ]
    const int tid  = threadIdx.x;
    const int lane = tid & 63, wave = tid >> 6;
    const int quad = lane >> 4, l16 = lane & 15;
    const int bid = blockIdx.x;
    const int s    = bid & 63;
    const int hl   = ((s & 7) << 2) | ((s >> 3) & 3);  // XCD-swizzle: 4 heads/XCD
    const int half = (s >> 5) & 1;
    const int qt   = bid >> 6;
    const int b = hl >> 4, h = hl & 15;
    const int kt0 = half * 1024;

    const bf16_t* Qbase = qk + (size_t)(b * 2048 + qt * 128 + wave * 32) * 2048 + h * 64;
    const bf16_t* Kbase = qk + (size_t)(b * 2048) * 2048 + 1024 + h * 64;
    const bf16_t* Vbase = vT + (size_t)(hl * 64) * 2048;

    const int srow = tid >> 2;
    // source chunk pre-swizzle: LDS slot (tid&3) of row srow holds global chunk (tid&3)^((srow>>1)&3)
    const int sc8 = ((tid & 3) ^ ((tid >> 3) & 3)) * 8;
    const bf16_t* KgA = Kbase + (size_t)(kt0 + srow) * 2048 + sc8;   // d 0..31
    const bf16_t* KgB = KgA + 32;                                     // d 32..63
    const bf16_t* VgA = Vbase + (size_t)srow * 2048 + kt0 + sc8;     // t-half 0 (p-cols)
    const bf16_t* VgB = VgA + 32;                                     // t-half 1
    const int wbase = wave * 512;   // wave-uniform LDS dest; HW adds lane*16B

    // read-side swizzled chunk: fragment rows are nt*16+l16 / ct*16+l16 -> bits 1-2 from l16 only
    const int xq8 = (quad ^ ((l16 >> 1) & 3)) * 8;

    bf16x8 qf[2][2];  // B-operand: n = q = l16, k = kc*32 + quad*8
#pragma unroll
    for (int rt = 0; rt < 2; rt++)
#pragma unroll
        for (int kc = 0; kc < 2; kc++)
            qf[rt][kc] = *(const bf16x8*)(Qbase + (size_t)(rt * 16 + l16) * 2048 + kc * 32 + quad * 8);

    floatx4 accO[2][4] = {};    // O[q=quad*4+r][d=ct*16+l16]
    float lacc[2] = {0.f, 0.f};

    gll16(KgA, &Kbuf[0][wbase]);
    gll16(KgB, &Kbuf[0][2048 + wbase]);
    gll16(VgA, &Vbuf[0][wbase]);
    gll16(VgB, &Vbuf[0][2048 + wbase]);

    for (int it = 0; it < 16; ++it) {
        const int cur = it & 1, nxt = cur ^ 1;
        __syncthreads();   // drains gll -> buf[cur] ready
        if (it < 15) {
            const size_t ko = (size_t)(it + 1) * 64 * 2048;
            const int    vo = (it + 1) * 64;
            gll16(KgA + ko, &Kbuf[nxt][wbase]);
            gll16(KgB + ko, &Kbuf[nxt][2048 + wbase]);
            gll16(VgA + vo, &Vbuf[nxt][wbase]);
            gll16(VgB + vo, &Vbuf[nxt][2048 + wbase]);
        }
        // S^T = K.Q^T : rows t (quad*4+r per nt-tile), cols q (l16)
        floatx4 st[2][4] = {};
#pragma unroll
        for (int nt = 0; nt < 4; nt++) {
            bf16x8 k0 = *(const bf16x8*)&Kbuf[cur][(nt * 16 + l16) * 32 + xq8];
            bf16x8 k1 = *(const bf16x8*)&Kbuf[cur][2048 + (nt * 16 + l16) * 32 + xq8];
            st[0][nt] = __builtin_amdgcn_mfma_f32_16x16x32_bf16(k0, qf[0][0], st[0][nt], 0, 0, 0);
            st[0][nt] = __builtin_amdgcn_mfma_f32_16x16x32_bf16(k1, qf[0][1], st[0][nt], 0, 0, 0);
            st[1][nt] = __builtin_amdgcn_mfma_f32_16x16x32_bf16(k0, qf[1][0], st[1][nt], 0, 0, 0);
            st[1][nt] = __builtin_amdgcn_mfma_f32_16x16x32_bf16(k1, qf[1][1], st[1][nt], 0, 0, 0);
        }
        // per t-half: V frags once; P frags built in-register (permuted t-order)
#pragma unroll
        for (int kc2 = 0; kc2 < 2; kc2++) {
            bf16x8 vf[4];
#pragma unroll
            for (int ct = 0; ct < 4; ct++)
                vf[ct] = *(const bf16x8*)&Vbuf[cur][kc2 * 2048 + (ct * 16 + l16) * 32 + xq8];
#pragma unroll
            for (int rt = 0; rt < 2; rt++) {
                float p[8];
                float ls = 0.f;
#pragma unroll
                for (int j = 0; j < 8; j++) {
                    p[j] = __builtin_amdgcn_exp2f(st[rt][kc2 * 2 + (j >> 2)][j & 3]);
                    ls += p[j];
                }
                lacc[rt] += ls;
                bf16x8 pf = pack8(p);
#pragma unroll
                for (int ct = 0; ct < 4; ct++)
                    accO[rt][ct] = __builtin_amdgcn_mfma_f32_16x16x32_bf16(pf, vf[ct], accO[rt][ct], 0, 0, 0);
            }
        }
    }

    // partial l
    float lsum[2];
#pragma unroll
    for (int rt = 0; rt < 2; rt++) {
        float l = lacc[rt];
        l += __shfl_xor(l, 16);
        l += __shfl_xor(l, 32);
        lsum[rt] = l;
    }
    // partial O with "faithful bug" permutation: dest row (hl&1)*2048 + t, col (hl>>1)*64 + d
    const int b2 = hl & 1;
    const int colb = hl >> 1;
    const int rowb = b2 * 2048 + qt * 128 + wave * 32;
    bf16_t* outb = Opart + (size_t)half * (4096 * 1024) + (size_t)rowb * 1024 + colb * 64;
#pragma unroll
    for (int rt = 0; rt < 2; rt++)
#pragma unroll
        for (int ct = 0; ct < 4; ct++)
#pragma unroll
            for (int r = 0; r < 4; r++)
                outb[(size_t)(rt * 16 + quad * 4 + r) * 1024 + ct * 16 + l16] = (bf16_t)(accO[rt][ct][r]);
    if (quad == 0) {
#pragma unroll
        for (int rt = 0; rt < 2; rt++)
            lpart[half * 65536 + (rowb + rt * 16 + l16) * 16 + colb] = lsum[rt];
    }
}

// ---------------------------------------------------------------- O GEMM, double-buffered, fused split-K combine
// R7: XCD-chunked block swizzle — the 8 n-panel blocks sharing one bm panel now
// land on ONE XCD (xcd = L&7 owns bm panels [8*xcd, 8*xcd+8) x all bn). Per-XCD
// working set: A 2 MB + B 2 MB = 4 MB (L2-resident). Kills the 8x A(opart)
// re-fetch from L3 (was ~128 MB aggregate). Otherwise exact R1 structure.
__global__ __launch_bounds__(256, 4)
void gemm_o(const bf16_t* __restrict__ Op, const float* __restrict__ lp,
            const bf16_t* __restrict__ Bw, bf16_t* __restrict__ out) {
    constexpr int K = 1024;
    __shared__ bf16_t lA[2][64 * 32];    // 2 x 4 KB
    __shared__ bf16_t lB[2][128 * 32];   // 2 x 8 KB
    const int tid  = threadIdx.x;
    const int lane = tid & 63, wave = tid >> 6;
    const int quad = lane >> 4, l16 = lane & 15;
    const int wy = wave >> 1, wx = wave & 1;   // wave tile: 32m x 64n

    // XCD-chunked swizzle: 512 wg, bijective (512 % 8 == 0).
    const int L  = blockIdx.y * 8 + blockIdx.x;
    const int nL = (L & 7) * 64 + (L >> 3);
    const int bm = (nL >> 3) * 64, bn = (nL & 7) * 128;

    const int ca = tid;                         // A: 64 rows x 4 chunks
    const int arow = bm + (ca >> 2);
    const int ak   = (ca & 3) * 8;              // global chunk carried by this thread
    // swizzled LDS write slot: slot = chunk ^ ((row>>1)&3)
    const int aslot = ((ca & 3) ^ ((ca >> 3) & 3));
    const int awr   = ((ca >> 2) * 4 + aslot) * 8;
    const bf16_t* Ap0 = Op + (size_t)arow * 1024 + ak;
    const bf16_t* Ap1 = Ap0 + (size_t)4096 * 1024;
    const float*  lrow = lp + arow * 16;
    const int cb0 = tid, cb1 = tid + 256;       // B: 128 rows x 4 chunks
    // B source chunk pre-swizzle (gll writes LDS linearly)
    const int bk0 = ((cb0 & 3) ^ ((cb0 >> 3) & 3)) * 8;
    const int bk1 = ((cb1 & 3) ^ ((cb1 >> 3) & 3)) * 8;
    const bf16_t* Bp0 = Bw + (size_t)(bn + (cb0 >> 2)) * K + bk0;
    const bf16_t* Bp1 = Bw + (size_t)(bn + (cb1 >> 2)) * K + bk1;
    const int d0 = (wave * 64) * 8;
    const int d1 = (256 + wave * 64) * 8;

    // read-side swizzled chunk (fragment rows: bits 1-2 from l16 only)
    const int xq8 = (quad ^ ((l16 >> 1) & 3)) * 8;

    // prologue: stage tile 0 (A combine + B gll)
    gll16(Bp0, &lB[0][d0]);
    gll16(Bp1, &lB[0][d1]);
    {
        bf16x8 a0 = *(const bf16x8*)(Ap0);
        bf16x8 a1 = *(const bf16x8*)(Ap1);
        const float inv = 1.0f / (lrow[ak >> 6] + lrow[65536 + (ak >> 6)]);
        float p[8];
#pragma unroll
        for (int j = 0; j < 8; j++) p[j] = ((float)a0[j] + (float)a1[j]) * inv;
        *(bf16x8*)&lA[0][awr] = pack8(p);
    }

    floatx4 acc[2][4] = {};
    for (int it = 0; it < 32; ++it) {
        const int cur = it & 1, nxt = cur ^ 1;
        __syncthreads();                    // drains gll + lA writes -> [cur] ready
        bf16x8 na0, na1;
        int kt1 = (it + 1) * 32;
        if (it < 31) {
            na0 = *(const bf16x8*)(Ap0 + kt1);
            na1 = *(const bf16x8*)(Ap1 + kt1);
            gll16(Bp0 + kt1, &lB[nxt][d0]);
            gll16(Bp1 + kt1, &lB[nxt][d1]);
        }
        bf16x8 af[2], bfr[4];
#pragma unroll
        for (int i = 0; i < 2; i++)
            af[i] = *(const bf16x8*)(&lA[cur][(wy * 32 + i * 16 + l16) * 32 + xq8]);
#pragma unroll
        for (int j = 0; j < 4; j++)
            bfr[j] = *(const bf16x8*)(&lB[cur][(wx * 64 + j * 16 + l16) * 32 + xq8]);
#pragma unroll
        for (int i = 0; i < 2; i++)
#pragma unroll
            for (int j = 0; j < 4; j++)
                acc[i][j] = __builtin_amdgcn_mfma_f32_16x16x32_bf16(af[i], bfr[j], acc[i][j], 0, 0, 0);
        if (it < 31) {                      // combine after MFMA phase (na latency hidden)
            const int cb = (kt1 + ak) >> 6;
            const float inv = 1.0f / (lrow[cb] + lrow[65536 + cb]);
            float p[8];
#pragma unroll
            for (int j = 0; j < 8; j++) p[j] = ((float)na0[j] + (float)na1[j]) * inv;
            *(bf16x8*)&lA[nxt][awr] = pack8(p);
        }
    }
#pragma unroll
    for (int j = 0; j < 4; j++) {
        const int n = bn + wx * 64 + j * 16 + l16;
#pragma unroll
        for (int i = 0; i < 2; i++) {
            const int mbase = bm + wy * 32 + i * 16 + quad * 4;
#pragma unroll
            for (int r = 0; r < 4; r++)
                out[(size_t)(mbase + r) * 1024 + n] = (bf16_t)acc[i][j][r];
        }
    }
}

// ---------------------------------------------------------------- residual + LayerNorm (ao in bf16)
__global__ __launch_bounds__(256)
void ln_kernel(const float* __restrict__ inp, const bf16_t* __restrict__ ao,
               const float* __restrict__ gamma, const float* __restrict__ beta,
               float* __restrict__ out) {
    const int row = blockIdx.x, tid = threadIdx.x;
    const int wave = tid >> 6, lane = tid & 63;
    float4 a = ((const float4*)(inp + (size_t)row * 1024))[tid];
    bf16x4 c4 = ((const bf16x4*)(ao + (size_t)row * 1024))[tid];
    float x0 = a.x + (float)c4[0], x1 = a.y + (float)c4[1];
    float x2 = a.z + (float)c4[2], x3 = a.w + (float)c4[3];
    float s = x0 + x1 + x2 + x3;
    float sq = x0 * x0 + x1 * x1 + x2 * x2 + x3 * x3;
#pragma unroll
    for (int mm = 32; mm >= 1; mm >>= 1) {
        s += __shfl_xor(s, mm);
        sq += __shfl_xor(sq, mm);
    }
    __shared__ float rs[4], rq[4];
    if (lane == 0) { rs[wave] = s; rq[wave] = sq; }
    __syncthreads();
    s = rs[0] + rs[1] + rs[2] + rs[3];
    sq = rq[0] + rq[1] + rq[2] + rq[3];
    const float mu = s * (1.0f / 1024.0f);
    const float var = sq * (1.0f / 1024.0f) - mu * mu;
    const float rstd = rsqrtf(var + 1e-5f);
    float4 g = ((const float4*)gamma)[tid], bt = ((const float4*)beta)[tid];
    float4 o;
    o.x = (x0 - mu) * rstd * g.x + bt.x;
    o.y = (x1 - mu) * rstd * g.y + bt.y;
    o.z = (x2 - mu) * rstd * g.z + bt.z;
    o.w = (x3 - mu) * rstd * g.w + bt.w;
    ((float4*)(out + (size_t)row * 1024))[tid] = o;
}

// ---------------------------------------------------------------- launch
extern "C" void kernel_launch(void* const* d_in, const int* in_sizes, int n_in,
                              void* d_out, int out_size, void* d_ws, size_t ws_size,
                              hipStream_t stream) {
    const float* inp   = (const float*)d_in[0];
    const float* Wqkv  = (const float*)d_in[1];
    const float* bqkv  = (const float*)d_in[2];
    const float* Wo    = (const float*)d_in[3];
    const float* gamma = (const float*)d_in[4];
    const float* beta  = (const float*)d_in[5];
    float* out = (float*)d_out;

    // workspace layout (64 MB):
    //  0- 8 : inp_bf   (dead after gemm_qkv)  -> lpart overlay (512 KB, attn)
    //  8-14 : wqkv_bf  (dead after gemm_qkv)
    // 14-16 : wo_bf    (live until gemm_o)
    // 16-32 : qk_buf   (dead after attn)
    // 32-40 : vT_buf   (dead after attn)      -> ao_bf overlay (8 MB, gemm_o out)
    // 48-64 : opart    (2 x 8 MB, attn out, read by gemm_o)
    char* ws = (char*)d_ws;
    bf16_t* inp_bf  = (bf16_t*)(ws);
    bf16_t* wqkv_bf = (bf16_t*)(ws + (8u << 20));
    bf16_t* wo_bf   = (bf16_t*)(ws + (14u << 20));
    bf16_t* qk_buf  = (bf16_t*)(ws + (16u << 20));
    bf16_t* vT_buf  = (bf16_t*)(ws + (32u << 20));
    bf16_t* ao_bf   = (bf16_t*)(ws + (32u << 20));
    bf16_t* opart   = (bf16_t*)(ws + (48u << 20));
    float*  lpart   = (float*)(ws);

    cvt_all<<<8192, 256, 0, stream>>>(inp, Wqkv, Wo, inp_bf, wqkv_bf, wo_bf);
    gemm_qkv<<<dim3(24, 32), 256, 0, stream>>>(inp_bf, wqkv_bf, bqkv, qk_buf, vT_buf);
    attn_kernel<<<1024, 256, 0, stream>>>(qk_buf, vT_buf, opart, lpart);
    gemm_o<<<dim3(8, 64), 256, 0, stream>>>(opart, lpart, wo_bf, ao_bf);
    ln_kernel<<<4096, 256, 0, stream>>>(inp, ao_bf, gamma, beta, out);
}

// Round 10
// 189.912 us; speedup vs baseline: 1.4786x; 1.0277x over previous
//
#include <hip/hip_runtime.h>
#include <hip/hip_bf16.h>
#include <stdint.h>

typedef __bf16 bf16_t;
typedef __bf16 bf16x8 __attribute__((ext_vector_type(8)));
typedef __bf16 bf16x4 __attribute__((ext_vector_type(4)));
typedef __bf16 bf16x2 __attribute__((ext_vector_type(2)));
typedef float floatx4 __attribute__((ext_vector_type(4)));

#define QSCALE 0.180336879f  /* 0.125 * log2(e) : fold score scale + exp2 domain into Q */

#if __has_builtin(__builtin_amdgcn_cvt_pk_bf16_f32)
#define HAS_PK_BF16 1
#endif

__device__ static inline void gll16(const void* g, void* l) {
    __builtin_amdgcn_global_load_lds((const __attribute__((address_space(1))) void*)g,
                                     (__attribute__((address_space(3))) void*)l, 16, 0, 0);
}

__device__ static inline bf16x8 pack8(const float* p) {
    bf16x8 o;
#ifdef HAS_PK_BF16
#pragma unroll
    for (int j = 0; j < 4; j++) {
        bf16x2 t2 = __builtin_amdgcn_cvt_pk_bf16_f32(p[2 * j], p[2 * j + 1]);
        o[2 * j] = t2[0]; o[2 * j + 1] = t2[1];
    }
#else
#pragma unroll
    for (int j = 0; j < 8; j++) o[j] = (bf16_t)p[j];
#endif
    return o;
}

// ---------------------------------------------------------------- fp32 -> bf16 (fused: inp, Wqkv, Wo)
__global__ __launch_bounds__(256) void cvt_all(const float* __restrict__ inp,
                                               const float* __restrict__ wqkv,
                                               const float* __restrict__ wo,
                                               bf16_t* __restrict__ o_inp,
                                               bf16_t* __restrict__ o_wqkv,
                                               bf16_t* __restrict__ o_wo) {
    int blk = blockIdx.x;
    const float* src;
    bf16_t* dst;
    if (blk < 4096)      { src = inp;  dst = o_inp; }
    else if (blk < 7168) { src = wqkv; dst = o_wqkv; blk -= 4096; }
    else                 { src = wo;   dst = o_wo;   blk -= 7168; }
    int i = blk * 256 + threadIdx.x;
    float4 v = ((const float4*)src)[i];
    float p[4] = {v.x, v.y, v.z, v.w};
    bf16x4 o;
#ifdef HAS_PK_BF16
    bf16x2 t0 = __builtin_amdgcn_cvt_pk_bf16_f32(p[0], p[1]);
    bf16x2 t1 = __builtin_amdgcn_cvt_pk_bf16_f32(p[2], p[3]);
    o[0] = t0[0]; o[1] = t0[1]; o[2] = t1[0]; o[3] = t1[1];
#else
    o[0] = (bf16_t)p[0]; o[1] = (bf16_t)p[1]; o[2] = (bf16_t)p[2]; o[3] = (bf16_t)p[3];
#endif
    ((bf16x4*)dst)[i] = o;
}

// ---------------------------------------------------------------- QKV GEMM
// Depth-2 prefetch (3 LDS buffers), counted vmcnt + raw barriers, LDS chunk-XOR
// swizzle (source-side inverse per rule #21), XCD-chunked block swizzle.
// vT columns are t-PERMUTED within each 32-group: p = (t&~31) | q*8 | h*4 | r.
__global__ __launch_bounds__(256, 3)
void gemm_qkv(const bf16_t* __restrict__ A, const bf16_t* __restrict__ Bw,
              const float* __restrict__ bias,
              bf16_t* __restrict__ qk, bf16_t* __restrict__ vT) {
    constexpr int K = 1024;
    __shared__ bf16_t lA[3][128 * 32];
    __shared__ bf16_t lB[3][128 * 32];
    const int tid  = threadIdx.x;
    const int lane = tid & 63, wave = tid >> 6;
    const int quad = lane >> 4, l16 = lane & 15;
    const int wy = wave >> 1, wx = wave & 1;

    // XCD-chunked swizzle: 768 wg -> 96/XCD contiguous (768 % 8 == 0, bijective).
    const int L  = blockIdx.y * 24 + blockIdx.x;
    const int nL = (L & 7) * 96 + (L >> 3);
    const int bm = (nL / 24) * 128, bn = (nL % 24) * 128;

    const int c0 = tid, c1 = tid + 256;
    // source chunk pre-swizzle: LDS slot s of row r holds global chunk s ^ ((r>>1)&3)
    const int k0 = ((c0 & 3) ^ ((c0 >> 3) & 3)) * 8;
    const int k1 = ((c1 & 3) ^ ((c1 >> 3) & 3)) * 8;
    const bf16_t* Ap0 = A + (size_t)(bm + (c0 >> 2)) * K + k0;
    const bf16_t* Ap1 = A + (size_t)(bm + (c1 >> 2)) * K + k1;
    const bf16_t* Bp0 = Bw + (size_t)(bn + (c0 >> 2)) * K + k0;
    const bf16_t* Bp1 = Bw + (size_t)(bn + (c1 >> 2)) * K + k1;
    const int d0 = (wave * 64) * 8;          // wave-uniform dest (elems); HW adds lane*16B
    const int d1 = (256 + wave * 64) * 8;

    // read-side swizzled chunk
    const int sq8 = (quad ^ ((l16 >> 1) & 3)) * 8;

    floatx4 acc[4][4] = {};

    // prologue: stage tiles 0 and 1 (8 gll in flight)
    gll16(Ap0, &lA[0][d0]); gll16(Ap1, &lA[0][d1]);
    gll16(Bp0, &lB[0][d0]); gll16(Bp1, &lB[0][d1]);
    gll16(Ap0 + 32, &lA[1][d0]); gll16(Ap1 + 32, &lA[1][d1]);
    gll16(Bp0 + 32, &lB[1][d0]); gll16(Bp1 + 32, &lB[1][d1]);

    int cur = 0;
    for (int it = 0; it < 32; ++it) {
        if (it < 30) {
            const int kt = (it + 2) * 32;
            const int nb = cur >= 1 ? cur - 1 : 2;        // (cur+2)%3
            gll16(Ap0 + kt, &lA[nb][d0]); gll16(Ap1 + kt, &lA[nb][d1]);
            gll16(Bp0 + kt, &lB[nb][d0]); gll16(Bp1 + kt, &lB[nb][d1]);
            asm volatile("s_waitcnt vmcnt(8)" ::: "memory");   // tile `it` landed; 8 newer stay in flight
        } else if (it == 30) {
            asm volatile("s_waitcnt vmcnt(4)" ::: "memory");
        } else {
            asm volatile("s_waitcnt vmcnt(0)" ::: "memory");
        }
        __builtin_amdgcn_s_barrier();          // all waves' tile-cur data visible
        __builtin_amdgcn_sched_barrier(0);

        bf16x8 af[4], bfr[4];
#pragma unroll
        for (int i = 0; i < 4; i++) {
            af[i]  = *(const bf16x8*)(&lA[cur][(wy * 64 + i * 16 + l16) * 32 + sq8]);
            bfr[i] = *(const bf16x8*)(&lB[cur][(wx * 64 + i * 16 + l16) * 32 + sq8]);
        }
#pragma unroll
        for (int i = 0; i < 4; i++)
#pragma unroll
            for (int j = 0; j < 4; j++)
                acc[i][j] = __builtin_amdgcn_mfma_f32_16x16x32_bf16(af[i], bfr[j], acc[i][j], 0, 0, 0);

        __builtin_amdgcn_sched_barrier(0);
        __builtin_amdgcn_s_barrier();          // reads of buf[cur] complete -> safe to overwrite next iter
        cur = cur < 2 ? cur + 1 : 0;
    }

    const bool is_v = (bn >= 2048);
#pragma unroll
    for (int j = 0; j < 4; j++) {
        const int n = bn + wx * 64 + j * 16 + l16;
        const float bv = bias[n];
        const bool isq = (n < 1024);
#pragma unroll
        for (int i = 0; i < 4; i++) {
            const int mbase = bm + wy * 64 + i * 16 + quad * 4;
            if (!is_v) {
#pragma unroll
                for (int r = 0; r < 4; r++) {
                    float c = acc[i][j][r] + bv;
                    if (isq) c *= QSCALE;
                    qk[(size_t)(mbase + r) * 2048 + n] = (bf16_t)c;
                }
            } else {
                const int nn = n - 2048;             // h*64 + d
                const int b  = mbase >> 11;
                const int t  = mbase & 2047;         // 4-aligned
                const int vrow = b * 1024 + nn;      // (b*16+h)*64 + d
                const int pcol = (t & ~31) | (((t >> 2) & 3) << 3) | (((t >> 4) & 1) << 2);
                bf16x4 pack;
#pragma unroll
                for (int r = 0; r < 4; r++) pack[r] = (bf16_t)(acc[i][j][r] + bv);
                *(bf16x4*)(vT + (size_t)vrow * 2048 + pcol) = pack;
            }
        }
    }
}

// ---------------------------------------------------------------- flash attention (S^T, FULL-T, gll-staged K/V)
// R9: split-K removed. Grid 512 = 32 hl x 16 qt; each block runs all 32 K/V
// tiles (t 0..2047) and NORMALIZES in-epilogue (row-sum redistributed via
// __shfl l16->quad*4+r transpose). Writes final attn_vec (8 MB) — no lpart,
// no combine pass in gemm_o. K/V-loop structure identical to R1 (best: 43.2us).
__global__ __launch_bounds__(256, 4)
void attn_kernel(const bf16_t* __restrict__ qk, const bf16_t* __restrict__ vT,
                 bf16_t* __restrict__ Ofin) {
    __shared__ bf16_t Kbuf[2][64 * 64];   // [dbuf][ d-half(2) ][ t(64) ][ d(32) ]  (lane-linear)
    __shared__ bf16_t Vbuf[2][64 * 64];   // [dbuf][ t-half(2) ][ d(64) ][ p(32) ]
    const int tid  = threadIdx.x;
    const int lane = tid & 63, wave = tid >> 6;
    const int quad = lane >> 4, l16 = lane & 15;
    const int bid = blockIdx.x;
    const int s    = bid & 31;
    const int hl   = ((s & 7) << 2) | ((s >> 3) & 3);  // XCD-swizzle: 4 heads/XCD
    const int qt   = bid >> 5;
    const int b = hl >> 4, h = hl & 15;

    const bf16_t* Qbase = qk + (size_t)(b * 2048 + qt * 128 + wave * 32) * 2048 + h * 64;
    const bf16_t* Kbase = qk + (size_t)(b * 2048) * 2048 + 1024 + h * 64;
    const bf16_t* Vbase = vT + (size_t)(hl * 64) * 2048;

    const int srow = tid >> 2;
    // source chunk pre-swizzle: LDS slot (tid&3) of row srow holds global chunk (tid&3)^((srow>>1)&3)
    const int sc8 = ((tid & 3) ^ ((tid >> 3) & 3)) * 8;
    const bf16_t* KgA = Kbase + (size_t)srow * 2048 + sc8;        // d 0..31
    const bf16_t* KgB = KgA + 32;                                  // d 32..63
    const bf16_t* VgA = Vbase + (size_t)srow * 2048 + sc8;        // t-half 0 (p-cols)
    const bf16_t* VgB = VgA + 32;                                  // t-half 1
    const int wbase = wave * 512;   // wave-uniform LDS dest; HW adds lane*16B

    // read-side swizzled chunk: fragment rows are nt*16+l16 / ct*16+l16 -> bits 1-2 from l16 only
    const int xq8 = (quad ^ ((l16 >> 1) & 3)) * 8;

    bf16x8 qf[2][2];  // B-operand: n = q = l16, k = kc*32 + quad*8
#pragma unroll
    for (int rt = 0; rt < 2; rt++)
#pragma unroll
        for (int kc = 0; kc < 2; kc++)
            qf[rt][kc] = *(const bf16x8*)(Qbase + (size_t)(rt * 16 + l16) * 2048 + kc * 32 + quad * 8);

    floatx4 accO[2][4] = {};    // O[q=quad*4+r][d=ct*16+l16]
    float lacc[2] = {0.f, 0.f};

    gll16(KgA, &Kbuf[0][wbase]);
    gll16(KgB, &Kbuf[0][2048 + wbase]);
    gll16(VgA, &Vbuf[0][wbase]);
    gll16(VgB, &Vbuf[0][2048 + wbase]);

    for (int it = 0; it < 32; ++it) {
        const int cur = it & 1, nxt = cur ^ 1;
        __syncthreads();   // drains gll -> buf[cur] ready
        if (it < 31) {
            const size_t ko = (size_t)(it + 1) * 64 * 2048;
            const int    vo = (it + 1) * 64;
            gll16(KgA + ko, &Kbuf[nxt][wbase]);
            gll16(KgB + ko, &Kbuf[nxt][2048 + wbase]);
            gll16(VgA + vo, &Vbuf[nxt][wbase]);
            gll16(VgB + vo, &Vbuf[nxt][2048 + wbase]);
        }
        // S^T = K.Q^T : rows t (quad*4+r per nt-tile), cols q (l16)
        floatx4 st[2][4] = {};
#pragma unroll
        for (int nt = 0; nt < 4; nt++) {
            bf16x8 k0 = *(const bf16x8*)&Kbuf[cur][(nt * 16 + l16) * 32 + xq8];
            bf16x8 k1 = *(const bf16x8*)&Kbuf[cur][2048 + (nt * 16 + l16) * 32 + xq8];
            st[0][nt] = __builtin_amdgcn_mfma_f32_16x16x32_bf16(k0, qf[0][0], st[0][nt], 0, 0, 0);
            st[0][nt] = __builtin_amdgcn_mfma_f32_16x16x32_bf16(k1, qf[0][1], st[0][nt], 0, 0, 0);
            st[1][nt] = __builtin_amdgcn_mfma_f32_16x16x32_bf16(k0, qf[1][0], st[1][nt], 0, 0, 0);
            st[1][nt] = __builtin_amdgcn_mfma_f32_16x16x32_bf16(k1, qf[1][1], st[1][nt], 0, 0, 0);
        }
        // per t-half: V frags once; P frags built in-register (permuted t-order)
#pragma unroll
        for (int kc2 = 0; kc2 < 2; kc2++) {
            bf16x8 vf[4];
#pragma unroll
            for (int ct = 0; ct < 4; ct++)
                vf[ct] = *(const bf16x8*)&Vbuf[cur][kc2 * 2048 + (ct * 16 + l16) * 32 + xq8];
#pragma unroll
            for (int rt = 0; rt < 2; rt++) {
                float p[8];
                float ls = 0.f;
#pragma unroll
                for (int j = 0; j < 8; j++) {
                    p[j] = __builtin_amdgcn_exp2f(st[rt][kc2 * 2 + (j >> 2)][j & 3]);
                    ls += p[j];
                }
                lacc[rt] += ls;
                bf16x8 pf = pack8(p);
#pragma unroll
                for (int ct = 0; ct < 4; ct++)
                    accO[rt][ct] = __builtin_amdgcn_mfma_f32_16x16x32_bf16(pf, vf[ct], accO[rt][ct], 0, 0, 0);
            }
        }
    }

    // full softmax denominator per q-row (sum over quads); all lanes hold total for (rt, l16)
    float lsum[2];
#pragma unroll
    for (int rt = 0; rt < 2; rt++) {
        float l = lacc[rt];
        l += __shfl_xor(l, 16);
        l += __shfl_xor(l, 32);
        lsum[rt] = l;
    }
    // redistribute: accO rows are q = quad*4+r, lsum rows are q = l16 -> shfl transpose
    float linv[2][4];
#pragma unroll
    for (int rt = 0; rt < 2; rt++)
#pragma unroll
        for (int r = 0; r < 4; r++)
            linv[rt][r] = 1.0f / __shfl(lsum[rt], quad * 4 + r);

    // final O with "faithful bug" permutation: dest row (hl&1)*2048 + t, col (hl>>1)*64 + d
    const int b2 = hl & 1;
    const int colb = hl >> 1;
    const int rowb = b2 * 2048 + qt * 128 + wave * 32;
    bf16_t* outb = Ofin + (size_t)rowb * 1024 + colb * 64;
#pragma unroll
    for (int rt = 0; rt < 2; rt++)
#pragma unroll
        for (int ct = 0; ct < 4; ct++)
#pragma unroll
            for (int r = 0; r < 4; r++)
                outb[(size_t)(rt * 16 + quad * 4 + r) * 1024 + ct * 16 + l16] =
                    (bf16_t)(accO[rt][ct][r] * linv[rt][r]);
}

// ---------------------------------------------------------------- O GEMM (plain, A already normalized)
// R9: combine removed -> A staged via gll like B; gemm_qkv-style 3-buffer
// depth-2 counted-vmcnt pipeline (3 glls/iter -> vmcnt 6/3/0). R7 XCD swizzle.
__global__ __launch_bounds__(256, 4)
void gemm_o(const bf16_t* __restrict__ Op, const bf16_t* __restrict__ Bw,
            bf16_t* __restrict__ out) {
    constexpr int K = 1024;
    __shared__ bf16_t lA[3][64 * 32];    // 3 x 4 KB
    __shared__ bf16_t lB[3][128 * 32];   // 3 x 8 KB
    const int tid  = threadIdx.x;
    const int lane = tid & 63, wave = tid >> 6;
    const int quad = lane >> 4, l16 = lane & 15;
    const int wy = wave >> 1, wx = wave & 1;   // wave tile: 32m x 64n

    // XCD-chunked swizzle: 512 wg, bijective (512 % 8 == 0).
    const int L  = blockIdx.y * 8 + blockIdx.x;
    const int nL = (L & 7) * 64 + (L >> 3);
    const int bm = (nL >> 3) * 64, bn = (nL & 7) * 128;

    // A: 64 rows x 4 chunks, one gll16/thread; source chunk pre-swizzled
    const int akc = ((tid & 3) ^ ((tid >> 3) & 3)) * 8;
    const bf16_t* Ap = Op + (size_t)(bm + (tid >> 2)) * K + akc;
    const int dA = wave * 512;
    const int cb0 = tid, cb1 = tid + 256;       // B: 128 rows x 4 chunks
    const int bk0 = ((cb0 & 3) ^ ((cb0 >> 3) & 3)) * 8;
    const int bk1 = ((cb1 & 3) ^ ((cb1 >> 3) & 3)) * 8;
    const bf16_t* Bp0 = Bw + (size_t)(bn + (cb0 >> 2)) * K + bk0;
    const bf16_t* Bp1 = Bw + (size_t)(bn + (cb1 >> 2)) * K + bk1;
    const int d0 = wave * 512;
    const int d1 = 2048 + wave * 512;

    // read-side swizzled chunk (fragment rows: bits 1-2 from l16 only)
    const int xq8 = (quad ^ ((l16 >> 1) & 3)) * 8;

    // prologue: stage tiles 0 and 1 (6 gll in flight)
    gll16(Ap, &lA[0][dA]);
    gll16(Bp0, &lB[0][d0]); gll16(Bp1, &lB[0][d1]);
    gll16(Ap + 32, &lA[1][dA]);
    gll16(Bp0 + 32, &lB[1][d0]); gll16(Bp1 + 32, &lB[1][d1]);

    floatx4 acc[2][4] = {};
    int cur = 0;
    for (int it = 0; it < 32; ++it) {
        if (it < 30) {
            const int kt = (it + 2) * 32;
            const int nb = cur >= 1 ? cur - 1 : 2;        // (cur+2)%3
            gll16(Ap + kt, &lA[nb][dA]);
            gll16(Bp0 + kt, &lB[nb][d0]); gll16(Bp1 + kt, &lB[nb][d1]);
            asm volatile("s_waitcnt vmcnt(6)" ::: "memory");   // tile `it` landed; 6 newer in flight
        } else if (it == 30) {
            asm volatile("s_waitcnt vmcnt(3)" ::: "memory");
        } else {
            asm volatile("s_waitcnt vmcnt(0)" ::: "memory");
        }
        __builtin_amdgcn_s_barrier();
        __builtin_amdgcn_sched_barrier(0);

        bf16x8 af[2], bfr[4];
#pragma unroll
        for (int i = 0; i < 2; i++)
            af[i] = *(const bf16x8*)(&lA[cur][(wy * 32 + i * 16 + l16) * 32 + xq8]);
#pragma unroll
        for (int j = 0; j < 4; j++)
            bfr[j] = *(const bf16x8*)(&lB[cur][(wx * 64 + j * 16 + l16) * 32 + xq8]);
#pragma unroll
        for (int i = 0; i < 2; i++)
#pragma unroll
            for (int j = 0; j < 4; j++)
                acc[i][j] = __builtin_amdgcn_mfma_f32_16x16x32_bf16(af[i], bfr[j], acc[i][j], 0, 0, 0);

        __builtin_amdgcn_sched_barrier(0);
        __builtin_amdgcn_s_barrier();
        cur = cur < 2 ? cur + 1 : 0;
    }
#pragma unroll
    for (int j = 0; j < 4; j++) {
        const int n = bn + wx * 64 + j * 16 + l16;
#pragma unroll
        for (int i = 0; i < 2; i++) {
            const int mbase = bm + wy * 32 + i * 16 + quad * 4;
#pragma unroll
            for (int r = 0; r < 4; r++)
                out[(size_t)(mbase + r) * 1024 + n] = (bf16_t)acc[i][j][r];
        }
    }
}

// ---------------------------------------------------------------- residual + LayerNorm (ao in bf16)
__global__ __launch_bounds__(256)
void ln_kernel(const float* __restrict__ inp, const bf16_t* __restrict__ ao,
               const float* __restrict__ gamma, const float* __restrict__ beta,
               float* __restrict__ out) {
    const int row = blockIdx.x, tid = threadIdx.x;
    const int wave = tid >> 6, lane = tid & 63;
    float4 a = ((const float4*)(inp + (size_t)row * 1024))[tid];
    bf16x4 c4 = ((const bf16x4*)(ao + (size_t)row * 1024))[tid];
    float x0 = a.x + (float)c4[0], x1 = a.y + (float)c4[1];
    float x2 = a.z + (float)c4[2], x3 = a.w + (float)c4[3];
    float s = x0 + x1 + x2 + x3;
    float sq = x0 * x0 + x1 * x1 + x2 * x2 + x3 * x3;
#pragma unroll
    for (int mm = 32; mm >= 1; mm >>= 1) {
        s += __shfl_xor(s, mm);
        sq += __shfl_xor(sq, mm);
    }
    __shared__ float rs[4], rq[4];
    if (lane == 0) { rs[wave] = s; rq[wave] = sq; }
    __syncthreads();
    s = rs[0] + rs[1] + rs[2] + rs[3];
    sq = rq[0] + rq[1] + rq[2] + rq[3];
    const float mu = s * (1.0f / 1024.0f);
    const float var = sq * (1.0f / 1024.0f) - mu * mu;
    const float rstd = rsqrtf(var + 1e-5f);
    float4 g = ((const float4*)gamma)[tid], bt = ((const float4*)beta)[tid];
    float4 o;
    o.x = (x0 - mu) * rstd * g.x + bt.x;
    o.y = (x1 - mu) * rstd * g.y + bt.y;
    o.z = (x2 - mu) * rstd * g.z + bt.z;
    o.w = (x3 - mu) * rstd * g.w + bt.w;
    ((float4*)(out + (size_t)row * 1024))[tid] = o;
}

// ---------------------------------------------------------------- launch
extern "C" void kernel_launch(void* const* d_in, const int* in_sizes, int n_in,
                              void* d_out, int out_size, void* d_ws, size_t ws_size,
                              hipStream_t stream) {
    const float* inp   = (const float*)d_in[0];
    const float* Wqkv  = (const float*)d_in[1];
    const float* bqkv  = (const float*)d_in[2];
    const float* Wo    = (const float*)d_in[3];
    const float* gamma = (const float*)d_in[4];
    const float* beta  = (const float*)d_in[5];
    float* out = (float*)d_out;

    // workspace layout (64 MB):
    //  0- 8 : inp_bf   (dead after gemm_qkv)
    //  8-14 : wqkv_bf  (dead after gemm_qkv)
    // 14-16 : wo_bf    (live until gemm_o)
    // 16-32 : qk_buf   (dead after attn)
    // 32-40 : vT_buf   (dead after attn)      -> ao_bf overlay (8 MB, gemm_o out)
    // 48-56 : ofin     (8 MB, final normalized attn_vec, read by gemm_o)
    char* ws = (char*)d_ws;
    bf16_t* inp_bf  = (bf16_t*)(ws);
    bf16_t* wqkv_bf = (bf16_t*)(ws + (8u << 20));
    bf16_t* wo_bf   = (bf16_t*)(ws + (14u << 20));
    bf16_t* qk_buf  = (bf16_t*)(ws + (16u << 20));
    bf16_t* vT_buf  = (bf16_t*)(ws + (32u << 20));
    bf16_t* ao_bf   = (bf16_t*)(ws + (32u << 20));
    bf16_t* ofin    = (bf16_t*)(ws + (48u << 20));

    cvt_all<<<8192, 256, 0, stream>>>(inp, Wqkv, Wo, inp_bf, wqkv_bf, wo_bf);
    gemm_qkv<<<dim3(24, 32), 256, 0, stream>>>(inp_bf, wqkv_bf, bqkv, qk_buf, vT_buf);
    attn_kernel<<<512, 256, 0, stream>>>(qk_buf, vT_buf, ofin);
    gemm_o<<<dim3(8, 64), 256, 0, stream>>>(ofin, wo_bf, ao_bf);
    ln_kernel<<<4096, 256, 0, stream>>>(inp, ao_bf, gamma, beta, out);
}

// Round 11
// 184.636 us; speedup vs baseline: 1.5209x; 1.0286x over previous
//
#include <hip/hip_runtime.h>
#include <hip/hip_bf16.h>
#include <stdint.h>

typedef __bf16 bf16_t;
typedef __bf16 bf16x8 __attribute__((ext_vector_type(8)));
typedef __bf16 bf16x4 __attribute__((ext_vector_type(4)));
typedef __bf16 bf16x2 __attribute__((ext_vector_type(2)));
typedef float floatx4 __attribute__((ext_vector_type(4)));

#define QSCALE 0.180336879f  /* 0.125 * log2(e) : fold score scale + exp2 domain into Q */

#if __has_builtin(__builtin_amdgcn_cvt_pk_bf16_f32)
#define HAS_PK_BF16 1
#endif

__device__ static inline void gll16(const void* g, void* l) {
    __builtin_amdgcn_global_load_lds((const __attribute__((address_space(1))) void*)g,
                                     (__attribute__((address_space(3))) void*)l, 16, 0, 0);
}

__device__ static inline bf16x8 pack8(const float* p) {
    bf16x8 o;
#ifdef HAS_PK_BF16
#pragma unroll
    for (int j = 0; j < 4; j++) {
        bf16x2 t2 = __builtin_amdgcn_cvt_pk_bf16_f32(p[2 * j], p[2 * j + 1]);
        o[2 * j] = t2[0]; o[2 * j + 1] = t2[1];
    }
#else
#pragma unroll
    for (int j = 0; j < 8; j++) o[j] = (bf16_t)p[j];
#endif
    return o;
}

// ---------------------------------------------------------------- fp32 -> bf16 (fused: inp, Wqkv, Wo)
__global__ __launch_bounds__(256) void cvt_all(const float* __restrict__ inp,
                                               const float* __restrict__ wqkv,
                                               const float* __restrict__ wo,
                                               bf16_t* __restrict__ o_inp,
                                               bf16_t* __restrict__ o_wqkv,
                                               bf16_t* __restrict__ o_wo) {
    int blk = blockIdx.x;
    const float* src;
    bf16_t* dst;
    if (blk < 4096)      { src = inp;  dst = o_inp; }
    else if (blk < 7168) { src = wqkv; dst = o_wqkv; blk -= 4096; }
    else                 { src = wo;   dst = o_wo;   blk -= 7168; }
    int i = blk * 256 + threadIdx.x;
    float4 v = ((const float4*)src)[i];
    float p[4] = {v.x, v.y, v.z, v.w};
    bf16x4 o;
#ifdef HAS_PK_BF16
    bf16x2 t0 = __builtin_amdgcn_cvt_pk_bf16_f32(p[0], p[1]);
    bf16x2 t1 = __builtin_amdgcn_cvt_pk_bf16_f32(p[2], p[3]);
    o[0] = t0[0]; o[1] = t0[1]; o[2] = t1[0]; o[3] = t1[1];
#else
    o[0] = (bf16_t)p[0]; o[1] = (bf16_t)p[1]; o[2] = (bf16_t)p[2]; o[3] = (bf16_t)p[3];
#endif
    ((bf16x4*)dst)[i] = o;
}

// ---------------------------------------------------------------- QKV GEMM
// Depth-2 prefetch (3 LDS buffers), counted vmcnt + raw barriers, LDS chunk-XOR
// swizzle (source-side inverse per rule #21), XCD-chunked block swizzle.
// vT columns are t-PERMUTED within each 32-group: p = (t&~31) | q*8 | h*4 | r.
__global__ __launch_bounds__(256, 3)
void gemm_qkv(const bf16_t* __restrict__ A, const bf16_t* __restrict__ Bw,
              const float* __restrict__ bias,
              bf16_t* __restrict__ qk, bf16_t* __restrict__ vT) {
    constexpr int K = 1024;
    __shared__ bf16_t lA[3][128 * 32];
    __shared__ bf16_t lB[3][128 * 32];
    const int tid  = threadIdx.x;
    const int lane = tid & 63, wave = tid >> 6;
    const int quad = lane >> 4, l16 = lane & 15;
    const int wy = wave >> 1, wx = wave & 1;

    // XCD-chunked swizzle: 768 wg -> 96/XCD contiguous (768 % 8 == 0, bijective).
    const int L  = blockIdx.y * 24 + blockIdx.x;
    const int nL = (L & 7) * 96 + (L >> 3);
    const int bm = (nL / 24) * 128, bn = (nL % 24) * 128;

    const int c0 = tid, c1 = tid + 256;
    // source chunk pre-swizzle: LDS slot s of row r holds global chunk s ^ ((r>>1)&3)
    const int k0 = ((c0 & 3) ^ ((c0 >> 3) & 3)) * 8;
    const int k1 = ((c1 & 3) ^ ((c1 >> 3) & 3)) * 8;
    const bf16_t* Ap0 = A + (size_t)(bm + (c0 >> 2)) * K + k0;
    const bf16_t* Ap1 = A + (size_t)(bm + (c1 >> 2)) * K + k1;
    const bf16_t* Bp0 = Bw + (size_t)(bn + (c0 >> 2)) * K + k0;
    const bf16_t* Bp1 = Bw + (size_t)(bn + (c1 >> 2)) * K + k1;
    const int d0 = (wave * 64) * 8;          // wave-uniform dest (elems); HW adds lane*16B
    const int d1 = (256 + wave * 64) * 8;

    // read-side swizzled chunk
    const int sq8 = (quad ^ ((l16 >> 1) & 3)) * 8;

    floatx4 acc[4][4] = {};

    // prologue: stage tiles 0 and 1 (8 gll in flight)
    gll16(Ap0, &lA[0][d0]); gll16(Ap1, &lA[0][d1]);
    gll16(Bp0, &lB[0][d0]); gll16(Bp1, &lB[0][d1]);
    gll16(Ap0 + 32, &lA[1][d0]); gll16(Ap1 + 32, &lA[1][d1]);
    gll16(Bp0 + 32, &lB[1][d0]); gll16(Bp1 + 32, &lB[1][d1]);

    int cur = 0;
    for (int it = 0; it < 32; ++it) {
        if (it < 30) {
            const int kt = (it + 2) * 32;
            const int nb = cur >= 1 ? cur - 1 : 2;        // (cur+2)%3
            gll16(Ap0 + kt, &lA[nb][d0]); gll16(Ap1 + kt, &lA[nb][d1]);
            gll16(Bp0 + kt, &lB[nb][d0]); gll16(Bp1 + kt, &lB[nb][d1]);
            asm volatile("s_waitcnt vmcnt(8)" ::: "memory");   // tile `it` landed; 8 newer stay in flight
        } else if (it == 30) {
            asm volatile("s_waitcnt vmcnt(4)" ::: "memory");
        } else {
            asm volatile("s_waitcnt vmcnt(0)" ::: "memory");
        }
        __builtin_amdgcn_s_barrier();          // all waves' tile-cur data visible
        __builtin_amdgcn_sched_barrier(0);

        bf16x8 af[4], bfr[4];
#pragma unroll
        for (int i = 0; i < 4; i++) {
            af[i]  = *(const bf16x8*)(&lA[cur][(wy * 64 + i * 16 + l16) * 32 + sq8]);
            bfr[i] = *(const bf16x8*)(&lB[cur][(wx * 64 + i * 16 + l16) * 32 + sq8]);
        }
#pragma unroll
        for (int i = 0; i < 4; i++)
#pragma unroll
            for (int j = 0; j < 4; j++)
                acc[i][j] = __builtin_amdgcn_mfma_f32_16x16x32_bf16(af[i], bfr[j], acc[i][j], 0, 0, 0);

        __builtin_amdgcn_sched_barrier(0);
        __builtin_amdgcn_s_barrier();          // reads of buf[cur] complete -> safe to overwrite next iter
        cur = cur < 2 ? cur + 1 : 0;
    }

    const bool is_v = (bn >= 2048);
#pragma unroll
    for (int j = 0; j < 4; j++) {
        const int n = bn + wx * 64 + j * 16 + l16;
        const float bv = bias[n];
        const bool isq = (n < 1024);
#pragma unroll
        for (int i = 0; i < 4; i++) {
            const int mbase = bm + wy * 64 + i * 16 + quad * 4;
            if (!is_v) {
#pragma unroll
                for (int r = 0; r < 4; r++) {
                    float c = acc[i][j][r] + bv;
                    if (isq) c *= QSCALE;
                    qk[(size_t)(mbase + r) * 2048 + n] = (bf16_t)c;
                }
            } else {
                const int nn = n - 2048;             // h*64 + d
                const int b  = mbase >> 11;
                const int t  = mbase & 2047;         // 4-aligned
                const int vrow = b * 1024 + nn;      // (b*16+h)*64 + d
                const int pcol = (t & ~31) | (((t >> 2) & 3) << 3) | (((t >> 4) & 1) << 2);
                bf16x4 pack;
#pragma unroll
                for (int r = 0; r < 4; r++) pack[r] = (bf16_t)(acc[i][j][r] + bv);
                *(bf16x4*)(vT + (size_t)vrow * 2048 + pcol) = pack;
            }
        }
    }
}

// ---------------------------------------------------------------- flash attention (S^T, FULL-T, pipelined)
// R10: R9 full-T structure + gemm_qkv-style depth-2 counted-vmcnt pipeline.
// Grid 512 caps occupancy at 2 blocks/CU regardless of LDS, so the 3-buffer
// 48 KB footprint is free (R2's occupancy tax is gone). Tile it+2 issued at
// top of iter it; vmcnt(8) leaves tiles it+1/it+2 in flight — no full drain
// in the main loop. setprio(1) on MFMA clusters (blocks phase-diverge).
__global__ __launch_bounds__(256, 2)
void attn_kernel(const bf16_t* __restrict__ qk, const bf16_t* __restrict__ vT,
                 bf16_t* __restrict__ Ofin) {
    __shared__ bf16_t Kbuf[3][64 * 64];   // [buf][ d-half(2) ][ t(64) ][ d(32) ]  (lane-linear)
    __shared__ bf16_t Vbuf[3][64 * 64];   // [buf][ t-half(2) ][ d(64) ][ p(32) ]
    const int tid  = threadIdx.x;
    const int lane = tid & 63, wave = tid >> 6;
    const int quad = lane >> 4, l16 = lane & 15;
    const int bid = blockIdx.x;
    const int s    = bid & 31;
    const int hl   = ((s & 7) << 2) | ((s >> 3) & 3);  // XCD-swizzle: 4 heads/XCD
    const int qt   = bid >> 5;
    const int b = hl >> 4, h = hl & 15;

    const bf16_t* Qbase = qk + (size_t)(b * 2048 + qt * 128 + wave * 32) * 2048 + h * 64;
    const bf16_t* Kbase = qk + (size_t)(b * 2048) * 2048 + 1024 + h * 64;
    const bf16_t* Vbase = vT + (size_t)(hl * 64) * 2048;

    const int srow = tid >> 2;
    // source chunk pre-swizzle: LDS slot (tid&3) of row srow holds global chunk (tid&3)^((srow>>1)&3)
    const int sc8 = ((tid & 3) ^ ((tid >> 3) & 3)) * 8;
    const bf16_t* KgA = Kbase + (size_t)srow * 2048 + sc8;        // d 0..31
    const bf16_t* KgB = KgA + 32;                                  // d 32..63
    const bf16_t* VgA = Vbase + (size_t)srow * 2048 + sc8;        // t-half 0 (p-cols)
    const bf16_t* VgB = VgA + 32;                                  // t-half 1
    const int wbase = wave * 512;   // wave-uniform LDS dest; HW adds lane*16B

    // read-side swizzled chunk: fragment rows are nt*16+l16 / ct*16+l16 -> bits 1-2 from l16 only
    const int xq8 = (quad ^ ((l16 >> 1) & 3)) * 8;

    floatx4 accO[2][4] = {};    // O[q=quad*4+r][d=ct*16+l16]
    float lacc[2] = {0.f, 0.f};

    // prologue: stage tiles 0 and 1 (8 gll in flight), then Q fragments
    gll16(KgA, &Kbuf[0][wbase]);
    gll16(KgB, &Kbuf[0][2048 + wbase]);
    gll16(VgA, &Vbuf[0][wbase]);
    gll16(VgB, &Vbuf[0][2048 + wbase]);
    {
        const size_t ko = (size_t)64 * 2048;
        gll16(KgA + ko, &Kbuf[1][wbase]);
        gll16(KgB + ko, &Kbuf[1][2048 + wbase]);
        gll16(VgA + 64, &Vbuf[1][wbase]);
        gll16(VgB + 64, &Vbuf[1][2048 + wbase]);
    }

    bf16x8 qf[2][2];  // B-operand: n = q = l16, k = kc*32 + quad*8
#pragma unroll
    for (int rt = 0; rt < 2; rt++)
#pragma unroll
        for (int kc = 0; kc < 2; kc++)
            qf[rt][kc] = *(const bf16x8*)(Qbase + (size_t)(rt * 16 + l16) * 2048 + kc * 32 + quad * 8);

    int cur = 0;
    for (int it = 0; it < 32; ++it) {
        if (it < 30) {
            const int nb = cur >= 1 ? cur - 1 : 2;        // (cur+2)%3
            const size_t ko = (size_t)(it + 2) * 64 * 2048;
            const int    vo = (it + 2) * 64;
            gll16(KgA + ko, &Kbuf[nb][wbase]);
            gll16(KgB + ko, &Kbuf[nb][2048 + wbase]);
            gll16(VgA + vo, &Vbuf[nb][wbase]);
            gll16(VgB + vo, &Vbuf[nb][2048 + wbase]);
            asm volatile("s_waitcnt vmcnt(8)" ::: "memory");   // tile `it` landed; 8 newer in flight
        } else if (it == 30) {
            asm volatile("s_waitcnt vmcnt(4)" ::: "memory");
        } else {
            asm volatile("s_waitcnt vmcnt(0)" ::: "memory");
        }
        __builtin_amdgcn_s_barrier();          // buf[cur] ready for all waves
        __builtin_amdgcn_sched_barrier(0);

        // S^T = K.Q^T : rows t (quad*4+r per nt-tile), cols q (l16)
        floatx4 st[2][4] = {};
        __builtin_amdgcn_s_setprio(1);
#pragma unroll
        for (int nt = 0; nt < 4; nt++) {
            bf16x8 k0 = *(const bf16x8*)&Kbuf[cur][(nt * 16 + l16) * 32 + xq8];
            bf16x8 k1 = *(const bf16x8*)&Kbuf[cur][2048 + (nt * 16 + l16) * 32 + xq8];
            st[0][nt] = __builtin_amdgcn_mfma_f32_16x16x32_bf16(k0, qf[0][0], st[0][nt], 0, 0, 0);
            st[0][nt] = __builtin_amdgcn_mfma_f32_16x16x32_bf16(k1, qf[0][1], st[0][nt], 0, 0, 0);
            st[1][nt] = __builtin_amdgcn_mfma_f32_16x16x32_bf16(k0, qf[1][0], st[1][nt], 0, 0, 0);
            st[1][nt] = __builtin_amdgcn_mfma_f32_16x16x32_bf16(k1, qf[1][1], st[1][nt], 0, 0, 0);
        }
        __builtin_amdgcn_s_setprio(0);
        // per t-half: V frags once; P frags built in-register (permuted t-order)
#pragma unroll
        for (int kc2 = 0; kc2 < 2; kc2++) {
            bf16x8 vf[4];
#pragma unroll
            for (int ct = 0; ct < 4; ct++)
                vf[ct] = *(const bf16x8*)&Vbuf[cur][kc2 * 2048 + (ct * 16 + l16) * 32 + xq8];
#pragma unroll
            for (int rt = 0; rt < 2; rt++) {
                float p[8];
                float ls = 0.f;
#pragma unroll
                for (int j = 0; j < 8; j++) {
                    p[j] = __builtin_amdgcn_exp2f(st[rt][kc2 * 2 + (j >> 2)][j & 3]);
                    ls += p[j];
                }
                lacc[rt] += ls;
                bf16x8 pf = pack8(p);
                __builtin_amdgcn_s_setprio(1);
#pragma unroll
                for (int ct = 0; ct < 4; ct++)
                    accO[rt][ct] = __builtin_amdgcn_mfma_f32_16x16x32_bf16(pf, vf[ct], accO[rt][ct], 0, 0, 0);
                __builtin_amdgcn_s_setprio(0);
            }
        }

        __builtin_amdgcn_sched_barrier(0);
        __builtin_amdgcn_s_barrier();          // all waves done reading buf[cur]
        cur = cur < 2 ? cur + 1 : 0;
    }

    // full softmax denominator per q-row (sum over quads); all lanes hold total for (rt, l16)
    float lsum[2];
#pragma unroll
    for (int rt = 0; rt < 2; rt++) {
        float l = lacc[rt];
        l += __shfl_xor(l, 16);
        l += __shfl_xor(l, 32);
        lsum[rt] = l;
    }
    // redistribute: accO rows are q = quad*4+r, lsum rows are q = l16 -> shfl transpose
    float linv[2][4];
#pragma unroll
    for (int rt = 0; rt < 2; rt++)
#pragma unroll
        for (int r = 0; r < 4; r++)
            linv[rt][r] = 1.0f / __shfl(lsum[rt], quad * 4 + r);

    // final O with "faithful bug" permutation: dest row (hl&1)*2048 + t, col (hl>>1)*64 + d
    const int b2 = hl & 1;
    const int colb = hl >> 1;
    const int rowb = b2 * 2048 + qt * 128 + wave * 32;
    bf16_t* outb = Ofin + (size_t)rowb * 1024 + colb * 64;
#pragma unroll
    for (int rt = 0; rt < 2; rt++)
#pragma unroll
        for (int ct = 0; ct < 4; ct++)
#pragma unroll
            for (int r = 0; r < 4; r++)
                outb[(size_t)(rt * 16 + quad * 4 + r) * 1024 + ct * 16 + l16] =
                    (bf16_t)(accO[rt][ct][r] * linv[rt][r]);
}

// ---------------------------------------------------------------- O GEMM (plain, A already normalized)
// 3-buffer depth-2 counted-vmcnt pipeline (3 glls/iter -> vmcnt 6/3/0), XCD swizzle.
__global__ __launch_bounds__(256, 4)
void gemm_o(const bf16_t* __restrict__ Op, const bf16_t* __restrict__ Bw,
            bf16_t* __restrict__ out) {
    constexpr int K = 1024;
    __shared__ bf16_t lA[3][64 * 32];    // 3 x 4 KB
    __shared__ bf16_t lB[3][128 * 32];   // 3 x 8 KB
    const int tid  = threadIdx.x;
    const int lane = tid & 63, wave = tid >> 6;
    const int quad = lane >> 4, l16 = lane & 15;
    const int wy = wave >> 1, wx = wave & 1;   // wave tile: 32m x 64n

    // XCD-chunked swizzle: 512 wg, bijective (512 % 8 == 0).
    const int L  = blockIdx.y * 8 + blockIdx.x;
    const int nL = (L & 7) * 64 + (L >> 3);
    const int bm = (nL >> 3) * 64, bn = (nL & 7) * 128;

    // A: 64 rows x 4 chunks, one gll16/thread; source chunk pre-swizzled
    const int akc = ((tid & 3) ^ ((tid >> 3) & 3)) * 8;
    const bf16_t* Ap = Op + (size_t)(bm + (tid >> 2)) * K + akc;
    const int dA = wave * 512;
    const int cb0 = tid, cb1 = tid + 256;       // B: 128 rows x 4 chunks
    const int bk0 = ((cb0 & 3) ^ ((cb0 >> 3) & 3)) * 8;
    const int bk1 = ((cb1 & 3) ^ ((cb1 >> 3) & 3)) * 8;
    const bf16_t* Bp0 = Bw + (size_t)(bn + (cb0 >> 2)) * K + bk0;
    const bf16_t* Bp1 = Bw + (size_t)(bn + (cb1 >> 2)) * K + bk1;
    const int d0 = wave * 512;
    const int d1 = 2048 + wave * 512;

    // read-side swizzled chunk (fragment rows: bits 1-2 from l16 only)
    const int xq8 = (quad ^ ((l16 >> 1) & 3)) * 8;

    // prologue: stage tiles 0 and 1 (6 gll in flight)
    gll16(Ap, &lA[0][dA]);
    gll16(Bp0, &lB[0][d0]); gll16(Bp1, &lB[0][d1]);
    gll16(Ap + 32, &lA[1][dA]);
    gll16(Bp0 + 32, &lB[1][d0]); gll16(Bp1 + 32, &lB[1][d1]);

    floatx4 acc[2][4] = {};
    int cur = 0;
    for (int it = 0; it < 32; ++it) {
        if (it < 30) {
            const int kt = (it + 2) * 32;
            const int nb = cur >= 1 ? cur - 1 : 2;        // (cur+2)%3
            gll16(Ap + kt, &lA[nb][dA]);
            gll16(Bp0 + kt, &lB[nb][d0]); gll16(Bp1 + kt, &lB[nb][d1]);
            asm volatile("s_waitcnt vmcnt(6)" ::: "memory");   // tile `it` landed; 6 newer in flight
        } else if (it == 30) {
            asm volatile("s_waitcnt vmcnt(3)" ::: "memory");
        } else {
            asm volatile("s_waitcnt vmcnt(0)" ::: "memory");
        }
        __builtin_amdgcn_s_barrier();
        __builtin_amdgcn_sched_barrier(0);

        bf16x8 af[2], bfr[4];
#pragma unroll
        for (int i = 0; i < 2; i++)
            af[i] = *(const bf16x8*)(&lA[cur][(wy * 32 + i * 16 + l16) * 32 + xq8]);
#pragma unroll
        for (int j = 0; j < 4; j++)
            bfr[j] = *(const bf16x8*)(&lB[cur][(wx * 64 + j * 16 + l16) * 32 + xq8]);
#pragma unroll
        for (int i = 0; i < 2; i++)
#pragma unroll
            for (int j = 0; j < 4; j++)
                acc[i][j] = __builtin_amdgcn_mfma_f32_16x16x32_bf16(af[i], bfr[j], acc[i][j], 0, 0, 0);

        __builtin_amdgcn_sched_barrier(0);
        __builtin_amdgcn_s_barrier();
        cur = cur < 2 ? cur + 1 : 0;
    }
#pragma unroll
    for (int j = 0; j < 4; j++) {
        const int n = bn + wx * 64 + j * 16 + l16;
#pragma unroll
        for (int i = 0; i < 2; i++) {
            const int mbase = bm + wy * 32 + i * 16 + quad * 4;
#pragma unroll
            for (int r = 0; r < 4; r++)
                out[(size_t)(mbase + r) * 1024 + n] = (bf16_t)acc[i][j][r];
        }
    }
}

// ---------------------------------------------------------------- residual + LayerNorm (ao in bf16)
__global__ __launch_bounds__(256)
void ln_kernel(const float* __restrict__ inp, const bf16_t* __restrict__ ao,
               const float* __restrict__ gamma, const float* __restrict__ beta,
               float* __restrict__ out) {
    const int row = blockIdx.x, tid = threadIdx.x;
    const int wave = tid >> 6, lane = tid & 63;
    float4 a = ((const float4*)(inp + (size_t)row * 1024))[tid];
    bf16x4 c4 = ((const bf16x4*)(ao + (size_t)row * 1024))[tid];
    float x0 = a.x + (float)c4[0], x1 = a.y + (float)c4[1];
    float x2 = a.z + (float)c4[2], x3 = a.w + (float)c4[3];
    float s = x0 + x1 + x2 + x3;
    float sq = x0 * x0 + x1 * x1 + x2 * x2 + x3 * x3;
#pragma unroll
    for (int mm = 32; mm >= 1; mm >>= 1) {
        s += __shfl_xor(s, mm);
        sq += __shfl_xor(sq, mm);
    }
    __shared__ float rs[4], rq[4];
    if (lane == 0) { rs[wave] = s; rq[wave] = sq; }
    __syncthreads();
    s = rs[0] + rs[1] + rs[2] + rs[3];
    sq = rq[0] + rq[1] + rq[2] + rq[3];
    const float mu = s * (1.0f / 1024.0f);
    const float var = sq * (1.0f / 1024.0f) - mu * mu;
    const float rstd = rsqrtf(var + 1e-5f);
    float4 g = ((const float4*)gamma)[tid], bt = ((const float4*)beta)[tid];
    float4 o;
    o.x = (x0 - mu) * rstd * g.x + bt.x;
    o.y = (x1 - mu) * rstd * g.y + bt.y;
    o.z = (x2 - mu) * rstd * g.z + bt.z;
    o.w = (x3 - mu) * rstd * g.w + bt.w;
    ((float4*)(out + (size_t)row * 1024))[tid] = o;
}

// ---------------------------------------------------------------- launch
extern "C" void kernel_launch(void* const* d_in, const int* in_sizes, int n_in,
                              void* d_out, int out_size, void* d_ws, size_t ws_size,
                              hipStream_t stream) {
    const float* inp   = (const float*)d_in[0];
    const float* Wqkv  = (const float*)d_in[1];
    const float* bqkv  = (const float*)d_in[2];
    const float* Wo    = (const float*)d_in[3];
    const float* gamma = (const float*)d_in[4];
    const float* beta  = (const float*)d_in[5];
    float* out = (float*)d_out;

    // workspace layout (64 MB):
    //  0- 8 : inp_bf   (dead after gemm_qkv)
    //  8-14 : wqkv_bf  (dead after gemm_qkv)
    // 14-16 : wo_bf    (live until gemm_o)
    // 16-32 : qk_buf   (dead after attn)
    // 32-40 : vT_buf   (dead after attn)      -> ao_bf overlay (8 MB, gemm_o out)
    // 48-56 : ofin     (8 MB, final normalized attn_vec, read by gemm_o)
    char* ws = (char*)d_ws;
    bf16_t* inp_bf  = (bf16_t*)(ws);
    bf16_t* wqkv_bf = (bf16_t*)(ws + (8u << 20));
    bf16_t* wo_bf   = (bf16_t*)(ws + (14u << 20));
    bf16_t* qk_buf  = (bf16_t*)(ws + (16u << 20));
    bf16_t* vT_buf  = (bf16_t*)(ws + (32u << 20));
    bf16_t* ao_bf   = (bf16_t*)(ws + (32u << 20));
    bf16_t* ofin    = (bf16_t*)(ws + (48u << 20));

    cvt_all<<<8192, 256, 0, stream>>>(inp, Wqkv, Wo, inp_bf, wqkv_bf, wo_bf);
    gemm_qkv<<<dim3(24, 32), 256, 0, stream>>>(inp_bf, wqkv_bf, bqkv, qk_buf, vT_buf);
    attn_kernel<<<512, 256, 0, stream>>>(qk_buf, vT_buf, ofin);
    gemm_o<<<dim3(8, 64), 256, 0, stream>>>(ofin, wo_bf, ao_bf);
    ln_kernel<<<4096, 256, 0, stream>>>(inp, ao_bf, gamma, beta, out);
}

// Round 12
// 182.273 us; speedup vs baseline: 1.5406x; 1.0130x over previous
//
#include <hip/hip_runtime.h>
#include <hip/hip_bf16.h>
#include <stdint.h>

typedef __bf16 bf16_t;
typedef __bf16 bf16x8 __attribute__((ext_vector_type(8)));
typedef __bf16 bf16x4 __attribute__((ext_vector_type(4)));
typedef __bf16 bf16x2 __attribute__((ext_vector_type(2)));
typedef float floatx4 __attribute__((ext_vector_type(4)));

#define QSCALE 0.180336879f  /* 0.125 * log2(e) : fold score scale + exp2 domain into Q */

#if __has_builtin(__builtin_amdgcn_cvt_pk_bf16_f32)
#define HAS_PK_BF16 1
#endif

__device__ static inline void gll16(const void* g, void* l) {
    __builtin_amdgcn_global_load_lds((const __attribute__((address_space(1))) void*)g,
                                     (__attribute__((address_space(3))) void*)l, 16, 0, 0);
}

__device__ static inline bf16x8 pack8(const float* p) {
    bf16x8 o;
#ifdef HAS_PK_BF16
#pragma unroll
    for (int j = 0; j < 4; j++) {
        bf16x2 t2 = __builtin_amdgcn_cvt_pk_bf16_f32(p[2 * j], p[2 * j + 1]);
        o[2 * j] = t2[0]; o[2 * j + 1] = t2[1];
    }
#else
#pragma unroll
    for (int j = 0; j < 8; j++) o[j] = (bf16_t)p[j];
#endif
    return o;
}

// ---------------------------------------------------------------- fp32 -> bf16 (fused: inp, Wqkv, Wo)
__global__ __launch_bounds__(256) void cvt_all(const float* __restrict__ inp,
                                               const float* __restrict__ wqkv,
                                               const float* __restrict__ wo,
                                               bf16_t* __restrict__ o_inp,
                                               bf16_t* __restrict__ o_wqkv,
                                               bf16_t* __restrict__ o_wo) {
    int blk = blockIdx.x;
    const float* src;
    bf16_t* dst;
    if (blk < 4096)      { src = inp;  dst = o_inp; }
    else if (blk < 7168) { src = wqkv; dst = o_wqkv; blk -= 4096; }
    else                 { src = wo;   dst = o_wo;   blk -= 7168; }
    int i = blk * 256 + threadIdx.x;
    float4 v = ((const float4*)src)[i];
    float p[4] = {v.x, v.y, v.z, v.w};
    bf16x4 o;
#ifdef HAS_PK_BF16
    bf16x2 t0 = __builtin_amdgcn_cvt_pk_bf16_f32(p[0], p[1]);
    bf16x2 t1 = __builtin_amdgcn_cvt_pk_bf16_f32(p[2], p[3]);
    o[0] = t0[0]; o[1] = t0[1]; o[2] = t1[0]; o[3] = t1[1];
#else
    o[0] = (bf16_t)p[0]; o[1] = (bf16_t)p[1]; o[2] = (bf16_t)p[2]; o[3] = (bf16_t)p[3];
#endif
    ((bf16x4*)dst)[i] = o;
}

// ---------------------------------------------------------------- QKV GEMM
// R11: single barrier/iter — vmcnt(4) BEFORE the barrier (own tile-it glls
// drained; tile-it+1 stays in flight), prefetch tile-it+2 issued AFTER the
// barrier (reads of that buffer at iter it-1 are ordered before barrier(it)).
// 3 LDS buffers, chunk-XOR swizzle, XCD-chunked block swizzle.
// vT columns are t-PERMUTED within each 32-group: p = (t&~31) | q*8 | h*4 | r.
__global__ __launch_bounds__(256, 3)
void gemm_qkv(const bf16_t* __restrict__ A, const bf16_t* __restrict__ Bw,
              const float* __restrict__ bias,
              bf16_t* __restrict__ qk, bf16_t* __restrict__ vT) {
    constexpr int K = 1024;
    __shared__ bf16_t lA[3][128 * 32];
    __shared__ bf16_t lB[3][128 * 32];
    const int tid  = threadIdx.x;
    const int lane = tid & 63, wave = tid >> 6;
    const int quad = lane >> 4, l16 = lane & 15;
    const int wy = wave >> 1, wx = wave & 1;

    // XCD-chunked swizzle: 768 wg -> 96/XCD contiguous (768 % 8 == 0, bijective).
    const int L  = blockIdx.y * 24 + blockIdx.x;
    const int nL = (L & 7) * 96 + (L >> 3);
    const int bm = (nL / 24) * 128, bn = (nL % 24) * 128;

    const int c0 = tid, c1 = tid + 256;
    // source chunk pre-swizzle: LDS slot s of row r holds global chunk s ^ ((r>>1)&3)
    const int k0 = ((c0 & 3) ^ ((c0 >> 3) & 3)) * 8;
    const int k1 = ((c1 & 3) ^ ((c1 >> 3) & 3)) * 8;
    const bf16_t* Ap0 = A + (size_t)(bm + (c0 >> 2)) * K + k0;
    const bf16_t* Ap1 = A + (size_t)(bm + (c1 >> 2)) * K + k1;
    const bf16_t* Bp0 = Bw + (size_t)(bn + (c0 >> 2)) * K + k0;
    const bf16_t* Bp1 = Bw + (size_t)(bn + (c1 >> 2)) * K + k1;
    const int d0 = (wave * 64) * 8;          // wave-uniform dest (elems); HW adds lane*16B
    const int d1 = (256 + wave * 64) * 8;

    // read-side swizzled chunk
    const int sq8 = (quad ^ ((l16 >> 1) & 3)) * 8;

    floatx4 acc[4][4] = {};

    // prologue: stage tiles 0 and 1 (8 gll in flight)
    gll16(Ap0, &lA[0][d0]); gll16(Ap1, &lA[0][d1]);
    gll16(Bp0, &lB[0][d0]); gll16(Bp1, &lB[0][d1]);
    gll16(Ap0 + 32, &lA[1][d0]); gll16(Ap1 + 32, &lA[1][d1]);
    gll16(Bp0 + 32, &lB[1][d0]); gll16(Bp1 + 32, &lB[1][d1]);

    int cur = 0;
    for (int it = 0; it < 32; ++it) {
        if (it < 31) {
            asm volatile("s_waitcnt vmcnt(4)" ::: "memory");   // own tile-it glls landed
        } else {
            asm volatile("s_waitcnt vmcnt(0)" ::: "memory");
        }
        __builtin_amdgcn_s_barrier();          // everyone's tile-it writes published
        if (it < 30) {
            const int kt = (it + 2) * 32;
            const int nb = cur >= 1 ? cur - 1 : 2;        // (cur+2)%3 — read last at it-1
            gll16(Ap0 + kt, &lA[nb][d0]); gll16(Ap1 + kt, &lA[nb][d1]);
            gll16(Bp0 + kt, &lB[nb][d0]); gll16(Bp1 + kt, &lB[nb][d1]);
        }
        __builtin_amdgcn_sched_barrier(0);

        bf16x8 af[4], bfr[4];
#pragma unroll
        for (int i = 0; i < 4; i++) {
            af[i]  = *(const bf16x8*)(&lA[cur][(wy * 64 + i * 16 + l16) * 32 + sq8]);
            bfr[i] = *(const bf16x8*)(&lB[cur][(wx * 64 + i * 16 + l16) * 32 + sq8]);
        }
#pragma unroll
        for (int i = 0; i < 4; i++)
#pragma unroll
            for (int j = 0; j < 4; j++)
                acc[i][j] = __builtin_amdgcn_mfma_f32_16x16x32_bf16(af[i], bfr[j], acc[i][j], 0, 0, 0);

        cur = cur < 2 ? cur + 1 : 0;
    }

    const bool is_v = (bn >= 2048);
#pragma unroll
    for (int j = 0; j < 4; j++) {
        const int n = bn + wx * 64 + j * 16 + l16;
        const float bv = bias[n];
        const bool isq = (n < 1024);
#pragma unroll
        for (int i = 0; i < 4; i++) {
            const int mbase = bm + wy * 64 + i * 16 + quad * 4;
            if (!is_v) {
#pragma unroll
                for (int r = 0; r < 4; r++) {
                    float c = acc[i][j][r] + bv;
                    if (isq) c *= QSCALE;
                    qk[(size_t)(mbase + r) * 2048 + n] = (bf16_t)c;
                }
            } else {
                const int nn = n - 2048;             // h*64 + d
                const int b  = mbase >> 11;
                const int t  = mbase & 2047;         // 4-aligned
                const int vrow = b * 1024 + nn;      // (b*16+h)*64 + d
                const int pcol = (t & ~31) | (((t >> 2) & 3) << 3) | (((t >> 4) & 1) << 2);
                bf16x4 pack;
#pragma unroll
                for (int r = 0; r < 4; r++) pack[r] = (bf16_t)(acc[i][j][r] + bv);
                *(bf16x4*)(vT + (size_t)vrow * 2048 + pcol) = pack;
            }
        }
    }
}

// ---------------------------------------------------------------- flash attention (S^T, FULL-T, pipelined)
// R11: single barrier/iter (vmcnt(4) pre-barrier, prefetch post-barrier) and
// row-sum l computed via ones-MFMA: accL[rt] = mfma(pf, ones, accL[rt]) lands
// l_q in the SAME layout as accO (q = quad*4+r) — no scalar adds, no shfl
// transpose. 3 K/V buffers (48 KB; grid 512 caps occupancy at 2 blocks/CU so
// LDS is free). setprio(1) on MFMA clusters.
__global__ __launch_bounds__(256, 2)
void attn_kernel(const bf16_t* __restrict__ qk, const bf16_t* __restrict__ vT,
                 bf16_t* __restrict__ Ofin) {
    __shared__ bf16_t Kbuf[3][64 * 64];   // [buf][ d-half(2) ][ t(64) ][ d(32) ]  (lane-linear)
    __shared__ bf16_t Vbuf[3][64 * 64];   // [buf][ t-half(2) ][ d(64) ][ p(32) ]
    const int tid  = threadIdx.x;
    const int lane = tid & 63, wave = tid >> 6;
    const int quad = lane >> 4, l16 = lane & 15;
    const int bid = blockIdx.x;
    const int s    = bid & 31;
    const int hl   = ((s & 7) << 2) | ((s >> 3) & 3);  // XCD-swizzle: 4 heads/XCD
    const int qt   = bid >> 5;
    const int b = hl >> 4, h = hl & 15;

    const bf16_t* Qbase = qk + (size_t)(b * 2048 + qt * 128 + wave * 32) * 2048 + h * 64;
    const bf16_t* Kbase = qk + (size_t)(b * 2048) * 2048 + 1024 + h * 64;
    const bf16_t* Vbase = vT + (size_t)(hl * 64) * 2048;

    const int srow = tid >> 2;
    // source chunk pre-swizzle: LDS slot (tid&3) of row srow holds global chunk (tid&3)^((srow>>1)&3)
    const int sc8 = ((tid & 3) ^ ((tid >> 3) & 3)) * 8;
    const bf16_t* KgA = Kbase + (size_t)srow * 2048 + sc8;        // d 0..31
    const bf16_t* KgB = KgA + 32;                                  // d 32..63
    const bf16_t* VgA = Vbase + (size_t)srow * 2048 + sc8;        // t-half 0 (p-cols)
    const bf16_t* VgB = VgA + 32;                                  // t-half 1
    const int wbase = wave * 512;   // wave-uniform LDS dest; HW adds lane*16B

    // read-side swizzled chunk: fragment rows are nt*16+l16 / ct*16+l16 -> bits 1-2 from l16 only
    const int xq8 = (quad ^ ((l16 >> 1) & 3)) * 8;

    floatx4 accO[2][4] = {};    // O[q=quad*4+r][d=ct*16+l16]
    floatx4 accL[2] = {};       // l[q=quad*4+r] (ones-MFMA row sums; col l16 irrelevant)
    bf16x8 onesf;
#pragma unroll
    for (int j = 0; j < 8; j++) onesf[j] = (bf16_t)1.0f;

    // prologue: stage tiles 0 and 1 (8 gll in flight), then Q fragments
    gll16(KgA, &Kbuf[0][wbase]);
    gll16(KgB, &Kbuf[0][2048 + wbase]);
    gll16(VgA, &Vbuf[0][wbase]);
    gll16(VgB, &Vbuf[0][2048 + wbase]);
    {
        const size_t ko = (size_t)64 * 2048;
        gll16(KgA + ko, &Kbuf[1][wbase]);
        gll16(KgB + ko, &Kbuf[1][2048 + wbase]);
        gll16(VgA + 64, &Vbuf[1][wbase]);
        gll16(VgB + 64, &Vbuf[1][2048 + wbase]);
    }

    bf16x8 qf[2][2];  // B-operand: n = q = l16, k = kc*32 + quad*8
#pragma unroll
    for (int rt = 0; rt < 2; rt++)
#pragma unroll
        for (int kc = 0; kc < 2; kc++)
            qf[rt][kc] = *(const bf16x8*)(Qbase + (size_t)(rt * 16 + l16) * 2048 + kc * 32 + quad * 8);

    int cur = 0;
    for (int it = 0; it < 32; ++it) {
        if (it < 31) {
            asm volatile("s_waitcnt vmcnt(4)" ::: "memory");   // own tile-it glls landed
        } else {
            asm volatile("s_waitcnt vmcnt(0)" ::: "memory");
        }
        __builtin_amdgcn_s_barrier();          // everyone's tile-it writes published
        if (it < 30) {
            const int nb = cur >= 1 ? cur - 1 : 2;        // (cur+2)%3 — read last at it-1
            const size_t ko = (size_t)(it + 2) * 64 * 2048;
            const int    vo = (it + 2) * 64;
            gll16(KgA + ko, &Kbuf[nb][wbase]);
            gll16(KgB + ko, &Kbuf[nb][2048 + wbase]);
            gll16(VgA + vo, &Vbuf[nb][wbase]);
            gll16(VgB + vo, &Vbuf[nb][2048 + wbase]);
        }
        __builtin_amdgcn_sched_barrier(0);

        // S^T = K.Q^T : rows t (quad*4+r per nt-tile), cols q (l16)
        floatx4 st[2][4] = {};
        __builtin_amdgcn_s_setprio(1);
#pragma unroll
        for (int nt = 0; nt < 4; nt++) {
            bf16x8 k0 = *(const bf16x8*)&Kbuf[cur][(nt * 16 + l16) * 32 + xq8];
            bf16x8 k1 = *(const bf16x8*)&Kbuf[cur][2048 + (nt * 16 + l16) * 32 + xq8];
            st[0][nt] = __builtin_amdgcn_mfma_f32_16x16x32_bf16(k0, qf[0][0], st[0][nt], 0, 0, 0);
            st[0][nt] = __builtin_amdgcn_mfma_f32_16x16x32_bf16(k1, qf[0][1], st[0][nt], 0, 0, 0);
            st[1][nt] = __builtin_amdgcn_mfma_f32_16x16x32_bf16(k0, qf[1][0], st[1][nt], 0, 0, 0);
            st[1][nt] = __builtin_amdgcn_mfma_f32_16x16x32_bf16(k1, qf[1][1], st[1][nt], 0, 0, 0);
        }
        __builtin_amdgcn_s_setprio(0);
        // per t-half: V frags once; P frags built in-register (permuted t-order)
#pragma unroll
        for (int kc2 = 0; kc2 < 2; kc2++) {
            bf16x8 vf[4];
#pragma unroll
            for (int ct = 0; ct < 4; ct++)
                vf[ct] = *(const bf16x8*)&Vbuf[cur][kc2 * 2048 + (ct * 16 + l16) * 32 + xq8];
#pragma unroll
            for (int rt = 0; rt < 2; rt++) {
                float p[8];
#pragma unroll
                for (int j = 0; j < 8; j++)
                    p[j] = __builtin_amdgcn_exp2f(st[rt][kc2 * 2 + (j >> 2)][j & 3]);
                bf16x8 pf = pack8(p);
                __builtin_amdgcn_s_setprio(1);
#pragma unroll
                for (int ct = 0; ct < 4; ct++)
                    accO[rt][ct] = __builtin_amdgcn_mfma_f32_16x16x32_bf16(pf, vf[ct], accO[rt][ct], 0, 0, 0);
                accL[rt] = __builtin_amdgcn_mfma_f32_16x16x32_bf16(pf, onesf, accL[rt], 0, 0, 0);
                __builtin_amdgcn_s_setprio(0);
            }
        }

        cur = cur < 2 ? cur + 1 : 0;
    }

    // denominator already in accO layout: accL[rt][r] = l for q=quad*4+r
    float linv[2][4];
#pragma unroll
    for (int rt = 0; rt < 2; rt++)
#pragma unroll
        for (int r = 0; r < 4; r++)
            linv[rt][r] = 1.0f / accL[rt][r];

    // final O with "faithful bug" permutation: dest row (hl&1)*2048 + t, col (hl>>1)*64 + d
    const int b2 = hl & 1;
    const int colb = hl >> 1;
    const int rowb = b2 * 2048 + qt * 128 + wave * 32;
    bf16_t* outb = Ofin + (size_t)rowb * 1024 + colb * 64;
#pragma unroll
    for (int rt = 0; rt < 2; rt++)
#pragma unroll
        for (int ct = 0; ct < 4; ct++)
#pragma unroll
            for (int r = 0; r < 4; r++)
                outb[(size_t)(rt * 16 + quad * 4 + r) * 1024 + ct * 16 + l16] =
                    (bf16_t)(accO[rt][ct][r] * linv[rt][r]);
}

// ---------------------------------------------------------------- O GEMM (plain, A already normalized)
// R11: single barrier/iter (vmcnt(3) pre-barrier, prefetch post-barrier).
// 3-buffer depth-2 pipeline, XCD-chunked swizzle.
__global__ __launch_bounds__(256, 4)
void gemm_o(const bf16_t* __restrict__ Op, const bf16_t* __restrict__ Bw,
            bf16_t* __restrict__ out) {
    constexpr int K = 1024;
    __shared__ bf16_t lA[3][64 * 32];    // 3 x 4 KB
    __shared__ bf16_t lB[3][128 * 32];   // 3 x 8 KB
    const int tid  = threadIdx.x;
    const int lane = tid & 63, wave = tid >> 6;
    const int quad = lane >> 4, l16 = lane & 15;
    const int wy = wave >> 1, wx = wave & 1;   // wave tile: 32m x 64n

    // XCD-chunked swizzle: 512 wg, bijective (512 % 8 == 0).
    const int L  = blockIdx.y * 8 + blockIdx.x;
    const int nL = (L & 7) * 64 + (L >> 3);
    const int bm = (nL >> 3) * 64, bn = (nL & 7) * 128;

    // A: 64 rows x 4 chunks, one gll16/thread; source chunk pre-swizzled
    const int akc = ((tid & 3) ^ ((tid >> 3) & 3)) * 8;
    const bf16_t* Ap = Op + (size_t)(bm + (tid >> 2)) * K + akc;
    const int dA = wave * 512;
    const int cb0 = tid, cb1 = tid + 256;       // B: 128 rows x 4 chunks
    const int bk0 = ((cb0 & 3) ^ ((cb0 >> 3) & 3)) * 8;
    const int bk1 = ((cb1 & 3) ^ ((cb1 >> 3) & 3)) * 8;
    const bf16_t* Bp0 = Bw + (size_t)(bn + (cb0 >> 2)) * K + bk0;
    const bf16_t* Bp1 = Bw + (size_t)(bn + (cb1 >> 2)) * K + bk1;
    const int d0 = wave * 512;
    const int d1 = 2048 + wave * 512;

    // read-side swizzled chunk (fragment rows: bits 1-2 from l16 only)
    const int xq8 = (quad ^ ((l16 >> 1) & 3)) * 8;

    // prologue: stage tiles 0 and 1 (6 gll in flight)
    gll16(Ap, &lA[0][dA]);
    gll16(Bp0, &lB[0][d0]); gll16(Bp1, &lB[0][d1]);
    gll16(Ap + 32, &lA[1][dA]);
    gll16(Bp0 + 32, &lB[1][d0]); gll16(Bp1 + 32, &lB[1][d1]);

    floatx4 acc[2][4] = {};
    int cur = 0;
    for (int it = 0; it < 32; ++it) {
        if (it < 31) {
            asm volatile("s_waitcnt vmcnt(3)" ::: "memory");   // own tile-it glls landed
        } else {
            asm volatile("s_waitcnt vmcnt(0)" ::: "memory");
        }
        __builtin_amdgcn_s_barrier();
        if (it < 30) {
            const int kt = (it + 2) * 32;
            const int nb = cur >= 1 ? cur - 1 : 2;        // (cur+2)%3 — read last at it-1
            gll16(Ap + kt, &lA[nb][dA]);
            gll16(Bp0 + kt, &lB[nb][d0]); gll16(Bp1 + kt, &lB[nb][d1]);
        }
        __builtin_amdgcn_sched_barrier(0);

        bf16x8 af[2], bfr[4];
#pragma unroll
        for (int i = 0; i < 2; i++)
            af[i] = *(const bf16x8*)(&lA[cur][(wy * 32 + i * 16 + l16) * 32 + xq8]);
#pragma unroll
        for (int j = 0; j < 4; j++)
            bfr[j] = *(const bf16x8*)(&lB[cur][(wx * 64 + j * 16 + l16) * 32 + xq8]);
#pragma unroll
        for (int i = 0; i < 2; i++)
#pragma unroll
            for (int j = 0; j < 4; j++)
                acc[i][j] = __builtin_amdgcn_mfma_f32_16x16x32_bf16(af[i], bfr[j], acc[i][j], 0, 0, 0);

        cur = cur < 2 ? cur + 1 : 0;
    }
#pragma unroll
    for (int j = 0; j < 4; j++) {
        const int n = bn + wx * 64 + j * 16 + l16;
#pragma unroll
        for (int i = 0; i < 2; i++) {
            const int mbase = bm + wy * 32 + i * 16 + quad * 4;
#pragma unroll
            for (int r = 0; r < 4; r++)
                out[(size_t)(mbase + r) * 1024 + n] = (bf16_t)acc[i][j][r];
        }
    }
}

// ---------------------------------------------------------------- residual + LayerNorm (ao in bf16)
__global__ __launch_bounds__(256)
void ln_kernel(const float* __restrict__ inp, const bf16_t* __restrict__ ao,
               const float* __restrict__ gamma, const float* __restrict__ beta,
               float* __restrict__ out) {
    const int row = blockIdx.x, tid = threadIdx.x;
    const int wave = tid >> 6, lane = tid & 63;
    float4 a = ((const float4*)(inp + (size_t)row * 1024))[tid];
    bf16x4 c4 = ((const bf16x4*)(ao + (size_t)row * 1024))[tid];
    float x0 = a.x + (float)c4[0], x1 = a.y + (float)c4[1];
    float x2 = a.z + (float)c4[2], x3 = a.w + (float)c4[3];
    float s = x0 + x1 + x2 + x3;
    float sq = x0 * x0 + x1 * x1 + x2 * x2 + x3 * x3;
#pragma unroll
    for (int mm = 32; mm >= 1; mm >>= 1) {
        s += __shfl_xor(s, mm);
        sq += __shfl_xor(sq, mm);
    }
    __shared__ float rs[4], rq[4];
    if (lane == 0) { rs[wave] = s; rq[wave] = sq; }
    __syncthreads();
    s = rs[0] + rs[1] + rs[2] + rs[3];
    sq = rq[0] + rq[1] + rq[2] + rq[3];
    const float mu = s * (1.0f / 1024.0f);
    const float var = sq * (1.0f / 1024.0f) - mu * mu;
    const float rstd = rsqrtf(var + 1e-5f);
    float4 g = ((const float4*)gamma)[tid], bt = ((const float4*)beta)[tid];
    float4 o;
    o.x = (x0 - mu) * rstd * g.x + bt.x;
    o.y = (x1 - mu) * rstd * g.y + bt.y;
    o.z = (x2 - mu) * rstd * g.z + bt.z;
    o.w = (x3 - mu) * rstd * g.w + bt.w;
    ((float4*)(out + (size_t)row * 1024))[tid] = o;
}

// ---------------------------------------------------------------- launch
extern "C" void kernel_launch(void* const* d_in, const int* in_sizes, int n_in,
                              void* d_out, int out_size, void* d_ws, size_t ws_size,
                              hipStream_t stream) {
    const float* inp   = (const float*)d_in[0];
    const float* Wqkv  = (const float*)d_in[1];
    const float* bqkv  = (const float*)d_in[2];
    const float* Wo    = (const float*)d_in[3];
    const float* gamma = (const float*)d_in[4];
    const float* beta  = (const float*)d_in[5];
    float* out = (float*)d_out;

    // workspace layout (64 MB):
    //  0- 8 : inp_bf   (dead after gemm_qkv)
    //  8-14 : wqkv_bf  (dead after gemm_qkv)
    // 14-16 : wo_bf    (live until gemm_o)
    // 16-32 : qk_buf   (dead after attn)
    // 32-40 : vT_buf   (dead after attn)      -> ao_bf overlay (8 MB, gemm_o out)
    // 48-56 : ofin     (8 MB, final normalized attn_vec, read by gemm_o)
    char* ws = (char*)d_ws;
    bf16_t* inp_bf  = (bf16_t*)(ws);
    bf16_t* wqkv_bf = (bf16_t*)(ws + (8u << 20));
    bf16_t* wo_bf   = (bf16_t*)(ws + (14u << 20));
    bf16_t* qk_buf  = (bf16_t*)(ws + (16u << 20));
    bf16_t* vT_buf  = (bf16_t*)(ws + (32u << 20));
    bf16_t* ao_bf   = (bf16_t*)(ws + (32u << 20));
    bf16_t* ofin    = (bf16_t*)(ws + (48u << 20));

    cvt_all<<<8192, 256, 0, stream>>>(inp, Wqkv, Wo, inp_bf, wqkv_bf, wo_bf);
    gemm_qkv<<<dim3(24, 32), 256, 0, stream>>>(inp_bf, wqkv_bf, bqkv, qk_buf, vT_buf);
    attn_kernel<<<512, 256, 0, stream>>>(qk_buf, vT_buf, ofin);
    gemm_o<<<dim3(8, 64), 256, 0, stream>>>(ofin, wo_bf, ao_bf);
    ln_kernel<<<4096, 256, 0, stream>>>(inp, ao_bf, gamma, beta, out);
}

// Round 13
// 181.870 us; speedup vs baseline: 1.5440x; 1.0022x over previous
//
#include <hip/hip_runtime.h>
#include <hip/hip_bf16.h>
#include <stdint.h>

typedef __bf16 bf16_t;
typedef __bf16 bf16x8 __attribute__((ext_vector_type(8)));
typedef __bf16 bf16x4 __attribute__((ext_vector_type(4)));
typedef __bf16 bf16x2 __attribute__((ext_vector_type(2)));
typedef float floatx4 __attribute__((ext_vector_type(4)));

#define QSCALE 0.180336879f  /* 0.125 * log2(e) : fold score scale + exp2 domain into Q */

#if __has_builtin(__builtin_amdgcn_cvt_pk_bf16_f32)
#define HAS_PK_BF16 1
#endif

__device__ static inline void gll16(const void* g, void* l) {
    __builtin_amdgcn_global_load_lds((const __attribute__((address_space(1))) void*)g,
                                     (__attribute__((address_space(3))) void*)l, 16, 0, 0);
}

__device__ static inline bf16x8 pack8(const float* p) {
    bf16x8 o;
#ifdef HAS_PK_BF16
#pragma unroll
    for (int j = 0; j < 4; j++) {
        bf16x2 t2 = __builtin_amdgcn_cvt_pk_bf16_f32(p[2 * j], p[2 * j + 1]);
        o[2 * j] = t2[0]; o[2 * j + 1] = t2[1];
    }
#else
#pragma unroll
    for (int j = 0; j < 8; j++) o[j] = (bf16_t)p[j];
#endif
    return o;
}

// ---------------------------------------------------------------- fp32 -> bf16 (fused: inp, Wqkv, Wo)
__global__ __launch_bounds__(256) void cvt_all(const float* __restrict__ inp,
                                               const float* __restrict__ wqkv,
                                               const float* __restrict__ wo,
                                               bf16_t* __restrict__ o_inp,
                                               bf16_t* __restrict__ o_wqkv,
                                               bf16_t* __restrict__ o_wo) {
    int blk = blockIdx.x;
    const float* src;
    bf16_t* dst;
    if (blk < 4096)      { src = inp;  dst = o_inp; }
    else if (blk < 7168) { src = wqkv; dst = o_wqkv; blk -= 4096; }
    else                 { src = wo;   dst = o_wo;   blk -= 7168; }
    int i = blk * 256 + threadIdx.x;
    float4 v = ((const float4*)src)[i];
    float p[4] = {v.x, v.y, v.z, v.w};
    bf16x4 o;
#ifdef HAS_PK_BF16
    bf16x2 t0 = __builtin_amdgcn_cvt_pk_bf16_f32(p[0], p[1]);
    bf16x2 t1 = __builtin_amdgcn_cvt_pk_bf16_f32(p[2], p[3]);
    o[0] = t0[0]; o[1] = t0[1]; o[2] = t1[0]; o[3] = t1[1];
#else
    o[0] = (bf16_t)p[0]; o[1] = (bf16_t)p[1]; o[2] = (bf16_t)p[2]; o[3] = (bf16_t)p[3];
#endif
    ((bf16x4*)dst)[i] = o;
}

// ---------------------------------------------------------------- QKV GEMM
// R11 state: single barrier/iter (vmcnt(4) pre-barrier, prefetch post-barrier),
// 3 LDS buffers, chunk-XOR swizzle, XCD-chunked block swizzle.
// vT columns are t-PERMUTED within each 32-group: p = (t&~31) | q*8 | h*4 | r.
__global__ __launch_bounds__(256, 3)
void gemm_qkv(const bf16_t* __restrict__ A, const bf16_t* __restrict__ Bw,
              const float* __restrict__ bias,
              bf16_t* __restrict__ qk, bf16_t* __restrict__ vT) {
    constexpr int K = 1024;
    __shared__ bf16_t lA[3][128 * 32];
    __shared__ bf16_t lB[3][128 * 32];
    const int tid  = threadIdx.x;
    const int lane = tid & 63, wave = tid >> 6;
    const int quad = lane >> 4, l16 = lane & 15;
    const int wy = wave >> 1, wx = wave & 1;

    // XCD-chunked swizzle: 768 wg -> 96/XCD contiguous (768 % 8 == 0, bijective).
    const int L  = blockIdx.y * 24 + blockIdx.x;
    const int nL = (L & 7) * 96 + (L >> 3);
    const int bm = (nL / 24) * 128, bn = (nL % 24) * 128;

    const int c0 = tid, c1 = tid + 256;
    // source chunk pre-swizzle: LDS slot s of row r holds global chunk s ^ ((r>>1)&3)
    const int k0 = ((c0 & 3) ^ ((c0 >> 3) & 3)) * 8;
    const int k1 = ((c1 & 3) ^ ((c1 >> 3) & 3)) * 8;
    const bf16_t* Ap0 = A + (size_t)(bm + (c0 >> 2)) * K + k0;
    const bf16_t* Ap1 = A + (size_t)(bm + (c1 >> 2)) * K + k1;
    const bf16_t* Bp0 = Bw + (size_t)(bn + (c0 >> 2)) * K + k0;
    const bf16_t* Bp1 = Bw + (size_t)(bn + (c1 >> 2)) * K + k1;
    const int d0 = (wave * 64) * 8;          // wave-uniform dest (elems); HW adds lane*16B
    const int d1 = (256 + wave * 64) * 8;

    // read-side swizzled chunk
    const int sq8 = (quad ^ ((l16 >> 1) & 3)) * 8;

    floatx4 acc[4][4] = {};

    // prologue: stage tiles 0 and 1 (8 gll in flight)
    gll16(Ap0, &lA[0][d0]); gll16(Ap1, &lA[0][d1]);
    gll16(Bp0, &lB[0][d0]); gll16(Bp1, &lB[0][d1]);
    gll16(Ap0 + 32, &lA[1][d0]); gll16(Ap1 + 32, &lA[1][d1]);
    gll16(Bp0 + 32, &lB[1][d0]); gll16(Bp1 + 32, &lB[1][d1]);

    int cur = 0;
    for (int it = 0; it < 32; ++it) {
        if (it < 31) {
            asm volatile("s_waitcnt vmcnt(4)" ::: "memory");   // own tile-it glls landed
        } else {
            asm volatile("s_waitcnt vmcnt(0)" ::: "memory");
        }
        __builtin_amdgcn_s_barrier();          // everyone's tile-it writes published
        if (it < 30) {
            const int kt = (it + 2) * 32;
            const int nb = cur >= 1 ? cur - 1 : 2;        // (cur+2)%3 — read last at it-1
            gll16(Ap0 + kt, &lA[nb][d0]); gll16(Ap1 + kt, &lA[nb][d1]);
            gll16(Bp0 + kt, &lB[nb][d0]); gll16(Bp1 + kt, &lB[nb][d1]);
        }
        __builtin_amdgcn_sched_barrier(0);

        bf16x8 af[4], bfr[4];
#pragma unroll
        for (int i = 0; i < 4; i++) {
            af[i]  = *(const bf16x8*)(&lA[cur][(wy * 64 + i * 16 + l16) * 32 + sq8]);
            bfr[i] = *(const bf16x8*)(&lB[cur][(wx * 64 + i * 16 + l16) * 32 + sq8]);
        }
#pragma unroll
        for (int i = 0; i < 4; i++)
#pragma unroll
            for (int j = 0; j < 4; j++)
                acc[i][j] = __builtin_amdgcn_mfma_f32_16x16x32_bf16(af[i], bfr[j], acc[i][j], 0, 0, 0);

        cur = cur < 2 ? cur + 1 : 0;
    }

    const bool is_v = (bn >= 2048);
#pragma unroll
    for (int j = 0; j < 4; j++) {
        const int n = bn + wx * 64 + j * 16 + l16;
        const float bv = bias[n];
        const bool isq = (n < 1024);
#pragma unroll
        for (int i = 0; i < 4; i++) {
            const int mbase = bm + wy * 64 + i * 16 + quad * 4;
            if (!is_v) {
#pragma unroll
                for (int r = 0; r < 4; r++) {
                    float c = acc[i][j][r] + bv;
                    if (isq) c *= QSCALE;
                    qk[(size_t)(mbase + r) * 2048 + n] = (bf16_t)c;
                }
            } else {
                const int nn = n - 2048;             // h*64 + d
                const int b  = mbase >> 11;
                const int t  = mbase & 2047;         // 4-aligned
                const int vrow = b * 1024 + nn;      // (b*16+h)*64 + d
                const int pcol = (t & ~31) | (((t >> 2) & 3) << 3) | (((t >> 4) & 1) << 2);
                bf16x4 pack;
#pragma unroll
                for (int r = 0; r < 4; r++) pack[r] = (bf16_t)(acc[i][j][r] + bv);
                *(bf16x4*)(vT + (size_t)vrow * 2048 + pcol) = pack;
            }
        }
    }
}

// ---------------------------------------------------------------- flash attention (S^T, FULL-T, pipelined, 8-wave)
// R12: 512 threads / 8 waves per block, 16 q-rows per wave. Grid stays 512
// (2 blocks/CU) but waves/SIMD doubles 2 -> 4 — same LDS (48 KB x 2 = 96),
// same barrier count, same total MFMA; per-wave registers DROP (rt dim gone).
// Staging: one K-gll + one V-gll per thread/iter (dhalf=tid>>8, row=(tid>>2)&63,
// chunk=(tid&3)^XOR); per-wave vmcnt = 2/iter -> depth-2 = vmcnt(2) pre-barrier.
// Row-sum via ones-MFMA (R11). Single barrier/iter.
__global__ __launch_bounds__(512, 4)
void attn_kernel(const bf16_t* __restrict__ qk, const bf16_t* __restrict__ vT,
                 bf16_t* __restrict__ Ofin) {
    __shared__ bf16_t Kbuf[3][64 * 64];   // [buf][ d-half(2) ][ t(64) ][ d(32) ]  (lane-linear)
    __shared__ bf16_t Vbuf[3][64 * 64];   // [buf][ t-half(2) ][ d(64) ][ p(32) ]
    const int tid  = threadIdx.x;
    const int lane = tid & 63, wave = tid >> 6;
    const int quad = lane >> 4, l16 = lane & 15;
    const int bid = blockIdx.x;
    const int s    = bid & 31;
    const int hl   = ((s & 7) << 2) | ((s >> 3) & 3);  // XCD-swizzle: 4 heads/XCD
    const int qt   = bid >> 5;
    const int b = hl >> 4, h = hl & 15;

    const bf16_t* Qbase = qk + (size_t)(b * 2048 + qt * 128 + wave * 16) * 2048 + h * 64;
    const bf16_t* Kbase = qk + (size_t)(b * 2048) * 2048 + 1024 + h * 64;
    const bf16_t* Vbase = vT + (size_t)(hl * 64) * 2048;

    // staging (512 threads): LDS elem offset tid*8 -> dhalf=tid>>8, row=(tid>>2)&63, chunk=tid&3
    const int srow  = (tid >> 2) & 63;
    const int dhalf = tid >> 8;
    const int sc8 = ((tid & 3) ^ ((tid >> 3) & 3)) * 8;   // source chunk pre-swizzle
    const bf16_t* Kg = Kbase + (size_t)srow * 2048 + dhalf * 32 + sc8;
    const bf16_t* Vg = Vbase + (size_t)srow * 2048 + dhalf * 32 + sc8;  // srow=d-row, dhalf=t-half
    const int wbase = wave * 512;   // wave-uniform LDS dest; HW adds lane*16B

    // read-side swizzled chunk: fragment rows are nt*16+l16 / ct*16+l16 -> bits 1-2 from l16 only
    const int xq8 = (quad ^ ((l16 >> 1) & 3)) * 8;

    floatx4 accO[4] = {};    // O[q=quad*4+r][d=ct*16+l16]
    floatx4 accL = {};       // l[q=quad*4+r] (ones-MFMA row sums)
    bf16x8 onesf;
#pragma unroll
    for (int j = 0; j < 8; j++) onesf[j] = (bf16_t)1.0f;

    // Q fragments FIRST (so iter-0's vmcnt(2) drains them with tile 0)
    bf16x8 qf[2];  // B-operand: n = q = l16, k = kc*32 + quad*8
#pragma unroll
    for (int kc = 0; kc < 2; kc++)
        qf[kc] = *(const bf16x8*)(Qbase + (size_t)l16 * 2048 + kc * 32 + quad * 8);

    // prologue: stage tiles 0 and 1 (2 gll/wave each)
    gll16(Kg, &Kbuf[0][wbase]);
    gll16(Vg, &Vbuf[0][wbase]);
    gll16(Kg + (size_t)64 * 2048, &Kbuf[1][wbase]);
    gll16(Vg + 64, &Vbuf[1][wbase]);

    int cur = 0;
    for (int it = 0; it < 32; ++it) {
        if (it < 31) {
            asm volatile("s_waitcnt vmcnt(2)" ::: "memory");   // own tile-it glls landed; it+1 in flight
        } else {
            asm volatile("s_waitcnt vmcnt(0)" ::: "memory");
        }
        __builtin_amdgcn_s_barrier();          // everyone's tile-it writes published
        if (it < 30) {
            const int nb = cur >= 1 ? cur - 1 : 2;        // (cur+2)%3 — read last at it-1
            gll16(Kg + (size_t)(it + 2) * 64 * 2048, &Kbuf[nb][wbase]);
            gll16(Vg + (it + 2) * 64, &Vbuf[nb][wbase]);
        }
        __builtin_amdgcn_sched_barrier(0);

        // S^T = K.Q^T : rows t (quad*4+r per nt-tile), cols q (l16)
        floatx4 st[4] = {};
        __builtin_amdgcn_s_setprio(1);
#pragma unroll
        for (int nt = 0; nt < 4; nt++) {
            bf16x8 k0 = *(const bf16x8*)&Kbuf[cur][(nt * 16 + l16) * 32 + xq8];
            bf16x8 k1 = *(const bf16x8*)&Kbuf[cur][2048 + (nt * 16 + l16) * 32 + xq8];
            st[nt] = __builtin_amdgcn_mfma_f32_16x16x32_bf16(k0, qf[0], st[nt], 0, 0, 0);
            st[nt] = __builtin_amdgcn_mfma_f32_16x16x32_bf16(k1, qf[1], st[nt], 0, 0, 0);
        }
        __builtin_amdgcn_s_setprio(0);
        // per t-half: V frags once; P frags built in-register (permuted t-order)
#pragma unroll
        for (int kc2 = 0; kc2 < 2; kc2++) {
            bf16x8 vf[4];
#pragma unroll
            for (int ct = 0; ct < 4; ct++)
                vf[ct] = *(const bf16x8*)&Vbuf[cur][kc2 * 2048 + (ct * 16 + l16) * 32 + xq8];
            float p[8];
#pragma unroll
            for (int j = 0; j < 8; j++)
                p[j] = __builtin_amdgcn_exp2f(st[kc2 * 2 + (j >> 2)][j & 3]);
            bf16x8 pf = pack8(p);
            __builtin_amdgcn_s_setprio(1);
#pragma unroll
            for (int ct = 0; ct < 4; ct++)
                accO[ct] = __builtin_amdgcn_mfma_f32_16x16x32_bf16(pf, vf[ct], accO[ct], 0, 0, 0);
            accL = __builtin_amdgcn_mfma_f32_16x16x32_bf16(pf, onesf, accL, 0, 0, 0);
            __builtin_amdgcn_s_setprio(0);
        }

        cur = cur < 2 ? cur + 1 : 0;
    }

    // denominator already in accO layout: accL[r] = l for q=quad*4+r
    float linv[4];
#pragma unroll
    for (int r = 0; r < 4; r++) linv[r] = 1.0f / accL[r];

    // final O with "faithful bug" permutation: dest row (hl&1)*2048 + t, col (hl>>1)*64 + d
    const int b2 = hl & 1;
    const int colb = hl >> 1;
    const int rowb = b2 * 2048 + qt * 128 + wave * 16;
    bf16_t* outb = Ofin + (size_t)rowb * 1024 + colb * 64;
#pragma unroll
    for (int ct = 0; ct < 4; ct++)
#pragma unroll
        for (int r = 0; r < 4; r++)
            outb[(size_t)(quad * 4 + r) * 1024 + ct * 16 + l16] =
                (bf16_t)(accO[ct][r] * linv[r]);
}

// ---------------------------------------------------------------- O GEMM (plain, A already normalized)
// R11 state: single barrier/iter (vmcnt(3) pre-barrier, prefetch post-barrier),
// 3-buffer depth-2 pipeline, XCD-chunked swizzle.
__global__ __launch_bounds__(256, 4)
void gemm_o(const bf16_t* __restrict__ Op, const bf16_t* __restrict__ Bw,
            bf16_t* __restrict__ out) {
    constexpr int K = 1024;
    __shared__ bf16_t lA[3][64 * 32];    // 3 x 4 KB
    __shared__ bf16_t lB[3][128 * 32];   // 3 x 8 KB
    const int tid  = threadIdx.x;
    const int lane = tid & 63, wave = tid >> 6;
    const int quad = lane >> 4, l16 = lane & 15;
    const int wy = wave >> 1, wx = wave & 1;   // wave tile: 32m x 64n

    // XCD-chunked swizzle: 512 wg, bijective (512 % 8 == 0).
    const int L  = blockIdx.y * 8 + blockIdx.x;
    const int nL = (L & 7) * 64 + (L >> 3);
    const int bm = (nL >> 3) * 64, bn = (nL & 7) * 128;

    // A: 64 rows x 4 chunks, one gll16/thread; source chunk pre-swizzled
    const int akc = ((tid & 3) ^ ((tid >> 3) & 3)) * 8;
    const bf16_t* Ap = Op + (size_t)(bm + (tid >> 2)) * K + akc;
    const int dA = wave * 512;
    const int cb0 = tid, cb1 = tid + 256;       // B: 128 rows x 4 chunks
    const int bk0 = ((cb0 & 3) ^ ((cb0 >> 3) & 3)) * 8;
    const int bk1 = ((cb1 & 3) ^ ((cb1 >> 3) & 3)) * 8;
    const bf16_t* Bp0 = Bw + (size_t)(bn + (cb0 >> 2)) * K + bk0;
    const bf16_t* Bp1 = Bw + (size_t)(bn + (cb1 >> 2)) * K + bk1;
    const int d0 = wave * 512;
    const int d1 = 2048 + wave * 512;

    // read-side swizzled chunk (fragment rows: bits 1-2 from l16 only)
    const int xq8 = (quad ^ ((l16 >> 1) & 3)) * 8;

    // prologue: stage tiles 0 and 1 (6 gll in flight)
    gll16(Ap, &lA[0][dA]);
    gll16(Bp0, &lB[0][d0]); gll16(Bp1, &lB[0][d1]);
    gll16(Ap + 32, &lA[1][dA]);
    gll16(Bp0 + 32, &lB[1][d0]); gll16(Bp1 + 32, &lB[1][d1]);

    floatx4 acc[2][4] = {};
    int cur = 0;
    for (int it = 0; it < 32; ++it) {
        if (it < 31) {
            asm volatile("s_waitcnt vmcnt(3)" ::: "memory");   // own tile-it glls landed
        } else {
            asm volatile("s_waitcnt vmcnt(0)" ::: "memory");
        }
        __builtin_amdgcn_s_barrier();
        if (it < 30) {
            const int kt = (it + 2) * 32;
            const int nb = cur >= 1 ? cur - 1 : 2;        // (cur+2)%3 — read last at it-1
            gll16(Ap + kt, &lA[nb][dA]);
            gll16(Bp0 + kt, &lB[nb][d0]); gll16(Bp1 + kt, &lB[nb][d1]);
        }
        __builtin_amdgcn_sched_barrier(0);

        bf16x8 af[2], bfr[4];
#pragma unroll
        for (int i = 0; i < 2; i++)
            af[i] = *(const bf16x8*)(&lA[cur][(wy * 32 + i * 16 + l16) * 32 + xq8]);
#pragma unroll
        for (int j = 0; j < 4; j++)
            bfr[j] = *(const bf16x8*)(&lB[cur][(wx * 64 + j * 16 + l16) * 32 + xq8]);
#pragma unroll
        for (int i = 0; i < 2; i++)
#pragma unroll
            for (int j = 0; j < 4; j++)
                acc[i][j] = __builtin_amdgcn_mfma_f32_16x16x32_bf16(af[i], bfr[j], acc[i][j], 0, 0, 0);

        cur = cur < 2 ? cur + 1 : 0;
    }
#pragma unroll
    for (int j = 0; j < 4; j++) {
        const int n = bn + wx * 64 + j * 16 + l16;
#pragma unroll
        for (int i = 0; i < 2; i++) {
            const int mbase = bm + wy * 32 + i * 16 + quad * 4;
#pragma unroll
            for (int r = 0; r < 4; r++)
                out[(size_t)(mbase + r) * 1024 + n] = (bf16_t)acc[i][j][r];
        }
    }
}

// ---------------------------------------------------------------- residual + LayerNorm (ao in bf16)
__global__ __launch_bounds__(256)
void ln_kernel(const float* __restrict__ inp, const bf16_t* __restrict__ ao,
               const float* __restrict__ gamma, const float* __restrict__ beta,
               float* __restrict__ out) {
    const int row = blockIdx.x, tid = threadIdx.x;
    const int wave = tid >> 6, lane = tid & 63;
    float4 a = ((const float4*)(inp + (size_t)row * 1024))[tid];
    bf16x4 c4 = ((const bf16x4*)(ao + (size_t)row * 1024))[tid];
    float x0 = a.x + (float)c4[0], x1 = a.y + (float)c4[1];
    float x2 = a.z + (float)c4[2], x3 = a.w + (float)c4[3];
    float s = x0 + x1 + x2 + x3;
    float sq = x0 * x0 + x1 * x1 + x2 * x2 + x3 * x3;
#pragma unroll
    for (int mm = 32; mm >= 1; mm >>= 1) {
        s += __shfl_xor(s, mm);
        sq += __shfl_xor(sq, mm);
    }
    __shared__ float rs[4], rq[4];
    if (lane == 0) { rs[wave] = s; rq[wave] = sq; }
    __syncthreads();
    s = rs[0] + rs[1] + rs[2] + rs[3];
    sq = rq[0] + rq[1] + rq[2] + rq[3];
    const float mu = s * (1.0f / 1024.0f);
    const float var = sq * (1.0f / 1024.0f) - mu * mu;
    const float rstd = rsqrtf(var + 1e-5f);
    float4 g = ((const float4*)gamma)[tid], bt = ((const float4*)beta)[tid];
    float4 o;
    o.x = (x0 - mu) * rstd * g.x + bt.x;
    o.y = (x1 - mu) * rstd * g.y + bt.y;
    o.z = (x2 - mu) * rstd * g.z + bt.z;
    o.w = (x3 - mu) * rstd * g.w + bt.w;
    ((float4*)(out + (size_t)row * 1024))[tid] = o;
}

// ---------------------------------------------------------------- launch
extern "C" void kernel_launch(void* const* d_in, const int* in_sizes, int n_in,
                              void* d_out, int out_size, void* d_ws, size_t ws_size,
                              hipStream_t stream) {
    const float* inp   = (const float*)d_in[0];
    const float* Wqkv  = (const float*)d_in[1];
    const float* bqkv  = (const float*)d_in[2];
    const float* Wo    = (const float*)d_in[3];
    const float* gamma = (const float*)d_in[4];
    const float* beta  = (const float*)d_in[5];
    float* out = (float*)d_out;

    // workspace layout (64 MB):
    //  0- 8 : inp_bf   (dead after gemm_qkv)
    //  8-14 : wqkv_bf  (dead after gemm_qkv)
    // 14-16 : wo_bf    (live until gemm_o)
    // 16-32 : qk_buf   (dead after attn)
    // 32-40 : vT_buf   (dead after attn)      -> ao_bf overlay (8 MB, gemm_o out)
    // 48-56 : ofin     (8 MB, final normalized attn_vec, read by gemm_o)
    char* ws = (char*)d_ws;
    bf16_t* inp_bf  = (bf16_t*)(ws);
    bf16_t* wqkv_bf = (bf16_t*)(ws + (8u << 20));
    bf16_t* wo_bf   = (bf16_t*)(ws + (14u << 20));
    bf16_t* qk_buf  = (bf16_t*)(ws + (16u << 20));
    bf16_t* vT_buf  = (bf16_t*)(ws + (32u << 20));
    bf16_t* ao_bf   = (bf16_t*)(ws + (32u << 20));
    bf16_t* ofin    = (bf16_t*)(ws + (48u << 20));

    cvt_all<<<8192, 256, 0, stream>>>(inp, Wqkv, Wo, inp_bf, wqkv_bf, wo_bf);
    gemm_qkv<<<dim3(24, 32), 256, 0, stream>>>(inp_bf, wqkv_bf, bqkv, qk_buf, vT_buf);
    attn_kernel<<<512, 512, 0, stream>>>(qk_buf, vT_buf, ofin);
    gemm_o<<<dim3(8, 64), 256, 0, stream>>>(ofin, wo_bf, ao_bf);
    ln_kernel<<<4096, 256, 0, stream>>>(inp, ao_bf, gamma, beta, out);
}